// Round 4
// baseline (2327.411 us; speedup 1.0000x reference)
//
#include <hip/hip_runtime.h>

typedef __attribute__((ext_vector_type(8))) short bf16x8_t;
typedef __attribute__((ext_vector_type(4))) float f32x4_t;

constexpr int NG = 16;
constexpr float EPS = 1e-5f;

__device__ inline unsigned short f2bf(float f) {
  unsigned u = __builtin_bit_cast(unsigned, f);
  u += 0x7FFFu + ((u >> 16) & 1u);
  return (unsigned short)(u >> 16);
}
__device__ inline float bf2f(unsigned short u) {
  unsigned x = ((unsigned)u) << 16;
  return __builtin_bit_cast(float, x);
}

// =====================================================================
// K1: EDGE update MM + (optional) nmp partial.
//   e_out = affE_in(e_in) + [x_s|x_d|affE_in(e_in)]@W_ne + b_ne  (+stats)
//   pn    = [x_s|x_d]@W_nmp[0:256]   (bf16, no bias)   [PN only]
// Shares the x gathers between stage 1 and stage 4.
// =====================================================================
template<bool PN>
__global__ __launch_bounds__(256, 2) void k_fused_edge(
    const float* __restrict__ x, const float* e_in, float* e_out,
    const int* __restrict__ ei, const int* __restrict__ ebatch,
    const unsigned short* __restrict__ WtE,   // wt_ne  [64][320]
    const unsigned short* __restrict__ WtP,   // wt_nmp [128][320]
    const float* __restrict__ bias,           // b_ne
    const float* __restrict__ afA, const float* __restrict__ afB,
    float* __restrict__ gs1, float* __restrict__ gs2,
    unsigned short* __restrict__ pn, int nE)
{
  __shared__ float lA[1024], lB[1024];
  __shared__ float ls1[NG], ls2[NG];
  for (int i = threadIdx.x; i < 1024; i += 256) { lA[i] = afA[i]; lB[i] = afB[i]; }
  if (threadIdx.x < NG) { ls1[threadIdx.x] = 0.f; ls2[threadIdx.x] = 0.f; }
  __syncthreads();
  int gw = (int)((blockIdx.x * 256u + threadIdx.x) >> 6);
  int ntile = nE >> 4;
  bool act = gw < ntile;
  int lane = threadIdx.x & 63;
  int colb = lane & 15;
  int ko = (lane >> 4) << 3;
  int rowb = (lane >> 4) << 2;
  float sr[4] = {0.f,0.f,0.f,0.f}, ssr[4] = {0.f,0.f,0.f,0.f};
  if (act) {
    int row = (gw << 4) + colb;
    int s = ei[row], d = ei[nE + row];
    int ge = ebatch[row];
    const float* xs = x + (size_t)s * 128;
    const float* xd = x + (size_t)d * 128;
    const float* er = e_in + (size_t)row * 64;
    f32x4_t accE[4] = {};
    f32x4_t accP[8] = {};
#pragma unroll
    for (int c = 0; c < 10; ++c) {
      float v[8];
      if (c < 8) {
        const float* bp = (c < 4) ? xs + c * 32 : xd + (c - 4) * 32;
        float4 f0 = *(const float4*)(bp + ko);
        float4 f1 = *(const float4*)(bp + ko + 4);
        v[0]=f0.x; v[1]=f0.y; v[2]=f0.z; v[3]=f0.w;
        v[4]=f1.x; v[5]=f1.y; v[6]=f1.z; v[7]=f1.w;
      } else {
        int fb = (c - 8) * 32 + ko;
        float4 f0 = *(const float4*)(er + fb);
        float4 f1 = *(const float4*)(er + fb + 4);
        float vv[8] = {f0.x,f0.y,f0.z,f0.w,f1.x,f1.y,f1.z,f1.w};
#pragma unroll
        for (int k = 0; k < 8; ++k) v[k] = vv[k] * lA[ge*64 + fb + k] + lB[ge*64 + fb + k];
      }
      bf16x8_t a;
#pragma unroll
      for (int k = 0; k < 8; ++k) a[k] = (short)f2bf(v[k]);
#pragma unroll
      for (int nb = 0; nb < 4; ++nb) {
        bf16x8_t b = *(const bf16x8_t*)(WtE + (size_t)(nb * 16 + colb) * 320 + c * 32 + ko);
        accE[nb] = __builtin_amdgcn_mfma_f32_16x16x32_bf16(a, b, accE[nb], 0, 0, 0);
      }
      if (PN && c < 8) {
#pragma unroll
        for (int nb = 0; nb < 8; ++nb) {
          bf16x8_t b = *(const bf16x8_t*)(WtP + (size_t)(nb * 16 + colb) * 320 + c * 32 + ko);
          accP[nb] = __builtin_amdgcn_mfma_f32_16x16x32_bf16(a, b, accP[nb], 0, 0, 0);
        }
      }
    }
#pragma unroll
    for (int r = 0; r < 4; ++r) {
      int e_ = (gw << 4) + rowb + r;
      int gr = ebatch[e_];
#pragma unroll
      for (int nb = 0; nb < 4; ++nb) {
        int col = nb * 16 + colb;
        size_t off = (size_t)e_ * 64 + col;
        float vv = e_in[off] * lA[gr*64 + col] + lB[gr*64 + col] + bias[col] + accE[nb][r];
        e_out[off] = vv;
        sr[r] += vv; ssr[r] += vv * vv;
      }
      if (PN) {
#pragma unroll
        for (int nb = 0; nb < 8; ++nb) {
          int col = nb * 16 + colb;
          pn[(size_t)e_ * 128 + col] = f2bf(accP[nb][r]);
        }
      }
    }
  }
#pragma unroll
  for (int m = 1; m <= 8; m <<= 1)
#pragma unroll
    for (int r = 0; r < 4; ++r) { sr[r] += __shfl_xor(sr[r], m); ssr[r] += __shfl_xor(ssr[r], m); }
  if (act && colb == 0) {
#pragma unroll
    for (int r = 0; r < 4; ++r) {
      int g = ebatch[(gw << 4) + rowb + r];
      atomicAdd(&ls1[g], sr[r]); atomicAdd(&ls2[g], ssr[r]);
    }
  }
  __syncthreads();
  if (threadIdx.x < NG) {
    atomicAdd(&gs1[threadIdx.x], ls1[threadIdx.x]);
    atomicAdd(&gs2[threadIdx.x], ls2[threadIdx.x]);
  }
}

// =====================================================================
// K2: ANGLE update MM + emp partial.
//   a_out = affA_in(a_in) + [affE1(e_s)|affE1(e_d)|affA_in(a_in)]@W_ea + b_ea (+stats)
//   pe    = [affE1(e_s)|affE1(e_d)]@W_emp[0:128]  (bf16, no bias) -> msg buffer
// Shares the e gathers between stage 2 and stage 3.
// =====================================================================
__global__ __launch_bounds__(256, 2) void k_fused_angle(
    const float* __restrict__ e, const float* a_in, float* a_out,
    const int* __restrict__ ti, const int* __restrict__ ebatch,
    const int* __restrict__ abatch,
    const unsigned short* __restrict__ WtA,   // wt_ea  [64][192]
    const unsigned short* __restrict__ WtP,   // wt_emp [64][192]
    const float* __restrict__ bias,           // b_ea
    const float* __restrict__ afEA, const float* __restrict__ afEB,
    const float* __restrict__ afAA, const float* __restrict__ afAB,
    float* __restrict__ gs1, float* __restrict__ gs2,
    unsigned short* __restrict__ pe, int nA)
{
  __shared__ float lEA[1024], lEB[1024], lAA[1024], lAB[1024];
  __shared__ float ls1[NG], ls2[NG];
  for (int i = threadIdx.x; i < 1024; i += 256) {
    lEA[i] = afEA[i]; lEB[i] = afEB[i]; lAA[i] = afAA[i]; lAB[i] = afAB[i];
  }
  if (threadIdx.x < NG) { ls1[threadIdx.x] = 0.f; ls2[threadIdx.x] = 0.f; }
  __syncthreads();
  int gw = (int)((blockIdx.x * 256u + threadIdx.x) >> 6);
  int ntile = nA >> 4;
  bool act = gw < ntile;
  int lane = threadIdx.x & 63;
  int colb = lane & 15;
  int ko = (lane >> 4) << 3;
  int rowb = (lane >> 4) << 2;
  float sr[4] = {0.f,0.f,0.f,0.f}, ssr[4] = {0.f,0.f,0.f,0.f};
  if (act) {
    int row = (gw << 4) + colb;
    int s = ti[row], d = ti[nA + row];
    int gs = ebatch[s], gd = ebatch[d], ga = abatch[row];
    const float* es = e + (size_t)s * 64;
    const float* ed = e + (size_t)d * 64;
    const float* ar = a_in + (size_t)row * 64;
    f32x4_t accA[4] = {};
    f32x4_t accP[4] = {};
#pragma unroll
    for (int c = 0; c < 6; ++c) {
      const float* bp; const float* tA; const float* tB; int fb;
      if (c < 2)      { bp = es + c * 32;       fb = c * 32 + ko;       tA = lEA + gs*64; tB = lEB + gs*64; }
      else if (c < 4) { bp = ed + (c - 2) * 32; fb = (c - 2) * 32 + ko; tA = lEA + gd*64; tB = lEB + gd*64; }
      else            { bp = ar + (c - 4) * 32; fb = (c - 4) * 32 + ko; tA = lAA + ga*64; tB = lAB + ga*64; }
      float4 f0 = *(const float4*)(bp + ko);
      float4 f1 = *(const float4*)(bp + ko + 4);
      float vv[8] = {f0.x,f0.y,f0.z,f0.w,f1.x,f1.y,f1.z,f1.w};
      bf16x8_t a;
#pragma unroll
      for (int k = 0; k < 8; ++k) a[k] = (short)f2bf(vv[k] * tA[fb + k] + tB[fb + k]);
#pragma unroll
      for (int nb = 0; nb < 4; ++nb) {
        bf16x8_t b = *(const bf16x8_t*)(WtA + (size_t)(nb * 16 + colb) * 192 + c * 32 + ko);
        accA[nb] = __builtin_amdgcn_mfma_f32_16x16x32_bf16(a, b, accA[nb], 0, 0, 0);
      }
      if (c < 4) {
#pragma unroll
        for (int nb = 0; nb < 4; ++nb) {
          bf16x8_t b = *(const bf16x8_t*)(WtP + (size_t)(nb * 16 + colb) * 192 + c * 32 + ko);
          accP[nb] = __builtin_amdgcn_mfma_f32_16x16x32_bf16(a, b, accP[nb], 0, 0, 0);
        }
      }
    }
#pragma unroll
    for (int r = 0; r < 4; ++r) {
      int a_ = (gw << 4) + rowb + r;
      int gr = abatch[a_];
#pragma unroll
      for (int nb = 0; nb < 4; ++nb) {
        int col = nb * 16 + colb;
        size_t off = (size_t)a_ * 64 + col;
        float vv = a_in[off] * lAA[gr*64 + col] + lAB[gr*64 + col] + bias[col] + accA[nb][r];
        a_out[off] = vv;
        sr[r] += vv; ssr[r] += vv * vv;
        pe[off] = f2bf(accP[nb][r]);
      }
    }
  }
#pragma unroll
  for (int m = 1; m <= 8; m <<= 1)
#pragma unroll
    for (int r = 0; r < 4; ++r) { sr[r] += __shfl_xor(sr[r], m); ssr[r] += __shfl_xor(ssr[r], m); }
  if (act && colb == 0) {
#pragma unroll
    for (int r = 0; r < 4; ++r) {
      int g = abatch[(gw << 4) + rowb + r];
      atomicAdd(&ls1[g], sr[r]); atomicAdd(&ls2[g], ssr[r]);
    }
  }
  __syncthreads();
  if (threadIdx.x < NG) {
    atomicAdd(&gs1[threadIdx.x], ls1[threadIdx.x]);
    atomicAdd(&gs2[threadIdx.x], ls2[threadIdx.x]);
  }
}

// =====================================================================
// K3: emp finish (stream, no gathers):
//   msg = relu(pe + affA1(a1_row)@W_emp[128:192] + b_emp)   [in-place in msg]
// =====================================================================
__global__ __launch_bounds__(256) void k_fin_emp(
    const float* __restrict__ a_, const int* __restrict__ abatch,
    const unsigned short* __restrict__ Wt,    // wt_emp [64][192]
    const float* __restrict__ bias,           // b_emp
    const float* __restrict__ afAA, const float* __restrict__ afAB,
    unsigned short* __restrict__ msg, int nA)
{
  __shared__ float lAA[1024], lAB[1024];
  for (int i = threadIdx.x; i < 1024; i += 256) { lAA[i] = afAA[i]; lAB[i] = afAB[i]; }
  __syncthreads();
  int gw = (int)((blockIdx.x * 256u + threadIdx.x) >> 6);
  int ntile = nA >> 4;
  if (gw >= ntile) return;
  int lane = threadIdx.x & 63;
  int colb = lane & 15;
  int ko = (lane >> 4) << 3;
  int rowb = (lane >> 4) << 2;
  int row = (gw << 4) + colb;
  int ga = abatch[row];
  const float* ar = a_ + (size_t)row * 64;
  f32x4_t acc[4] = {};
#pragma unroll
  for (int c2 = 0; c2 < 2; ++c2) {
    int fb = c2 * 32 + ko;
    float4 f0 = *(const float4*)(ar + fb);
    float4 f1 = *(const float4*)(ar + fb + 4);
    float vv[8] = {f0.x,f0.y,f0.z,f0.w,f1.x,f1.y,f1.z,f1.w};
    bf16x8_t a;
#pragma unroll
    for (int k = 0; k < 8; ++k) a[k] = (short)f2bf(vv[k] * lAA[ga*64 + fb + k] + lAB[ga*64 + fb + k]);
#pragma unroll
    for (int nb = 0; nb < 4; ++nb) {
      bf16x8_t b = *(const bf16x8_t*)(Wt + (size_t)(nb * 16 + colb) * 192 + 128 + c2 * 32 + ko);
      acc[nb] = __builtin_amdgcn_mfma_f32_16x16x32_bf16(a, b, acc[nb], 0, 0, 0);
    }
  }
#pragma unroll
  for (int r = 0; r < 4; ++r) {
    int a_idx = (gw << 4) + rowb + r;
#pragma unroll
    for (int nb = 0; nb < 4; ++nb) {
      int col = nb * 16 + colb;
      size_t off = (size_t)a_idx * 64 + col;
      float v = fmaxf(acc[nb][r] + bf2f(msg[off]) + bias[col], 0.f);
      msg[off] = f2bf(v);
    }
  }
}

// =====================================================================
// K5: nmp finish (stream, no gathers):
//   msg = relu(pn + affE2(e2_row)@W_nmp[256:320] + b_nmp)
// =====================================================================
__global__ __launch_bounds__(256) void k_fin_nmp(
    const float* __restrict__ e, const int* __restrict__ ebatch,
    const unsigned short* __restrict__ Wt,    // wt_nmp [128][320]
    const float* __restrict__ bias,           // b_nmp
    const float* __restrict__ afEA, const float* __restrict__ afEB,
    const unsigned short* __restrict__ pn,
    unsigned short* __restrict__ msg, int nE)
{
  __shared__ float lEA[1024], lEB[1024];
  for (int i = threadIdx.x; i < 1024; i += 256) { lEA[i] = afEA[i]; lEB[i] = afEB[i]; }
  __syncthreads();
  int gw = (int)((blockIdx.x * 256u + threadIdx.x) >> 6);
  int ntile = nE >> 4;
  if (gw >= ntile) return;
  int lane = threadIdx.x & 63;
  int colb = lane & 15;
  int ko = (lane >> 4) << 3;
  int rowb = (lane >> 4) << 2;
  int row = (gw << 4) + colb;
  int ge = ebatch[row];
  const float* er = e + (size_t)row * 64;
  f32x4_t acc[8] = {};
#pragma unroll
  for (int c2 = 0; c2 < 2; ++c2) {
    int fb = c2 * 32 + ko;
    float4 f0 = *(const float4*)(er + fb);
    float4 f1 = *(const float4*)(er + fb + 4);
    float vv[8] = {f0.x,f0.y,f0.z,f0.w,f1.x,f1.y,f1.z,f1.w};
    bf16x8_t a;
#pragma unroll
    for (int k = 0; k < 8; ++k) a[k] = (short)f2bf(vv[k] * lEA[ge*64 + fb + k] + lEB[ge*64 + fb + k]);
#pragma unroll
    for (int nb = 0; nb < 8; ++nb) {
      bf16x8_t b = *(const bf16x8_t*)(Wt + (size_t)(nb * 16 + colb) * 320 + 256 + c2 * 32 + ko);
      acc[nb] = __builtin_amdgcn_mfma_f32_16x16x32_bf16(a, b, acc[nb], 0, 0, 0);
    }
  }
#pragma unroll
  for (int r = 0; r < 4; ++r) {
    int e_ = (gw << 4) + rowb + r;
#pragma unroll
    for (int nb = 0; nb < 8; ++nb) {
      int col = nb * 16 + colb;
      size_t off = (size_t)e_ * 128 + col;
      float v = fmaxf(acc[nb][r] + bf2f(pn[off]) + bias[col], 0.f);
      msg[off] = f2bf(v);
    }
  }
}

// =====================================================================
// FALLBACK (ws too small for pn): original gather message MM for nodes.
// =====================================================================
__global__ __launch_bounds__(256) void k_mm_nmp(
    const float* __restrict__ x, const float* __restrict__ e,
    const int* __restrict__ ei, const int* __restrict__ ebatch,
    const unsigned short* __restrict__ Wt, const float* __restrict__ bias,
    const float* __restrict__ afEA, const float* __restrict__ afEB,
    unsigned short* __restrict__ msg, int nE)
{
  __shared__ float lA[1024], lB[1024];
  for (int i = threadIdx.x; i < 1024; i += 256) { lA[i] = afEA[i]; lB[i] = afEB[i]; }
  __syncthreads();
  int gw = (int)((blockIdx.x * 256u + threadIdx.x) >> 6);
  int ntile = nE >> 4;
  if (gw >= ntile) return;
  int lane = threadIdx.x & 63;
  int colb = lane & 15;
  int ko = (lane >> 4) << 3;
  int rowb = (lane >> 4) << 2;
  int row = (gw << 4) + colb;
  int s = ei[row], d = ei[nE + row];
  int ge = ebatch[row];
  const float* xs = x + (size_t)s * 128;
  const float* xd = x + (size_t)d * 128;
  const float* er = e + (size_t)row * 64;
  f32x4_t acc[8] = {};
#pragma unroll
  for (int c = 0; c < 10; ++c) {
    float v[8];
    if (c < 8) {
      const float* bp = (c < 4) ? xs + c * 32 : xd + (c - 4) * 32;
      float4 f0 = *(const float4*)(bp + ko);
      float4 f1 = *(const float4*)(bp + ko + 4);
      v[0]=f0.x; v[1]=f0.y; v[2]=f0.z; v[3]=f0.w;
      v[4]=f1.x; v[5]=f1.y; v[6]=f1.z; v[7]=f1.w;
    } else {
      int fb = (c - 8) * 32 + ko;
      float4 f0 = *(const float4*)(er + fb);
      float4 f1 = *(const float4*)(er + fb + 4);
      float vv[8] = {f0.x,f0.y,f0.z,f0.w,f1.x,f1.y,f1.z,f1.w};
#pragma unroll
      for (int k = 0; k < 8; ++k) v[k] = vv[k] * lA[ge*64 + fb + k] + lB[ge*64 + fb + k];
    }
    bf16x8_t a;
#pragma unroll
    for (int k = 0; k < 8; ++k) a[k] = (short)f2bf(v[k]);
#pragma unroll
    for (int nb = 0; nb < 8; ++nb) {
      bf16x8_t b = *(const bf16x8_t*)(Wt + (size_t)(nb * 16 + colb) * 320 + c * 32 + ko);
      acc[nb] = __builtin_amdgcn_mfma_f32_16x16x32_bf16(a, b, acc[nb], 0, 0, 0);
    }
  }
#pragma unroll
  for (int r = 0; r < 4; ++r) {
    int e_ = (gw << 4) + rowb + r;
#pragma unroll
    for (int nb = 0; nb < 8; ++nb) {
      int col = nb * 16 + colb;
      float v = fmaxf(acc[nb][r] + bias[col], 0.f);
      msg[(size_t)e_ * 128 + col] = f2bf(v);
    }
  }
}

// =====================================================================
// CSR gather-reduce over edges: e2 = affE1(e1) + sum(msg rows); fused stats.
// =====================================================================
__global__ __launch_bounds__(256) void k_red_e(
    const unsigned short* __restrict__ msg, const float* e_in, float* e_out,
    const int* __restrict__ ptr, const int* __restrict__ perm,
    const int* __restrict__ ebatch,
    const float* __restrict__ afA, const float* __restrict__ afB,
    float* __restrict__ gs1, float* __restrict__ gs2, int nE)
{
  __shared__ float lA[1024], lB[1024], ls1[NG], ls2[NG];
  for (int i = threadIdx.x; i < 1024; i += 256) { lA[i] = afA[i]; lB[i] = afB[i]; }
  if (threadIdx.x < NG) { ls1[threadIdx.x] = 0.f; ls2[threadIdx.x] = 0.f; }
  __syncthreads();
  int lane = threadIdx.x & 63;
  int wv = (int)((blockIdx.x * 256u + threadIdx.x) >> 6);
  int nw = (int)((gridDim.x * 256u) >> 6);
  for (int eidx = wv; eidx < nE; eidx += nw) {
    int p0 = ptr[eidx], p1 = ptr[eidx + 1];
    float sum = 0.f;
    for (int j = p0; j < p1; ++j) {
      int aidx = perm[j];
      sum += bf2f(msg[(size_t)aidx * 64 + lane]);
    }
    int g = ebatch[eidx];
    size_t off = (size_t)eidx * 64 + lane;
    float v = e_in[off] * lA[g*64 + lane] + lB[g*64 + lane] + sum;
    e_out[off] = v;
    float s = v, ss = v * v;
#pragma unroll
    for (int m = 1; m < 64; m <<= 1) { s += __shfl_xor(s, m); ss += __shfl_xor(ss, m); }
    if (lane == 0) { atomicAdd(&ls1[g], s); atomicAdd(&ls2[g], ss); }
  }
  __syncthreads();
  if (threadIdx.x < NG) {
    atomicAdd(&gs1[threadIdx.x], ls1[threadIdx.x]);
    atomicAdd(&gs2[threadIdx.x], ls2[threadIdx.x]);
  }
}

// =====================================================================
// CSR gather-reduce over nodes: h = x + sum(msg rows); fused stats.
// =====================================================================
__global__ __launch_bounds__(256) void k_red_n(
    const unsigned short* __restrict__ msg, const float* x_in, float* out,
    const int* __restrict__ ptr, const int* __restrict__ perm,
    const int* __restrict__ nbatch,
    float* __restrict__ gs1, float* __restrict__ gs2, int nN)
{
  __shared__ float ls1[NG], ls2[NG];
  if (threadIdx.x < NG) { ls1[threadIdx.x] = 0.f; ls2[threadIdx.x] = 0.f; }
  __syncthreads();
  int lane = threadIdx.x & 63;
  int wv = (int)((blockIdx.x * 256u + threadIdx.x) >> 6);
  int nw = (int)((gridDim.x * 256u) >> 6);
  for (int n = wv; n < nN; n += nw) {
    int p0 = ptr[n], p1 = ptr[n + 1];
    float s0 = 0.f, s1v = 0.f;
    for (int j = p0; j < p1; ++j) {
      int e = perm[j];
      unsigned u = *(const unsigned*)(msg + (size_t)e * 128 + lane * 2);
      s0 += bf2f((unsigned short)(u & 0xffffu));
      s1v += bf2f((unsigned short)(u >> 16));
    }
    size_t off = (size_t)n * 128 + lane * 2;
    float h0 = x_in[off] + s0, h1 = x_in[off + 1] + s1v;
    out[off] = h0; out[off + 1] = h1;
    float s = h0 + h1, ss = h0 * h0 + h1 * h1;
#pragma unroll
    for (int m = 1; m < 64; m <<= 1) { s += __shfl_xor(s, m); ss += __shfl_xor(ss, m); }
    if (lane == 0) { int g = nbatch[n]; atomicAdd(&ls1[g], s); atomicAdd(&ls2[g], ss); }
  }
  __syncthreads();
  if (threadIdx.x < NG) {
    atomicAdd(&gs1[threadIdx.x], ls1[threadIdx.x]);
    atomicAdd(&gs2[threadIdx.x], ls2[threadIdx.x]);
  }
}

// ---- affine table construction: A=inv*w[f], B=b[f]-m*inv*w[f] ----
__global__ __launch_bounds__(256) void k_mkaff(
    const float* __restrict__ s1, const float* __restrict__ s2,
    const float* __restrict__ cnt, int F,
    const float* __restrict__ w, const float* __restrict__ b,
    float* __restrict__ A, float* __restrict__ B)
{
  int idx = blockIdx.x * 256 + threadIdx.x;
  if (idx >= NG * F) return;
  int g = idx / F, f = idx - g * F;
  float norm = fmaxf(cnt[g], 1.f) * (float)F;
  float m = s1[g] / norm;
  float var = s2[g] / norm - m * m;
  float inv = rsqrtf(var + EPS);
  float a = inv * w[f];
  A[idx] = a;
  B[idx] = b[f] - m * a;
}

__global__ __launch_bounds__(256) void k_idaff(float* __restrict__ A, float* __restrict__ B, int n)
{
  int idx = blockIdx.x * 256 + threadIdx.x;
  if (idx < n) { A[idx] = 1.f; B[idx] = 0.f; }
}

// ---- apply materialized norm to x (in-place) ----
__global__ __launch_bounds__(256) void k_apply(
    float* h, const int* __restrict__ batch,
    const float* __restrict__ A, const float* __restrict__ B, long total)
{
  long stride = (long)gridDim.x * 256;
  for (long idx = (long)blockIdx.x * 256 + threadIdx.x; idx < total; idx += stride) {
    int g = batch[idx >> 7];
    int f = (int)(idx & 127);
    h[idx] = h[idx] * A[(g << 7) | f] + B[(g << 7) | f];
  }
}

__global__ __launch_bounds__(256) void k_count(
    const int* __restrict__ batch, int n, float* __restrict__ cnt)
{
  __shared__ float lc[NG];
  if (threadIdx.x < NG) lc[threadIdx.x] = 0.f;
  __syncthreads();
  for (int i = blockIdx.x * 256 + threadIdx.x; i < n; i += gridDim.x * 256)
    atomicAdd(&lc[batch[i]], 1.f);
  __syncthreads();
  if (threadIdx.x < NG) atomicAdd(&cnt[threadIdx.x], lc[threadIdx.x]);
}

// ---- CSR build: histogram, 3-kernel scan, scatter ----
__global__ __launch_bounds__(256) void k_hist(
    const int* __restrict__ dst, int n, int* __restrict__ cnt)
{
  for (int i = blockIdx.x * 256 + threadIdx.x; i < n; i += gridDim.x * 256)
    atomicAdd(&cnt[dst[i]], 1);
}

__global__ __launch_bounds__(256) void k_scan1(
    const int* __restrict__ in, int* __restrict__ out, int* __restrict__ bsum, int n)
{
  __shared__ int wtot[4];
  int tid = threadIdx.x, lane = tid & 63, wid = tid >> 6;
  int base = blockIdx.x * 1024 + tid * 4;
  int v[4];
#pragma unroll
  for (int k = 0; k < 4; ++k) v[k] = (base + k < n) ? in[base + k] : 0;
  int tsum = v[0] + v[1] + v[2] + v[3];
  int incl = tsum;
#pragma unroll
  for (int off = 1; off < 64; off <<= 1) {
    int up = __shfl_up(incl, off);
    if (lane >= off) incl += up;
  }
  if (lane == 63) wtot[wid] = incl;
  __syncthreads();
  if (tid == 0) {
    int r = 0;
#pragma unroll
    for (int w2 = 0; w2 < 4; ++w2) { int t = wtot[w2]; wtot[w2] = r; r += t; }
    bsum[blockIdx.x] = r;
  }
  __syncthreads();
  int excl = wtot[wid] + incl - tsum;
#pragma unroll
  for (int k = 0; k < 4; ++k) {
    if (base + k < n) out[base + k] = excl;
    excl += v[k];
  }
}

__global__ __launch_bounds__(256) void k_scan2(int* __restrict__ bsum, int nb, int* __restrict__ total_out)
{
  __shared__ int wtot[4];
  int tid = threadIdx.x, lane = tid & 63, wid = tid >> 6;
  int base = tid * 4;
  int v[4];
#pragma unroll
  for (int k = 0; k < 4; ++k) v[k] = (base + k < nb) ? bsum[base + k] : 0;
  int tsum = v[0] + v[1] + v[2] + v[3];
  int incl = tsum;
#pragma unroll
  for (int off = 1; off < 64; off <<= 1) {
    int up = __shfl_up(incl, off);
    if (lane >= off) incl += up;
  }
  if (lane == 63) wtot[wid] = incl;
  __syncthreads();
  if (tid == 0) {
    int r = 0;
#pragma unroll
    for (int w2 = 0; w2 < 4; ++w2) { int t = wtot[w2]; wtot[w2] = r; r += t; }
    *total_out = r;
  }
  __syncthreads();
  int excl = wtot[wid] + incl - tsum;
#pragma unroll
  for (int k = 0; k < 4; ++k) {
    if (base + k < nb) bsum[base + k] = excl;
    excl += v[k];
  }
}

__global__ __launch_bounds__(256) void k_scan3(
    int* __restrict__ ptr, int* __restrict__ cur, const int* __restrict__ bsum, int n)
{
  for (int i = blockIdx.x * 256 + threadIdx.x; i < n; i += gridDim.x * 256) {
    int v = ptr[i] + bsum[i >> 10];
    ptr[i] = v; cur[i] = v;
  }
}

__global__ __launch_bounds__(256) void k_scatter(
    const int* __restrict__ dst, int* __restrict__ cur, int* __restrict__ perm, int n)
{
  for (int i = blockIdx.x * 256 + threadIdx.x; i < n; i += gridDim.x * 256) {
    int d = dst[i];
    int p = atomicAdd(&cur[d], 1);
    perm[p] = i;
  }
}

// ---- weight prep: W[k][j] fp32 -> Wt[j][k] bf16 ----
__global__ __launch_bounds__(256) void k_wt(
    const float* __restrict__ W, unsigned short* __restrict__ Wt, int K, int NO)
{
  int idx = blockIdx.x * 256 + threadIdx.x;
  if (idx >= K * NO) return;
  int k = idx / NO, j = idx - k * NO;
  Wt[(size_t)j * K + k] = f2bf(W[idx]);
}

extern "C" void kernel_launch(void* const* d_in, const int* in_sizes, int n_in,
                              void* d_out, int out_size, void* d_ws, size_t ws_size,
                              hipStream_t stream)
{
  const float* x0    = (const float*)d_in[0];
  const float* e0    = (const float*)d_in[1];
  const float* a0    = (const float*)d_in[2];
  const float* W_ne  = (const float*)d_in[3];
  const float* b_ne  = (const float*)d_in[4];
  const float* g_e   = (const float*)d_in[5];
  const float* be_e  = (const float*)d_in[6];
  const float* W_ea  = (const float*)d_in[7];
  const float* b_ea  = (const float*)d_in[8];
  const float* g_a   = (const float*)d_in[9];
  const float* be_a  = (const float*)d_in[10];
  const float* W_emp = (const float*)d_in[11];
  const float* b_emp = (const float*)d_in[12];
  const float* g_emp = (const float*)d_in[13];
  const float* be_emp= (const float*)d_in[14];
  const float* W_nmp = (const float*)d_in[15];
  const float* b_nmp = (const float*)d_in[16];
  const float* g_nmp = (const float*)d_in[17];
  const float* be_nmp= (const float*)d_in[18];
  const int* node_batch  = (const int*)d_in[19];
  const int* edge_index  = (const int*)d_in[20];
  const int* edge_batch  = (const int*)d_in[21];
  const int* tb_index    = (const int*)d_in[22];
  const int* angle_batch = (const int*)d_in[23];

  const int N = in_sizes[0] / 128;
  const int E = in_sizes[1] / 64;
  const int A = in_sizes[2] / 64;

  // ---- workspace layout (bytes, 256-aligned) ----
  char* wsp = (char*)d_ws;
  auto alloc = [&](size_t bytes) { char* p = wsp; wsp += (bytes + 255) & ~(size_t)255; return p; };
  float*          eA     = (float*)alloc((size_t)E * 64 * 4);
  float*          aA     = (float*)alloc((size_t)A * 64 * 4);
  unsigned short* msg    = (unsigned short*)alloc((size_t)A * 64 * 2);  // pe / msg_e / msg_n share
  int* ptr_n  = (int*)alloc((size_t)(N + 1) * 4);
  int* cur_n  = (int*)alloc((size_t)N * 4);
  int* perm_n = (int*)alloc((size_t)E * 4);
  int* ptr_e  = (int*)alloc((size_t)(E + 1) * 4);
  int* cur_e  = (int*)alloc((size_t)E * 4);
  int* perm_e = (int*)alloc((size_t)A * 4);
  int* bsum   = (int*)alloc(4096 * 4);
  // stats: ONE contiguous block (memset correctness depends on adjacency)
  float* stats = (float*)alloc(5 * NG * 4);
  float* s1    = stats;
  float* s2    = stats + NG;
  float* cnt_n = stats + 2 * NG;
  float* cnt_e = stats + 3 * NG;
  float* cnt_a = stats + 4 * NG;
  float* afE_idA = (float*)alloc(1024 * 4); float* afE_idB = (float*)alloc(1024 * 4);
  float* afA_idA = (float*)alloc(1024 * 4); float* afA_idB = (float*)alloc(1024 * 4);
  float* afE1A   = (float*)alloc(1024 * 4); float* afE1B   = (float*)alloc(1024 * 4);
  float* afE2A   = (float*)alloc(1024 * 4); float* afE2B   = (float*)alloc(1024 * 4);
  float* afA1A   = (float*)alloc(1024 * 4); float* afA1B   = (float*)alloc(1024 * 4);
  float* afXA    = (float*)alloc(2048 * 4); float* afXB    = (float*)alloc(2048 * 4);
  unsigned short* wt_ne  = (unsigned short*)alloc((size_t)2 * 320 * 64 * 2);
  unsigned short* wt_ea  = (unsigned short*)alloc((size_t)2 * 192 * 64 * 2);
  unsigned short* wt_emp = (unsigned short*)alloc((size_t)2 * 192 * 64 * 2);
  unsigned short* wt_nmp = (unsigned short*)alloc((size_t)2 * 320 * 128 * 2);
  // pn allocated LAST; adaptive: only used if it fits in the workspace.
  unsigned short* pn     = (unsigned short*)alloc((size_t)E * 128 * 2);
  bool usePN = ((size_t)(wsp - (char*)d_ws) <= ws_size);

  float* x_out = (float*)d_out;

  // ---- one-time prep ----
  for (int i = 0; i < 2; ++i) {
    k_wt<<<(320*64 + 255)/256, 256, 0, stream>>>(W_ne  + (size_t)i*320*64,  wt_ne  + (size_t)i*320*64,  320, 64);
    k_wt<<<(192*64 + 255)/256, 256, 0, stream>>>(W_ea  + (size_t)i*192*64,  wt_ea  + (size_t)i*192*64,  192, 64);
    k_wt<<<(192*64 + 255)/256, 256, 0, stream>>>(W_emp + (size_t)i*192*64,  wt_emp + (size_t)i*192*64,  192, 64);
    k_wt<<<(320*128 + 255)/256, 256, 0, stream>>>(W_nmp + (size_t)i*320*128, wt_nmp + (size_t)i*320*128, 320, 128);
  }
  hipMemsetAsync(stats, 0, 5 * NG * 4, stream);
  k_count<<<512, 256, 0, stream>>>(node_batch, N, cnt_n);
  k_count<<<512, 256, 0, stream>>>(edge_batch, E, cnt_e);
  k_count<<<512, 256, 0, stream>>>(angle_batch, A, cnt_a);
  k_idaff<<<4, 256, 0, stream>>>(afE_idA, afE_idB, 1024);
  k_idaff<<<4, 256, 0, stream>>>(afA_idA, afA_idB, 1024);

  // CSR over nodes (dst of edge_index) and over edges (dst of threebody)
  hipMemsetAsync(cur_n, 0, (size_t)N * 4, stream);
  hipMemsetAsync(cur_e, 0, (size_t)E * 4, stream);
  k_hist<<<1024, 256, 0, stream>>>(edge_index + E, E, cur_n);
  k_hist<<<1024, 256, 0, stream>>>(tb_index + A, A, cur_e);
  int nbN = (N + 1023) / 1024, nbE = (E + 1023) / 1024;
  k_scan1<<<nbN, 256, 0, stream>>>(cur_n, ptr_n, bsum, N);
  k_scan2<<<1, 256, 0, stream>>>(bsum, nbN, ptr_n + N);
  k_scan3<<<1024, 256, 0, stream>>>(ptr_n, cur_n, bsum, N);
  k_scatter<<<1024, 256, 0, stream>>>(edge_index + E, cur_n, perm_n, E);
  k_scan1<<<nbE, 256, 0, stream>>>(cur_e, ptr_e, bsum, E);
  k_scan2<<<1, 256, 0, stream>>>(bsum, nbE, ptr_e + E);
  k_scan3<<<1024, 256, 0, stream>>>(ptr_e, cur_e, bsum, E);
  k_scatter<<<1024, 256, 0, stream>>>(tb_index + A, cur_e, perm_e, A);

  const float* x_cur = x0;
  int blkE = (E / 16 + 3) / 4;   // 4 waves/block
  int blkA = (A / 16 + 3) / 4;

  for (int i = 0; i < 2; ++i) {
    const float* e_in  = (i == 0) ? e0 : eA;
    const float* a_in  = (i == 0) ? a0 : aA;
    const float* fEinA = (i == 0) ? afE_idA : afE2A;
    const float* fEinB = (i == 0) ? afE_idB : afE2B;
    const float* fAinA = (i == 0) ? afA_idA : afA1A;
    const float* fAinB = (i == 0) ? afA_idB : afA1B;

    // 1. edge update + nmp partial (shares x gathers) -> affE1
    hipMemsetAsync(s1, 0, 2 * NG * 4, stream);
    if (usePN)
      k_fused_edge<true><<<blkE, 256, 0, stream>>>(x_cur, e_in, eA, edge_index, edge_batch,
                                                   wt_ne + (size_t)i*320*64, wt_nmp + (size_t)i*320*128,
                                                   b_ne + i*64, fEinA, fEinB, s1, s2, pn, E);
    else
      k_fused_edge<false><<<blkE, 256, 0, stream>>>(x_cur, e_in, eA, edge_index, edge_batch,
                                                    wt_ne + (size_t)i*320*64, wt_nmp + (size_t)i*320*128,
                                                    b_ne + i*64, fEinA, fEinB, s1, s2, msg, E);
    k_mkaff<<<4, 256, 0, stream>>>(s1, s2, cnt_e, 64, g_e + i*64, be_e + i*64, afE1A, afE1B);

    // 2. angle update + emp partial (shares e gathers) -> affA1, pe->msg
    hipMemsetAsync(s1, 0, 2 * NG * 4, stream);
    k_fused_angle<<<blkA, 256, 0, stream>>>(eA, a_in, aA, tb_index, edge_batch, angle_batch,
                                            wt_ea + (size_t)i*192*64, wt_emp + (size_t)i*192*64,
                                            b_ea + i*64, afE1A, afE1B, fAinA, fAinB, s1, s2,
                                            msg, A);
    k_mkaff<<<4, 256, 0, stream>>>(s1, s2, cnt_a, 64, g_a + i*64, be_a + i*64, afA1A, afA1B);

    // 3. emp finish (stream) -> msg; CSR reduce -> affE2
    k_fin_emp<<<blkA, 256, 0, stream>>>(aA, angle_batch, wt_emp + (size_t)i*192*64,
                                        b_emp + i*64, afA1A, afA1B, msg, A);
    hipMemsetAsync(s1, 0, 2 * NG * 4, stream);
    k_red_e<<<2048, 256, 0, stream>>>(msg, eA, eA, ptr_e, perm_e, edge_batch,
                                      afE1A, afE1B, s1, s2, E);
    k_mkaff<<<4, 256, 0, stream>>>(s1, s2, cnt_e, 64, g_emp + i*64, be_emp + i*64, afE2A, afE2B);

    // 4. nmp finish (stream if PN, else gather fallback) -> msg; CSR reduce; apply
    if (usePN)
      k_fin_nmp<<<blkE, 256, 0, stream>>>(eA, edge_batch, wt_nmp + (size_t)i*320*128,
                                          b_nmp + i*128, afE2A, afE2B, pn, msg, E);
    else
      k_mm_nmp<<<blkE, 256, 0, stream>>>(x_cur, eA, edge_index, edge_batch,
                                         wt_nmp + (size_t)i*320*128, b_nmp + i*128,
                                         afE2A, afE2B, msg, E);
    hipMemsetAsync(s1, 0, 2 * NG * 4, stream);
    k_red_n<<<2048, 256, 0, stream>>>(msg, x_cur, x_out, ptr_n, perm_n, node_batch,
                                      s1, s2, N);
    k_mkaff<<<8, 256, 0, stream>>>(s1, s2, cnt_n, 128, g_nmp + i*128, be_nmp + i*128, afXA, afXB);
    k_apply<<<2048, 256, 0, stream>>>(x_out, node_batch, afXA, afXB, (long)N * 128);

    x_cur = x_out;
  }
}

// Round 5
// 2073.886 us; speedup vs baseline: 1.1222x; 1.1222x over previous
//
#include <hip/hip_runtime.h>

typedef __attribute__((ext_vector_type(8))) short bf16x8_t;
typedef __attribute__((ext_vector_type(4))) float f32x4_t;

constexpr int NG = 16;
constexpr float EPS = 1e-5f;

__device__ inline unsigned short f2bf(float f) {
  unsigned u = __builtin_bit_cast(unsigned, f);
  u += 0x7FFFu + ((u >> 16) & 1u);
  return (unsigned short)(u >> 16);
}
__device__ inline float bf2f(unsigned short u) {
  unsigned x = ((unsigned)u) << 16;
  return __builtin_bit_cast(float, x);
}

// =====================================================================
// EDGE update MM: e_out = affEin(e_in) + [x_s|x_d|affEin(e_in)]@W_ne + b
// x gathered from pre-converted bf16 table xB (no affine, no cvt).
// Fused per-graph stats. e_in/e_out alias-safe (wave owns its 16 rows).
// =====================================================================
__global__ __launch_bounds__(256) void k_mm_edge(
    const unsigned short* __restrict__ xB, const float* e_in, float* e_out,
    const int* __restrict__ ei, const int* __restrict__ ebatch,
    const unsigned short* __restrict__ Wt, const float* __restrict__ bias,
    const float* __restrict__ afA, const float* __restrict__ afB,
    float* __restrict__ gs1, float* __restrict__ gs2, int nE)
{
  __shared__ float lA[1024], lB[1024];
  __shared__ float ls1[NG], ls2[NG];
  for (int i = threadIdx.x; i < 1024; i += 256) { lA[i] = afA[i]; lB[i] = afB[i]; }
  if (threadIdx.x < NG) { ls1[threadIdx.x] = 0.f; ls2[threadIdx.x] = 0.f; }
  __syncthreads();
  int gw = (int)((blockIdx.x * 256u + threadIdx.x) >> 6);
  int ntile = nE >> 4;
  bool act = gw < ntile;
  int lane = threadIdx.x & 63;
  int colb = lane & 15;
  int ko = (lane >> 4) << 3;
  int rowb = (lane >> 4) << 2;
  float sr[4] = {0.f,0.f,0.f,0.f}, ssr[4] = {0.f,0.f,0.f,0.f};
  if (act) {
    int row = (gw << 4) + colb;
    int s = ei[row], d = ei[nE + row];
    int ge = ebatch[row];
    const unsigned short* xs = xB + (size_t)s * 128;
    const unsigned short* xd = xB + (size_t)d * 128;
    const float* er = e_in + (size_t)row * 64;
    f32x4_t acc[4] = {};
#pragma unroll
    for (int c = 0; c < 10; ++c) {
      bf16x8_t a;
      if (c < 8) {
        const unsigned short* bp = (c < 4) ? xs + c * 32 : xd + (c - 4) * 32;
        a = *(const bf16x8_t*)(bp + ko);
      } else {
        int fb = (c - 8) * 32 + ko;
        float4 f0 = *(const float4*)(er + fb);
        float4 f1 = *(const float4*)(er + fb + 4);
        float vv[8] = {f0.x,f0.y,f0.z,f0.w,f1.x,f1.y,f1.z,f1.w};
#pragma unroll
        for (int k = 0; k < 8; ++k) a[k] = (short)f2bf(vv[k] * lA[ge*64 + fb + k] + lB[ge*64 + fb + k]);
      }
#pragma unroll
      for (int nb = 0; nb < 4; ++nb) {
        bf16x8_t b = *(const bf16x8_t*)(Wt + (size_t)(nb * 16 + colb) * 320 + c * 32 + ko);
        acc[nb] = __builtin_amdgcn_mfma_f32_16x16x32_bf16(a, b, acc[nb], 0, 0, 0);
      }
    }
#pragma unroll
    for (int r = 0; r < 4; ++r) {
      int e_ = (gw << 4) + rowb + r;
      int gr = ebatch[e_];
#pragma unroll
      for (int nb = 0; nb < 4; ++nb) {
        int col = nb * 16 + colb;
        size_t off = (size_t)e_ * 64 + col;
        float vv = e_in[off] * lA[gr*64 + col] + lB[gr*64 + col] + bias[col] + acc[nb][r];
        e_out[off] = vv;
        sr[r] += vv; ssr[r] += vv * vv;
      }
    }
  }
#pragma unroll
  for (int m = 1; m <= 8; m <<= 1)
#pragma unroll
    for (int r = 0; r < 4; ++r) { sr[r] += __shfl_xor(sr[r], m); ssr[r] += __shfl_xor(ssr[r], m); }
  if (act && colb == 0) {
#pragma unroll
    for (int r = 0; r < 4; ++r) {
      int g = ebatch[(gw << 4) + rowb + r];
      atomicAdd(&ls1[g], sr[r]); atomicAdd(&ls2[g], ssr[r]);
    }
  }
  __syncthreads();
  if (threadIdx.x < NG) {
    atomicAdd(&gs1[threadIdx.x], ls1[threadIdx.x]);
    atomicAdd(&gs2[threadIdx.x], ls2[threadIdx.x]);
  }
}

// =====================================================================
// ANGLE update MM: a_out = affAin(a_in) + [eB1_s|eB1_d|affAin(a_in)]@W_ea + b
// e gathered from pre-normalized bf16 table eB1 (no affine, no batch lookup).
// =====================================================================
__global__ __launch_bounds__(256) void k_mm_angle(
    const unsigned short* __restrict__ eB1, const float* a_in, float* a_out,
    const int* __restrict__ ti, const int* __restrict__ abatch,
    const unsigned short* __restrict__ Wt, const float* __restrict__ bias,
    const float* __restrict__ afAA, const float* __restrict__ afAB,
    float* __restrict__ gs1, float* __restrict__ gs2, int nA)
{
  __shared__ float lAA[1024], lAB[1024];
  __shared__ float ls1[NG], ls2[NG];
  for (int i = threadIdx.x; i < 1024; i += 256) { lAA[i] = afAA[i]; lAB[i] = afAB[i]; }
  if (threadIdx.x < NG) { ls1[threadIdx.x] = 0.f; ls2[threadIdx.x] = 0.f; }
  __syncthreads();
  int gw = (int)((blockIdx.x * 256u + threadIdx.x) >> 6);
  int ntile = nA >> 4;
  bool act = gw < ntile;
  int lane = threadIdx.x & 63;
  int colb = lane & 15;
  int ko = (lane >> 4) << 3;
  int rowb = (lane >> 4) << 2;
  float sr[4] = {0.f,0.f,0.f,0.f}, ssr[4] = {0.f,0.f,0.f,0.f};
  if (act) {
    int row = (gw << 4) + colb;
    int s = ti[row], d = ti[nA + row];
    int ga = abatch[row];
    const unsigned short* es = eB1 + (size_t)s * 64;
    const unsigned short* ed = eB1 + (size_t)d * 64;
    const float* ar = a_in + (size_t)row * 64;
    f32x4_t acc[4] = {};
#pragma unroll
    for (int c = 0; c < 6; ++c) {
      bf16x8_t a;
      if (c < 4) {
        const unsigned short* bp = (c < 2) ? es + c * 32 : ed + (c - 2) * 32;
        a = *(const bf16x8_t*)(bp + ko);
      } else {
        int fb = (c - 4) * 32 + ko;
        float4 f0 = *(const float4*)(ar + fb);
        float4 f1 = *(const float4*)(ar + fb + 4);
        float vv[8] = {f0.x,f0.y,f0.z,f0.w,f1.x,f1.y,f1.z,f1.w};
#pragma unroll
        for (int k = 0; k < 8; ++k) a[k] = (short)f2bf(vv[k] * lAA[ga*64 + fb + k] + lAB[ga*64 + fb + k]);
      }
#pragma unroll
      for (int nb = 0; nb < 4; ++nb) {
        bf16x8_t b = *(const bf16x8_t*)(Wt + (size_t)(nb * 16 + colb) * 192 + c * 32 + ko);
        acc[nb] = __builtin_amdgcn_mfma_f32_16x16x32_bf16(a, b, acc[nb], 0, 0, 0);
      }
    }
#pragma unroll
    for (int r = 0; r < 4; ++r) {
      int a_ = (gw << 4) + rowb + r;
      int gr = abatch[a_];
#pragma unroll
      for (int nb = 0; nb < 4; ++nb) {
        int col = nb * 16 + colb;
        size_t off = (size_t)a_ * 64 + col;
        float vv = a_in[off] * lAA[gr*64 + col] + lAB[gr*64 + col] + bias[col] + acc[nb][r];
        a_out[off] = vv;
        sr[r] += vv; ssr[r] += vv * vv;
      }
    }
  }
#pragma unroll
  for (int m = 1; m <= 8; m <<= 1)
#pragma unroll
    for (int r = 0; r < 4; ++r) { sr[r] += __shfl_xor(sr[r], m); ssr[r] += __shfl_xor(ssr[r], m); }
  if (act && colb == 0) {
#pragma unroll
    for (int r = 0; r < 4; ++r) {
      int g = abatch[(gw << 4) + rowb + r];
      atomicAdd(&ls1[g], sr[r]); atomicAdd(&ls2[g], ssr[r]);
    }
  }
  __syncthreads();
  if (threadIdx.x < NG) {
    atomicAdd(&gs1[threadIdx.x], ls1[threadIdx.x]);
    atomicAdd(&gs2[threadIdx.x], ls2[threadIdx.x]);
  }
}

// =====================================================================
// edge_graph_mp message MM: msg = relu([eB1_s|eB1_d|affA1(a)]@W_emp + b)
// -> bf16 msg[A][64], coalesced stores, no atomics, no batch lookups on gathers.
// =====================================================================
__global__ __launch_bounds__(256) void k_mm_emp(
    const unsigned short* __restrict__ eB1, const float* __restrict__ a_,
    const int* __restrict__ ti, const int* __restrict__ abatch,
    const unsigned short* __restrict__ Wt, const float* __restrict__ bias,
    const float* __restrict__ afAA, const float* __restrict__ afAB,
    unsigned short* __restrict__ msg, int nA)
{
  __shared__ float lAA[1024], lAB[1024];
  for (int i = threadIdx.x; i < 1024; i += 256) { lAA[i] = afAA[i]; lAB[i] = afAB[i]; }
  __syncthreads();
  int gw = (int)((blockIdx.x * 256u + threadIdx.x) >> 6);
  int ntile = nA >> 4;
  if (gw >= ntile) return;
  int lane = threadIdx.x & 63;
  int colb = lane & 15;
  int ko = (lane >> 4) << 3;
  int rowb = (lane >> 4) << 2;
  int row = (gw << 4) + colb;
  int s = ti[row], d = ti[nA + row];
  int ga = abatch[row];
  const unsigned short* es = eB1 + (size_t)s * 64;
  const unsigned short* ed = eB1 + (size_t)d * 64;
  const float* ar = a_ + (size_t)row * 64;
  f32x4_t acc[4] = {};
#pragma unroll
  for (int c = 0; c < 6; ++c) {
    bf16x8_t a;
    if (c < 4) {
      const unsigned short* bp = (c < 2) ? es + c * 32 : ed + (c - 2) * 32;
      a = *(const bf16x8_t*)(bp + ko);
    } else {
      int fb = (c - 4) * 32 + ko;
      float4 f0 = *(const float4*)(ar + fb);
      float4 f1 = *(const float4*)(ar + fb + 4);
      float vv[8] = {f0.x,f0.y,f0.z,f0.w,f1.x,f1.y,f1.z,f1.w};
#pragma unroll
      for (int k = 0; k < 8; ++k) a[k] = (short)f2bf(vv[k] * lAA[ga*64 + fb + k] + lAB[ga*64 + fb + k]);
    }
#pragma unroll
    for (int nb = 0; nb < 4; ++nb) {
      bf16x8_t b = *(const bf16x8_t*)(Wt + (size_t)(nb * 16 + colb) * 192 + c * 32 + ko);
      acc[nb] = __builtin_amdgcn_mfma_f32_16x16x32_bf16(a, b, acc[nb], 0, 0, 0);
    }
  }
#pragma unroll
  for (int r = 0; r < 4; ++r) {
    int a_idx = (gw << 4) + rowb + r;
#pragma unroll
    for (int nb = 0; nb < 4; ++nb) {
      int col = nb * 16 + colb;
      float v = fmaxf(acc[nb][r] + bias[col], 0.f);
      msg[(size_t)a_idx * 64 + col] = f2bf(v);
    }
  }
}

// =====================================================================
// node_graph_mp message MM: msg = relu([xB_s|xB_d|affE2(e)]@W_nmp + b) -> bf16 msg[E][128]
// =====================================================================
__global__ __launch_bounds__(256) void k_mm_nmp(
    const unsigned short* __restrict__ xB, const float* __restrict__ e,
    const int* __restrict__ ei, const int* __restrict__ ebatch,
    const unsigned short* __restrict__ Wt, const float* __restrict__ bias,
    const float* __restrict__ afEA, const float* __restrict__ afEB,
    unsigned short* __restrict__ msg, int nE)
{
  __shared__ float lA[1024], lB[1024];
  for (int i = threadIdx.x; i < 1024; i += 256) { lA[i] = afEA[i]; lB[i] = afEB[i]; }
  __syncthreads();
  int gw = (int)((blockIdx.x * 256u + threadIdx.x) >> 6);
  int ntile = nE >> 4;
  if (gw >= ntile) return;
  int lane = threadIdx.x & 63;
  int colb = lane & 15;
  int ko = (lane >> 4) << 3;
  int rowb = (lane >> 4) << 2;
  int row = (gw << 4) + colb;
  int s = ei[row], d = ei[nE + row];
  int ge = ebatch[row];
  const unsigned short* xs = xB + (size_t)s * 128;
  const unsigned short* xd = xB + (size_t)d * 128;
  const float* er = e + (size_t)row * 64;
  f32x4_t acc[8] = {};
#pragma unroll
  for (int c = 0; c < 10; ++c) {
    bf16x8_t a;
    if (c < 8) {
      const unsigned short* bp = (c < 4) ? xs + c * 32 : xd + (c - 4) * 32;
      a = *(const bf16x8_t*)(bp + ko);
    } else {
      int fb = (c - 8) * 32 + ko;
      float4 f0 = *(const float4*)(er + fb);
      float4 f1 = *(const float4*)(er + fb + 4);
      float vv[8] = {f0.x,f0.y,f0.z,f0.w,f1.x,f1.y,f1.z,f1.w};
#pragma unroll
      for (int k = 0; k < 8; ++k) a[k] = (short)f2bf(vv[k] * lA[ge*64 + fb + k] + lB[ge*64 + fb + k]);
    }
#pragma unroll
    for (int nb = 0; nb < 8; ++nb) {
      bf16x8_t b = *(const bf16x8_t*)(Wt + (size_t)(nb * 16 + colb) * 320 + c * 32 + ko);
      acc[nb] = __builtin_amdgcn_mfma_f32_16x16x32_bf16(a, b, acc[nb], 0, 0, 0);
    }
  }
#pragma unroll
  for (int r = 0; r < 4; ++r) {
    int e_ = (gw << 4) + rowb + r;
#pragma unroll
    for (int nb = 0; nb < 8; ++nb) {
      int col = nb * 16 + colb;
      float v = fmaxf(acc[nb][r] + bias[col], 0.f);
      msg[(size_t)e_ * 128 + col] = f2bf(v);
    }
  }
}

// =====================================================================
// CSR gather-reduce over edges: e2 = affE1(e1) + sum(msg rows); fused stats.
// =====================================================================
__global__ __launch_bounds__(256) void k_red_e(
    const unsigned short* __restrict__ msg, const float* e_in, float* e_out,
    const int* __restrict__ ptr, const int* __restrict__ perm,
    const int* __restrict__ ebatch,
    const float* __restrict__ afA, const float* __restrict__ afB,
    float* __restrict__ gs1, float* __restrict__ gs2, int nE)
{
  __shared__ float lA[1024], lB[1024], ls1[NG], ls2[NG];
  for (int i = threadIdx.x; i < 1024; i += 256) { lA[i] = afA[i]; lB[i] = afB[i]; }
  if (threadIdx.x < NG) { ls1[threadIdx.x] = 0.f; ls2[threadIdx.x] = 0.f; }
  __syncthreads();
  int lane = threadIdx.x & 63;
  int wv = (int)((blockIdx.x * 256u + threadIdx.x) >> 6);
  int nw = (int)((gridDim.x * 256u) >> 6);
  for (int eidx = wv; eidx < nE; eidx += nw) {
    int p0 = ptr[eidx], p1 = ptr[eidx + 1];
    float sum = 0.f;
    for (int j = p0; j < p1; ++j) {
      int aidx = perm[j];
      sum += bf2f(msg[(size_t)aidx * 64 + lane]);
    }
    int g = ebatch[eidx];
    size_t off = (size_t)eidx * 64 + lane;
    float v = e_in[off] * lA[g*64 + lane] + lB[g*64 + lane] + sum;
    e_out[off] = v;
    float s = v, ss = v * v;
#pragma unroll
    for (int m = 1; m < 64; m <<= 1) { s += __shfl_xor(s, m); ss += __shfl_xor(ss, m); }
    if (lane == 0) { atomicAdd(&ls1[g], s); atomicAdd(&ls2[g], ss); }
  }
  __syncthreads();
  if (threadIdx.x < NG) {
    atomicAdd(&gs1[threadIdx.x], ls1[threadIdx.x]);
    atomicAdd(&gs2[threadIdx.x], ls2[threadIdx.x]);
  }
}

// =====================================================================
// CSR gather-reduce over nodes: h = x + sum(msg rows); fused stats.
// =====================================================================
__global__ __launch_bounds__(256) void k_red_n(
    const unsigned short* __restrict__ msg, const float* x_in, float* out,
    const int* __restrict__ ptr, const int* __restrict__ perm,
    const int* __restrict__ nbatch,
    float* __restrict__ gs1, float* __restrict__ gs2, int nN)
{
  __shared__ float ls1[NG], ls2[NG];
  if (threadIdx.x < NG) { ls1[threadIdx.x] = 0.f; ls2[threadIdx.x] = 0.f; }
  __syncthreads();
  int lane = threadIdx.x & 63;
  int wv = (int)((blockIdx.x * 256u + threadIdx.x) >> 6);
  int nw = (int)((gridDim.x * 256u) >> 6);
  for (int n = wv; n < nN; n += nw) {
    int p0 = ptr[n], p1 = ptr[n + 1];
    float s0 = 0.f, s1v = 0.f;
    for (int j = p0; j < p1; ++j) {
      int e = perm[j];
      unsigned u = *(const unsigned*)(msg + (size_t)e * 128 + lane * 2);
      s0 += bf2f((unsigned short)(u & 0xffffu));
      s1v += bf2f((unsigned short)(u >> 16));
    }
    size_t off = (size_t)n * 128 + lane * 2;
    float h0 = x_in[off] + s0, h1 = x_in[off + 1] + s1v;
    out[off] = h0; out[off + 1] = h1;
    float s = h0 + h1, ss = h0 * h0 + h1 * h1;
#pragma unroll
    for (int m = 1; m < 64; m <<= 1) { s += __shfl_xor(s, m); ss += __shfl_xor(ss, m); }
    if (lane == 0) { int g = nbatch[n]; atomicAdd(&ls1[g], s); atomicAdd(&ls2[g], ss); }
  }
  __syncthreads();
  if (threadIdx.x < NG) {
    atomicAdd(&gs1[threadIdx.x], ls1[threadIdx.x]);
    atomicAdd(&gs2[threadIdx.x], ls2[threadIdx.x]);
  }
}

// ---- affine table construction: A=inv*w[f], B=b[f]-m*inv*w[f] ----
__global__ __launch_bounds__(256) void k_mkaff(
    const float* __restrict__ s1, const float* __restrict__ s2,
    const float* __restrict__ cnt, int F,
    const float* __restrict__ w, const float* __restrict__ b,
    float* __restrict__ A, float* __restrict__ B)
{
  int idx = blockIdx.x * 256 + threadIdx.x;
  if (idx >= NG * F) return;
  int g = idx / F, f = idx - g * F;
  float norm = fmaxf(cnt[g], 1.f) * (float)F;
  float m = s1[g] / norm;
  float var = s2[g] / norm - m * m;
  float inv = rsqrtf(var + EPS);
  float a = inv * w[f];
  A[idx] = a;
  B[idx] = b[f] - m * a;
}

__global__ __launch_bounds__(256) void k_idaff(float* __restrict__ A, float* __restrict__ B, int n)
{
  int idx = blockIdx.x * 256 + threadIdx.x;
  if (idx < n) { A[idx] = 1.f; B[idx] = 0.f; }
}

// ---- stream: eB1 = bf16(affE1(eA))  (gather table for angle/emp stages) ----
__global__ __launch_bounds__(256) void k_norm_ebf(
    const float* __restrict__ e, const int* __restrict__ ebatch,
    const float* __restrict__ afA, const float* __restrict__ afB,
    unsigned short* __restrict__ eB, int nE)
{
  int total = nE * 8;                       // 8 threads per 64-wide row
  int stride = gridDim.x * 256;
  for (int idx = blockIdx.x * 256 + threadIdx.x; idx < total; idx += stride) {
    int row = idx >> 3, q = (idx & 7) * 8;
    int g = ebatch[row];
    const float* er = e + (size_t)row * 64 + q;
    float4 f0 = *(const float4*)er;
    float4 f1 = *(const float4*)(er + 4);
    float vv[8] = {f0.x,f0.y,f0.z,f0.w,f1.x,f1.y,f1.z,f1.w};
    bf16x8_t o;
#pragma unroll
    for (int k = 0; k < 8; ++k) o[k] = (short)f2bf(vv[k] * afA[g*64 + q + k] + afB[g*64 + q + k]);
    *(bf16x8_t*)(eB + (size_t)row * 64 + q) = o;
  }
}

// ---- stream: xB = bf16(x) (layer-0 raw input convert) ----
__global__ __launch_bounds__(256) void k_cvt_x(
    const float* __restrict__ x, unsigned short* __restrict__ xB, long total8)
{
  long stride = (long)gridDim.x * 256;
  for (long idx = (long)blockIdx.x * 256 + threadIdx.x; idx < total8; idx += stride) {
    const float* p = x + idx * 8;
    float4 f0 = *(const float4*)p;
    float4 f1 = *(const float4*)(p + 4);
    float vv[8] = {f0.x,f0.y,f0.z,f0.w,f1.x,f1.y,f1.z,f1.w};
    bf16x8_t o;
#pragma unroll
    for (int k = 0; k < 8; ++k) o[k] = (short)f2bf(vv[k]);
    *(bf16x8_t*)(xB + idx * 8) = o;
  }
}

// ---- apply norm to x (in-place) + emit bf16 gather table for next layer ----
__global__ __launch_bounds__(256) void k_apply(
    float* h, const int* __restrict__ batch,
    const float* __restrict__ A, const float* __restrict__ B,
    unsigned short* __restrict__ xB, int nN)
{
  int total = nN * 16;                      // 16 threads per 128-wide row
  int stride = gridDim.x * 256;
  for (int idx = blockIdx.x * 256 + threadIdx.x; idx < total; idx += stride) {
    int row = idx >> 4, q = (idx & 15) * 8;
    int g = batch[row];
    float* hp = h + (size_t)row * 128 + q;
    float4 f0 = *(const float4*)hp;
    float4 f1 = *(const float4*)(hp + 4);
    float vv[8] = {f0.x,f0.y,f0.z,f0.w,f1.x,f1.y,f1.z,f1.w};
    bf16x8_t o;
#pragma unroll
    for (int k = 0; k < 8; ++k) {
      vv[k] = vv[k] * A[(g << 7) + q + k] + B[(g << 7) + q + k];
      o[k] = (short)f2bf(vv[k]);
    }
    float4 g0 = {vv[0],vv[1],vv[2],vv[3]}, g1 = {vv[4],vv[5],vv[6],vv[7]};
    *(float4*)hp = g0;
    *(float4*)(hp + 4) = g1;
    *(bf16x8_t*)(xB + (size_t)row * 128 + q) = o;
  }
}

__global__ __launch_bounds__(256) void k_count(
    const int* __restrict__ batch, int n, float* __restrict__ cnt)
{
  __shared__ float lc[NG];
  if (threadIdx.x < NG) lc[threadIdx.x] = 0.f;
  __syncthreads();
  for (int i = blockIdx.x * 256 + threadIdx.x; i < n; i += gridDim.x * 256)
    atomicAdd(&lc[batch[i]], 1.f);
  __syncthreads();
  if (threadIdx.x < NG) atomicAdd(&cnt[threadIdx.x], lc[threadIdx.x]);
}

// ---- CSR build: histogram, 3-kernel scan, scatter ----
__global__ __launch_bounds__(256) void k_hist(
    const int* __restrict__ dst, int n, int* __restrict__ cnt)
{
  for (int i = blockIdx.x * 256 + threadIdx.x; i < n; i += gridDim.x * 256)
    atomicAdd(&cnt[dst[i]], 1);
}

__global__ __launch_bounds__(256) void k_scan1(
    const int* __restrict__ in, int* __restrict__ out, int* __restrict__ bsum, int n)
{
  __shared__ int wtot[4];
  int tid = threadIdx.x, lane = tid & 63, wid = tid >> 6;
  int base = blockIdx.x * 1024 + tid * 4;
  int v[4];
#pragma unroll
  for (int k = 0; k < 4; ++k) v[k] = (base + k < n) ? in[base + k] : 0;
  int tsum = v[0] + v[1] + v[2] + v[3];
  int incl = tsum;
#pragma unroll
  for (int off = 1; off < 64; off <<= 1) {
    int up = __shfl_up(incl, off);
    if (lane >= off) incl += up;
  }
  if (lane == 63) wtot[wid] = incl;
  __syncthreads();
  if (tid == 0) {
    int r = 0;
#pragma unroll
    for (int w2 = 0; w2 < 4; ++w2) { int t = wtot[w2]; wtot[w2] = r; r += t; }
    bsum[blockIdx.x] = r;
  }
  __syncthreads();
  int excl = wtot[wid] + incl - tsum;
#pragma unroll
  for (int k = 0; k < 4; ++k) {
    if (base + k < n) out[base + k] = excl;
    excl += v[k];
  }
}

__global__ __launch_bounds__(256) void k_scan2(int* __restrict__ bsum, int nb, int* __restrict__ total_out)
{
  __shared__ int wtot[4];
  int tid = threadIdx.x, lane = tid & 63, wid = tid >> 6;
  int base = tid * 4;
  int v[4];
#pragma unroll
  for (int k = 0; k < 4; ++k) v[k] = (base + k < nb) ? bsum[base + k] : 0;
  int tsum = v[0] + v[1] + v[2] + v[3];
  int incl = tsum;
#pragma unroll
  for (int off = 1; off < 64; off <<= 1) {
    int up = __shfl_up(incl, off);
    if (lane >= off) incl += up;
  }
  if (lane == 63) wtot[wid] = incl;
  __syncthreads();
  if (tid == 0) {
    int r = 0;
#pragma unroll
    for (int w2 = 0; w2 < 4; ++w2) { int t = wtot[w2]; wtot[w2] = r; r += t; }
    *total_out = r;
  }
  __syncthreads();
  int excl = wtot[wid] + incl - tsum;
#pragma unroll
  for (int k = 0; k < 4; ++k) {
    if (base + k < nb) bsum[base + k] = excl;
    excl += v[k];
  }
}

__global__ __launch_bounds__(256) void k_scan3(
    int* __restrict__ ptr, int* __restrict__ cur, const int* __restrict__ bsum, int n)
{
  for (int i = blockIdx.x * 256 + threadIdx.x; i < n; i += gridDim.x * 256) {
    int v = ptr[i] + bsum[i >> 10];
    ptr[i] = v; cur[i] = v;
  }
}

__global__ __launch_bounds__(256) void k_scatter(
    const int* __restrict__ dst, int* __restrict__ cur, int* __restrict__ perm, int n)
{
  for (int i = blockIdx.x * 256 + threadIdx.x; i < n; i += gridDim.x * 256) {
    int d = dst[i];
    int p = atomicAdd(&cur[d], 1);
    perm[p] = i;
  }
}

// ---- weight prep: W[k][j] fp32 -> Wt[j][k] bf16 ----
__global__ __launch_bounds__(256) void k_wt(
    const float* __restrict__ W, unsigned short* __restrict__ Wt, int K, int NO)
{
  int idx = blockIdx.x * 256 + threadIdx.x;
  if (idx >= K * NO) return;
  int k = idx / NO, j = idx - k * NO;
  Wt[(size_t)j * K + k] = f2bf(W[idx]);
}

extern "C" void kernel_launch(void* const* d_in, const int* in_sizes, int n_in,
                              void* d_out, int out_size, void* d_ws, size_t ws_size,
                              hipStream_t stream)
{
  const float* x0    = (const float*)d_in[0];
  const float* e0    = (const float*)d_in[1];
  const float* a0    = (const float*)d_in[2];
  const float* W_ne  = (const float*)d_in[3];
  const float* b_ne  = (const float*)d_in[4];
  const float* g_e   = (const float*)d_in[5];
  const float* be_e  = (const float*)d_in[6];
  const float* W_ea  = (const float*)d_in[7];
  const float* b_ea  = (const float*)d_in[8];
  const float* g_a   = (const float*)d_in[9];
  const float* be_a  = (const float*)d_in[10];
  const float* W_emp = (const float*)d_in[11];
  const float* b_emp = (const float*)d_in[12];
  const float* g_emp = (const float*)d_in[13];
  const float* be_emp= (const float*)d_in[14];
  const float* W_nmp = (const float*)d_in[15];
  const float* b_nmp = (const float*)d_in[16];
  const float* g_nmp = (const float*)d_in[17];
  const float* be_nmp= (const float*)d_in[18];
  const int* node_batch  = (const int*)d_in[19];
  const int* edge_index  = (const int*)d_in[20];
  const int* edge_batch  = (const int*)d_in[21];
  const int* tb_index    = (const int*)d_in[22];
  const int* angle_batch = (const int*)d_in[23];

  const int N = in_sizes[0] / 128;
  const int E = in_sizes[1] / 64;
  const int A = in_sizes[2] / 64;

  // ---- workspace layout (bytes, 256-aligned) ----
  char* wsp = (char*)d_ws;
  auto alloc = [&](size_t bytes) { char* p = wsp; wsp += (bytes + 255) & ~(size_t)255; return p; };
  float*          eA     = (float*)alloc((size_t)E * 64 * 4);
  float*          aA     = (float*)alloc((size_t)A * 64 * 4);
  unsigned short* msg    = (unsigned short*)alloc((size_t)A * 64 * 2);  // pe/msg_e/msg_n share
  unsigned short* xB     = (unsigned short*)alloc((size_t)N * 128 * 2); // bf16 gather table for x
  unsigned short* eB1    = (unsigned short*)alloc((size_t)E * 64 * 2);  // bf16 affE1(e) gather table
  int* ptr_n  = (int*)alloc((size_t)(N + 1) * 4);
  int* cur_n  = (int*)alloc((size_t)N * 4);
  int* perm_n = (int*)alloc((size_t)E * 4);
  int* ptr_e  = (int*)alloc((size_t)(E + 1) * 4);
  int* cur_e  = (int*)alloc((size_t)E * 4);
  int* perm_e = (int*)alloc((size_t)A * 4);
  int* bsum   = (int*)alloc(4096 * 4);
  // stats: ONE contiguous block (memset correctness depends on adjacency)
  float* stats = (float*)alloc(5 * NG * 4);
  float* s1    = stats;
  float* s2    = stats + NG;
  float* cnt_n = stats + 2 * NG;
  float* cnt_e = stats + 3 * NG;
  float* cnt_a = stats + 4 * NG;
  float* afE_idA = (float*)alloc(1024 * 4); float* afE_idB = (float*)alloc(1024 * 4);
  float* afA_idA = (float*)alloc(1024 * 4); float* afA_idB = (float*)alloc(1024 * 4);
  float* afE1A   = (float*)alloc(1024 * 4); float* afE1B   = (float*)alloc(1024 * 4);
  float* afE2A   = (float*)alloc(1024 * 4); float* afE2B   = (float*)alloc(1024 * 4);
  float* afA1A   = (float*)alloc(1024 * 4); float* afA1B   = (float*)alloc(1024 * 4);
  float* afXA    = (float*)alloc(2048 * 4); float* afXB    = (float*)alloc(2048 * 4);
  unsigned short* wt_ne  = (unsigned short*)alloc((size_t)2 * 320 * 64 * 2);
  unsigned short* wt_ea  = (unsigned short*)alloc((size_t)2 * 192 * 64 * 2);
  unsigned short* wt_emp = (unsigned short*)alloc((size_t)2 * 192 * 64 * 2);
  unsigned short* wt_nmp = (unsigned short*)alloc((size_t)2 * 320 * 128 * 2);

  float* x_out = (float*)d_out;

  // ---- one-time prep ----
  for (int i = 0; i < 2; ++i) {
    k_wt<<<(320*64 + 255)/256, 256, 0, stream>>>(W_ne  + (size_t)i*320*64,  wt_ne  + (size_t)i*320*64,  320, 64);
    k_wt<<<(192*64 + 255)/256, 256, 0, stream>>>(W_ea  + (size_t)i*192*64,  wt_ea  + (size_t)i*192*64,  192, 64);
    k_wt<<<(192*64 + 255)/256, 256, 0, stream>>>(W_emp + (size_t)i*192*64,  wt_emp + (size_t)i*192*64,  192, 64);
    k_wt<<<(320*128 + 255)/256, 256, 0, stream>>>(W_nmp + (size_t)i*320*128, wt_nmp + (size_t)i*320*128, 320, 128);
  }
  hipMemsetAsync(stats, 0, 5 * NG * 4, stream);
  k_count<<<512, 256, 0, stream>>>(node_batch, N, cnt_n);
  k_count<<<512, 256, 0, stream>>>(edge_batch, E, cnt_e);
  k_count<<<512, 256, 0, stream>>>(angle_batch, A, cnt_a);
  k_idaff<<<4, 256, 0, stream>>>(afE_idA, afE_idB, 1024);
  k_idaff<<<4, 256, 0, stream>>>(afA_idA, afA_idB, 1024);
  k_cvt_x<<<2048, 256, 0, stream>>>(x0, xB, (long)N * 16);   // layer-0 x gather table

  // CSR over nodes (dst of edge_index) and over edges (dst of threebody)
  hipMemsetAsync(cur_n, 0, (size_t)N * 4, stream);
  hipMemsetAsync(cur_e, 0, (size_t)E * 4, stream);
  k_hist<<<1024, 256, 0, stream>>>(edge_index + E, E, cur_n);
  k_hist<<<1024, 256, 0, stream>>>(tb_index + A, A, cur_e);
  int nbN = (N + 1023) / 1024, nbE = (E + 1023) / 1024;
  k_scan1<<<nbN, 256, 0, stream>>>(cur_n, ptr_n, bsum, N);
  k_scan2<<<1, 256, 0, stream>>>(bsum, nbN, ptr_n + N);
  k_scan3<<<1024, 256, 0, stream>>>(ptr_n, cur_n, bsum, N);
  k_scatter<<<1024, 256, 0, stream>>>(edge_index + E, cur_n, perm_n, E);
  k_scan1<<<nbE, 256, 0, stream>>>(cur_e, ptr_e, bsum, E);
  k_scan2<<<1, 256, 0, stream>>>(bsum, nbE, ptr_e + E);
  k_scan3<<<1024, 256, 0, stream>>>(ptr_e, cur_e, bsum, E);
  k_scatter<<<1024, 256, 0, stream>>>(tb_index + A, cur_e, perm_e, A);

  const float* x_cur = x0;
  int blkE = (E / 16 + 3) / 4;   // 4 waves/block
  int blkA = (A / 16 + 3) / 4;

  for (int i = 0; i < 2; ++i) {
    const float* e_in  = (i == 0) ? e0 : eA;
    const float* a_in  = (i == 0) ? a0 : aA;
    const float* fEinA = (i == 0) ? afE_idA : afE2A;
    const float* fEinB = (i == 0) ? afE_idB : afE2B;
    const float* fAinA = (i == 0) ? afA_idA : afA1A;
    const float* fAinB = (i == 0) ? afA_idB : afA1B;

    // 1. edge update (+stats) -> affE1; then build bf16 gather table eB1
    hipMemsetAsync(s1, 0, 2 * NG * 4, stream);
    k_mm_edge<<<blkE, 256, 0, stream>>>(xB, e_in, eA, edge_index, edge_batch,
                                        wt_ne + (size_t)i*320*64, b_ne + i*64,
                                        fEinA, fEinB, s1, s2, E);
    k_mkaff<<<4, 256, 0, stream>>>(s1, s2, cnt_e, 64, g_e + i*64, be_e + i*64, afE1A, afE1B);
    k_norm_ebf<<<2048, 256, 0, stream>>>(eA, edge_batch, afE1A, afE1B, eB1, E);

    // 2. angle update (+stats) -> affA1  (gathers eB1, no per-gather affine)
    hipMemsetAsync(s1, 0, 2 * NG * 4, stream);
    k_mm_angle<<<blkA, 256, 0, stream>>>(eB1, a_in, aA, tb_index, angle_batch,
                                         wt_ea + (size_t)i*192*64, b_ea + i*64,
                                         fAinA, fAinB, s1, s2, A);
    k_mkaff<<<4, 256, 0, stream>>>(s1, s2, cnt_a, 64, g_a + i*64, be_a + i*64, afA1A, afA1B);

    // 3. edge_graph_mp: messages (gathers eB1) -> bf16 msg; CSR reduce -> affE2
    k_mm_emp<<<blkA, 256, 0, stream>>>(eB1, aA, tb_index, angle_batch,
                                       wt_emp + (size_t)i*192*64, b_emp + i*64,
                                       afA1A, afA1B, msg, A);
    hipMemsetAsync(s1, 0, 2 * NG * 4, stream);
    k_red_e<<<2048, 256, 0, stream>>>(msg, eA, eA, ptr_e, perm_e, edge_batch,
                                      afE1A, afE1B, s1, s2, E);
    k_mkaff<<<4, 256, 0, stream>>>(s1, s2, cnt_e, 64, g_emp + i*64, be_emp + i*64, afE2A, afE2B);

    // 4. node_graph_mp: messages (gathers xB) -> bf16 msg; CSR reduce; apply (+xB refresh)
    k_mm_nmp<<<blkE, 256, 0, stream>>>(xB, eA, edge_index, edge_batch,
                                       wt_nmp + (size_t)i*320*128, b_nmp + i*128,
                                       afE2A, afE2B, msg, E);
    hipMemsetAsync(s1, 0, 2 * NG * 4, stream);
    k_red_n<<<2048, 256, 0, stream>>>(msg, x_cur, x_out, ptr_n, perm_n, node_batch,
                                      s1, s2, N);
    k_mkaff<<<8, 256, 0, stream>>>(s1, s2, cnt_n, 128, g_nmp + i*128, be_nmp + i*128, afXA, afXB);
    k_apply<<<2048, 256, 0, stream>>>(x_out, node_batch, afXA, afXB, xB, N);

    x_cur = x_out;
  }
}

// Round 6
// 1866.384 us; speedup vs baseline: 1.2470x; 1.1112x over previous
//
#include <hip/hip_runtime.h>

typedef __attribute__((ext_vector_type(8))) short bf16x8_t;
typedef __attribute__((ext_vector_type(4))) short bf16x4_t;
typedef __attribute__((ext_vector_type(4))) float f32x4_t;

constexpr int NG = 16;
constexpr float EPS = 1e-5f;

__device__ inline unsigned short f2bf(float f) {
  unsigned u = __builtin_bit_cast(unsigned, f);
  u += 0x7FFFu + ((u >> 16) & 1u);
  return (unsigned short)(u >> 16);
}
__device__ inline float bf2f(unsigned short u) {
  unsigned x = ((unsigned)u) << 16;
  return __builtin_bit_cast(float, x);
}

// =====================================================================
// Dense partial GEMM over nodes (coalesced, no gathers):
//   P[n] = x[n] @ [Wne_s | Wne_d | Wnmp_s | Wnmp_d]   (N x 384, bf16)
// Column-swizzled per sub-table: sub-table T with NB 16-col blocks stores
// col (nb*16+colb) at sub_base + colb*NB + nb  -> each lane's nb-run is
// contiguous (8B/16B vector load at gather time).
//   T1 = x@W_ne[0:128]   (64 cols)  base 0
//   T2 = x@W_ne[128:256] (64 cols)  base 64
//   T3 = x@W_nmp[0:128]  (128 cols) base 128
//   T4 = x@W_nmp[128:256](128 cols) base 256
// =====================================================================
__global__ __launch_bounds__(256) void k_dense_x(
    const float* __restrict__ x,
    const unsigned short* __restrict__ WtNE,   // [64][320]
    const unsigned short* __restrict__ WtNM,   // [128][320]
    unsigned short* __restrict__ P, int nN)
{
  int gw = (int)((blockIdx.x * 256u + threadIdx.x) >> 6);
  int ntile = nN >> 4;
  if (gw >= ntile) return;
  int lane = threadIdx.x & 63;
  int colb = lane & 15;
  int ko = (lane >> 4) << 3;
  int rowb = (lane >> 4) << 2;
  int row = (gw << 4) + colb;
  const float* xr = x + (size_t)row * 128;
  f32x4_t a1[4] = {}, a2[4] = {}, a3[8] = {}, a4[8] = {};
#pragma unroll
  for (int c = 0; c < 4; ++c) {
    float4 f0 = *(const float4*)(xr + c * 32 + ko);
    float4 f1 = *(const float4*)(xr + c * 32 + ko + 4);
    float vv[8] = {f0.x,f0.y,f0.z,f0.w,f1.x,f1.y,f1.z,f1.w};
    bf16x8_t a;
#pragma unroll
    for (int k = 0; k < 8; ++k) a[k] = (short)f2bf(vv[k]);
#pragma unroll
    for (int nb = 0; nb < 4; ++nb) {
      bf16x8_t b1 = *(const bf16x8_t*)(WtNE + (size_t)(nb * 16 + colb) * 320 + c * 32 + ko);
      a1[nb] = __builtin_amdgcn_mfma_f32_16x16x32_bf16(a, b1, a1[nb], 0, 0, 0);
      bf16x8_t b2 = *(const bf16x8_t*)(WtNE + (size_t)(nb * 16 + colb) * 320 + (c + 4) * 32 + ko);
      a2[nb] = __builtin_amdgcn_mfma_f32_16x16x32_bf16(a, b2, a2[nb], 0, 0, 0);
    }
#pragma unroll
    for (int nb = 0; nb < 8; ++nb) {
      bf16x8_t b3 = *(const bf16x8_t*)(WtNM + (size_t)(nb * 16 + colb) * 320 + c * 32 + ko);
      a3[nb] = __builtin_amdgcn_mfma_f32_16x16x32_bf16(a, b3, a3[nb], 0, 0, 0);
      bf16x8_t b4 = *(const bf16x8_t*)(WtNM + (size_t)(nb * 16 + colb) * 320 + (c + 4) * 32 + ko);
      a4[nb] = __builtin_amdgcn_mfma_f32_16x16x32_bf16(a, b4, a4[nb], 0, 0, 0);
    }
  }
#pragma unroll
  for (int r = 0; r < 4; ++r) {
    size_t ro = (size_t)((gw << 4) + rowb + r) * 384;
    bf16x4_t t1, t2;
#pragma unroll
    for (int nb = 0; nb < 4; ++nb) { t1[nb] = (short)f2bf(a1[nb][r]); t2[nb] = (short)f2bf(a2[nb][r]); }
    *(bf16x4_t*)(P + ro + colb * 4) = t1;
    *(bf16x4_t*)(P + ro + 64 + colb * 4) = t2;
    bf16x8_t t3, t4;
#pragma unroll
    for (int nb = 0; nb < 8; ++nb) { t3[nb] = (short)f2bf(a3[nb][r]); t4[nb] = (short)f2bf(a4[nb][r]); }
    *(bf16x8_t*)(P + ro + 128 + colb * 8) = t3;
    *(bf16x8_t*)(P + ro + 256 + colb * 8) = t4;
  }
}

// =====================================================================
// EDGE stage (single gather pass for both stage-1 and stage-4 x-parts):
//   e_out = affEin(e_in) + P_T1[s] + P_T2[d] + affEin(e_in)@Wne_e + b (+stats)
//   pn    = P_T3[s] + P_T4[d]   (bf16, swizzled [E][colb*8+nb])
// =====================================================================
__global__ __launch_bounds__(256) void k_edge(
    const unsigned short* __restrict__ P, const float* e_in, float* e_out,
    const int* __restrict__ ei, const int* __restrict__ ebatch,
    const unsigned short* __restrict__ Wt,    // wt_ne [64][320]
    const float* __restrict__ bias,
    const float* __restrict__ afA, const float* __restrict__ afB,
    float* __restrict__ gs1, float* __restrict__ gs2,
    unsigned short* __restrict__ pn, int nE)
{
  __shared__ float lA[1024], lB[1024];
  __shared__ float ls1[NG], ls2[NG];
  for (int i = threadIdx.x; i < 1024; i += 256) { lA[i] = afA[i]; lB[i] = afB[i]; }
  if (threadIdx.x < NG) { ls1[threadIdx.x] = 0.f; ls2[threadIdx.x] = 0.f; }
  __syncthreads();
  int gw = (int)((blockIdx.x * 256u + threadIdx.x) >> 6);
  int ntile = nE >> 4;
  bool act = gw < ntile;
  int lane = threadIdx.x & 63;
  int colb = lane & 15;
  int ko = (lane >> 4) << 3;
  int rowb = (lane >> 4) << 2;
  float sr[4] = {0.f,0.f,0.f,0.f}, ssr[4] = {0.f,0.f,0.f,0.f};
  if (act) {
    // ---- issue all gathers first (16 indep loads -> deep MLP) ----
    int sI[4], dI[4];
#pragma unroll
    for (int r = 0; r < 4; ++r) {
      int e_r = (gw << 4) + rowb + r;
      sI[r] = ei[e_r]; dI[r] = ei[nE + e_r];
    }
    bf16x4_t g1[4], g2[4]; bf16x8_t g3[4], g4[4];
#pragma unroll
    for (int r = 0; r < 4; ++r) {
      g1[r] = *(const bf16x4_t*)(P + (size_t)sI[r] * 384 + colb * 4);
      g2[r] = *(const bf16x4_t*)(P + (size_t)dI[r] * 384 + 64 + colb * 4);
      g3[r] = *(const bf16x8_t*)(P + (size_t)sI[r] * 384 + 128 + colb * 8);
      g4[r] = *(const bf16x8_t*)(P + (size_t)dI[r] * 384 + 256 + colb * 8);
    }
    // ---- e-part MFMA (K=64) ----
    int row = (gw << 4) + colb;
    int ge = ebatch[row];
    const float* er = e_in + (size_t)row * 64;
    f32x4_t acc[4] = {};
#pragma unroll
    for (int c2 = 0; c2 < 2; ++c2) {
      int fb = c2 * 32 + ko;
      float4 f0 = *(const float4*)(er + fb);
      float4 f1 = *(const float4*)(er + fb + 4);
      float vv[8] = {f0.x,f0.y,f0.z,f0.w,f1.x,f1.y,f1.z,f1.w};
      bf16x8_t a;
#pragma unroll
      for (int k = 0; k < 8; ++k) a[k] = (short)f2bf(vv[k] * lA[ge*64 + fb + k] + lB[ge*64 + fb + k]);
#pragma unroll
      for (int nb = 0; nb < 4; ++nb) {
        bf16x8_t b = *(const bf16x8_t*)(Wt + (size_t)(nb * 16 + colb) * 320 + (8 + c2) * 32 + ko);
        acc[nb] = __builtin_amdgcn_mfma_f32_16x16x32_bf16(a, b, acc[nb], 0, 0, 0);
      }
    }
    // ---- epilogue ----
#pragma unroll
    for (int r = 0; r < 4; ++r) {
      int e_ = (gw << 4) + rowb + r;
      int gr = ebatch[e_];
#pragma unroll
      for (int nb = 0; nb < 4; ++nb) {
        int col = nb * 16 + colb;
        size_t off = (size_t)e_ * 64 + col;
        float vv = e_in[off] * lA[gr*64 + col] + lB[gr*64 + col] + bias[col]
                 + acc[nb][r] + bf2f((unsigned short)g1[r][nb]) + bf2f((unsigned short)g2[r][nb]);
        e_out[off] = vv;
        sr[r] += vv; ssr[r] += vv * vv;
      }
      bf16x8_t pv;
#pragma unroll
      for (int k = 0; k < 8; ++k)
        pv[k] = (short)f2bf(bf2f((unsigned short)g3[r][k]) + bf2f((unsigned short)g4[r][k]));
      *(bf16x8_t*)(pn + (size_t)e_ * 128 + colb * 8) = pv;
    }
  }
#pragma unroll
  for (int m = 1; m <= 8; m <<= 1)
#pragma unroll
    for (int r = 0; r < 4; ++r) { sr[r] += __shfl_xor(sr[r], m); ssr[r] += __shfl_xor(ssr[r], m); }
  if (act && colb == 0) {
#pragma unroll
    for (int r = 0; r < 4; ++r) {
      int g = ebatch[(gw << 4) + rowb + r];
      atomicAdd(&ls1[g], sr[r]); atomicAdd(&ls2[g], ssr[r]);
    }
  }
  __syncthreads();
  if (threadIdx.x < NG) {
    atomicAdd(&gs1[threadIdx.x], ls1[threadIdx.x]);
    atomicAdd(&gs2[threadIdx.x], ls2[threadIdx.x]);
  }
}

// =====================================================================
// nmp finish (pure stream): msg = relu(pn + affE2(e2)@Wnmp_e + b)
// pn read in its swizzled layout (16B per r per lane).
// =====================================================================
__global__ __launch_bounds__(256) void k_fin_nmp(
    const float* __restrict__ e, const int* __restrict__ ebatch,
    const unsigned short* __restrict__ Wt,    // wt_nmp [128][320]
    const float* __restrict__ bias,
    const float* __restrict__ afEA, const float* __restrict__ afEB,
    const unsigned short* __restrict__ pn,
    unsigned short* __restrict__ msg, int nE)
{
  __shared__ float lEA[1024], lEB[1024];
  for (int i = threadIdx.x; i < 1024; i += 256) { lEA[i] = afEA[i]; lEB[i] = afEB[i]; }
  __syncthreads();
  int gw = (int)((blockIdx.x * 256u + threadIdx.x) >> 6);
  int ntile = nE >> 4;
  if (gw >= ntile) return;
  int lane = threadIdx.x & 63;
  int colb = lane & 15;
  int ko = (lane >> 4) << 3;
  int rowb = (lane >> 4) << 2;
  int row = (gw << 4) + colb;
  int ge = ebatch[row];
  const float* er = e + (size_t)row * 64;
  f32x4_t acc[8] = {};
#pragma unroll
  for (int c2 = 0; c2 < 2; ++c2) {
    int fb = c2 * 32 + ko;
    float4 f0 = *(const float4*)(er + fb);
    float4 f1 = *(const float4*)(er + fb + 4);
    float vv[8] = {f0.x,f0.y,f0.z,f0.w,f1.x,f1.y,f1.z,f1.w};
    bf16x8_t a;
#pragma unroll
    for (int k = 0; k < 8; ++k) a[k] = (short)f2bf(vv[k] * lEA[ge*64 + fb + k] + lEB[ge*64 + fb + k]);
#pragma unroll
    for (int nb = 0; nb < 8; ++nb) {
      bf16x8_t b = *(const bf16x8_t*)(Wt + (size_t)(nb * 16 + colb) * 320 + (8 + c2) * 32 + ko);
      acc[nb] = __builtin_amdgcn_mfma_f32_16x16x32_bf16(a, b, acc[nb], 0, 0, 0);
    }
  }
#pragma unroll
  for (int r = 0; r < 4; ++r) {
    int e_ = (gw << 4) + rowb + r;
    bf16x8_t p8 = *(const bf16x8_t*)(pn + (size_t)e_ * 128 + colb * 8);
#pragma unroll
    for (int nb = 0; nb < 8; ++nb) {
      int col = nb * 16 + colb;
      float v = fmaxf(acc[nb][r] + bf2f((unsigned short)p8[nb]) + bias[col], 0.f);
      msg[(size_t)e_ * 128 + col] = f2bf(v);
    }
  }
}

// =====================================================================
// ANGLE update MM (unchanged R5): gathers pre-normalized bf16 table eB1.
// =====================================================================
__global__ __launch_bounds__(256) void k_mm_angle(
    const unsigned short* __restrict__ eB1, const float* a_in, float* a_out,
    const int* __restrict__ ti, const int* __restrict__ abatch,
    const unsigned short* __restrict__ Wt, const float* __restrict__ bias,
    const float* __restrict__ afAA, const float* __restrict__ afAB,
    float* __restrict__ gs1, float* __restrict__ gs2, int nA)
{
  __shared__ float lAA[1024], lAB[1024];
  __shared__ float ls1[NG], ls2[NG];
  for (int i = threadIdx.x; i < 1024; i += 256) { lAA[i] = afAA[i]; lAB[i] = afAB[i]; }
  if (threadIdx.x < NG) { ls1[threadIdx.x] = 0.f; ls2[threadIdx.x] = 0.f; }
  __syncthreads();
  int gw = (int)((blockIdx.x * 256u + threadIdx.x) >> 6);
  int ntile = nA >> 4;
  bool act = gw < ntile;
  int lane = threadIdx.x & 63;
  int colb = lane & 15;
  int ko = (lane >> 4) << 3;
  int rowb = (lane >> 4) << 2;
  float sr[4] = {0.f,0.f,0.f,0.f}, ssr[4] = {0.f,0.f,0.f,0.f};
  if (act) {
    int row = (gw << 4) + colb;
    int s = ti[row], d = ti[nA + row];
    int ga = abatch[row];
    const unsigned short* es = eB1 + (size_t)s * 64;
    const unsigned short* ed = eB1 + (size_t)d * 64;
    const float* ar = a_in + (size_t)row * 64;
    f32x4_t acc[4] = {};
#pragma unroll
    for (int c = 0; c < 6; ++c) {
      bf16x8_t a;
      if (c < 4) {
        const unsigned short* bp = (c < 2) ? es + c * 32 : ed + (c - 2) * 32;
        a = *(const bf16x8_t*)(bp + ko);
      } else {
        int fb = (c - 4) * 32 + ko;
        float4 f0 = *(const float4*)(ar + fb);
        float4 f1 = *(const float4*)(ar + fb + 4);
        float vv[8] = {f0.x,f0.y,f0.z,f0.w,f1.x,f1.y,f1.z,f1.w};
#pragma unroll
        for (int k = 0; k < 8; ++k) a[k] = (short)f2bf(vv[k] * lAA[ga*64 + fb + k] + lAB[ga*64 + fb + k]);
      }
#pragma unroll
      for (int nb = 0; nb < 4; ++nb) {
        bf16x8_t b = *(const bf16x8_t*)(Wt + (size_t)(nb * 16 + colb) * 192 + c * 32 + ko);
        acc[nb] = __builtin_amdgcn_mfma_f32_16x16x32_bf16(a, b, acc[nb], 0, 0, 0);
      }
    }
#pragma unroll
    for (int r = 0; r < 4; ++r) {
      int a_ = (gw << 4) + rowb + r;
      int gr = abatch[a_];
#pragma unroll
      for (int nb = 0; nb < 4; ++nb) {
        int col = nb * 16 + colb;
        size_t off = (size_t)a_ * 64 + col;
        float vv = a_in[off] * lAA[gr*64 + col] + lAB[gr*64 + col] + bias[col] + acc[nb][r];
        a_out[off] = vv;
        sr[r] += vv; ssr[r] += vv * vv;
      }
    }
  }
#pragma unroll
  for (int m = 1; m <= 8; m <<= 1)
#pragma unroll
    for (int r = 0; r < 4; ++r) { sr[r] += __shfl_xor(sr[r], m); ssr[r] += __shfl_xor(ssr[r], m); }
  if (act && colb == 0) {
#pragma unroll
    for (int r = 0; r < 4; ++r) {
      int g = abatch[(gw << 4) + rowb + r];
      atomicAdd(&ls1[g], sr[r]); atomicAdd(&ls2[g], ssr[r]);
    }
  }
  __syncthreads();
  if (threadIdx.x < NG) {
    atomicAdd(&gs1[threadIdx.x], ls1[threadIdx.x]);
    atomicAdd(&gs2[threadIdx.x], ls2[threadIdx.x]);
  }
}

// =====================================================================
// edge_graph_mp message MM (unchanged R5): msg = relu([eB1_s|eB1_d|affA1(a)]@W + b)
// =====================================================================
__global__ __launch_bounds__(256) void k_mm_emp(
    const unsigned short* __restrict__ eB1, const float* __restrict__ a_,
    const int* __restrict__ ti, const int* __restrict__ abatch,
    const unsigned short* __restrict__ Wt, const float* __restrict__ bias,
    const float* __restrict__ afAA, const float* __restrict__ afAB,
    unsigned short* __restrict__ msg, int nA)
{
  __shared__ float lAA[1024], lAB[1024];
  for (int i = threadIdx.x; i < 1024; i += 256) { lAA[i] = afAA[i]; lAB[i] = afAB[i]; }
  __syncthreads();
  int gw = (int)((blockIdx.x * 256u + threadIdx.x) >> 6);
  int ntile = nA >> 4;
  if (gw >= ntile) return;
  int lane = threadIdx.x & 63;
  int colb = lane & 15;
  int ko = (lane >> 4) << 3;
  int rowb = (lane >> 4) << 2;
  int row = (gw << 4) + colb;
  int s = ti[row], d = ti[nA + row];
  int ga = abatch[row];
  const unsigned short* es = eB1 + (size_t)s * 64;
  const unsigned short* ed = eB1 + (size_t)d * 64;
  const float* ar = a_ + (size_t)row * 64;
  f32x4_t acc[4] = {};
#pragma unroll
  for (int c = 0; c < 6; ++c) {
    bf16x8_t a;
    if (c < 4) {
      const unsigned short* bp = (c < 2) ? es + c * 32 : ed + (c - 2) * 32;
      a = *(const bf16x8_t*)(bp + ko);
    } else {
      int fb = (c - 4) * 32 + ko;
      float4 f0 = *(const float4*)(ar + fb);
      float4 f1 = *(const float4*)(ar + fb + 4);
      float vv[8] = {f0.x,f0.y,f0.z,f0.w,f1.x,f1.y,f1.z,f1.w};
#pragma unroll
      for (int k = 0; k < 8; ++k) a[k] = (short)f2bf(vv[k] * lAA[ga*64 + fb + k] + lAB[ga*64 + fb + k]);
    }
#pragma unroll
    for (int nb = 0; nb < 4; ++nb) {
      bf16x8_t b = *(const bf16x8_t*)(Wt + (size_t)(nb * 16 + colb) * 192 + c * 32 + ko);
      acc[nb] = __builtin_amdgcn_mfma_f32_16x16x32_bf16(a, b, acc[nb], 0, 0, 0);
    }
  }
#pragma unroll
  for (int r = 0; r < 4; ++r) {
    int a_idx = (gw << 4) + rowb + r;
#pragma unroll
    for (int nb = 0; nb < 4; ++nb) {
      int col = nb * 16 + colb;
      float v = fmaxf(acc[nb][r] + bias[col], 0.f);
      msg[(size_t)a_idx * 64 + col] = f2bf(v);
    }
  }
}

// =====================================================================
// CSR gather-reduce over edges (unchanged).
// =====================================================================
__global__ __launch_bounds__(256) void k_red_e(
    const unsigned short* __restrict__ msg, const float* e_in, float* e_out,
    const int* __restrict__ ptr, const int* __restrict__ perm,
    const int* __restrict__ ebatch,
    const float* __restrict__ afA, const float* __restrict__ afB,
    float* __restrict__ gs1, float* __restrict__ gs2, int nE)
{
  __shared__ float lA[1024], lB[1024], ls1[NG], ls2[NG];
  for (int i = threadIdx.x; i < 1024; i += 256) { lA[i] = afA[i]; lB[i] = afB[i]; }
  if (threadIdx.x < NG) { ls1[threadIdx.x] = 0.f; ls2[threadIdx.x] = 0.f; }
  __syncthreads();
  int lane = threadIdx.x & 63;
  int wv = (int)((blockIdx.x * 256u + threadIdx.x) >> 6);
  int nw = (int)((gridDim.x * 256u) >> 6);
  for (int eidx = wv; eidx < nE; eidx += nw) {
    int p0 = ptr[eidx], p1 = ptr[eidx + 1];
    float sum = 0.f;
    for (int j = p0; j < p1; ++j) {
      int aidx = perm[j];
      sum += bf2f(msg[(size_t)aidx * 64 + lane]);
    }
    int g = ebatch[eidx];
    size_t off = (size_t)eidx * 64 + lane;
    float v = e_in[off] * lA[g*64 + lane] + lB[g*64 + lane] + sum;
    e_out[off] = v;
    float s = v, ss = v * v;
#pragma unroll
    for (int m = 1; m < 64; m <<= 1) { s += __shfl_xor(s, m); ss += __shfl_xor(ss, m); }
    if (lane == 0) { atomicAdd(&ls1[g], s); atomicAdd(&ls2[g], ss); }
  }
  __syncthreads();
  if (threadIdx.x < NG) {
    atomicAdd(&gs1[threadIdx.x], ls1[threadIdx.x]);
    atomicAdd(&gs2[threadIdx.x], ls2[threadIdx.x]);
  }
}

// =====================================================================
// CSR gather-reduce over nodes (unchanged).
// =====================================================================
__global__ __launch_bounds__(256) void k_red_n(
    const unsigned short* __restrict__ msg, const float* x_in, float* out,
    const int* __restrict__ ptr, const int* __restrict__ perm,
    const int* __restrict__ nbatch,
    float* __restrict__ gs1, float* __restrict__ gs2, int nN)
{
  __shared__ float ls1[NG], ls2[NG];
  if (threadIdx.x < NG) { ls1[threadIdx.x] = 0.f; ls2[threadIdx.x] = 0.f; }
  __syncthreads();
  int lane = threadIdx.x & 63;
  int wv = (int)((blockIdx.x * 256u + threadIdx.x) >> 6);
  int nw = (int)((gridDim.x * 256u) >> 6);
  for (int n = wv; n < nN; n += nw) {
    int p0 = ptr[n], p1 = ptr[n + 1];
    float s0 = 0.f, s1v = 0.f;
    for (int j = p0; j < p1; ++j) {
      int e = perm[j];
      unsigned u = *(const unsigned*)(msg + (size_t)e * 128 + lane * 2);
      s0 += bf2f((unsigned short)(u & 0xffffu));
      s1v += bf2f((unsigned short)(u >> 16));
    }
    size_t off = (size_t)n * 128 + lane * 2;
    float h0 = x_in[off] + s0, h1 = x_in[off + 1] + s1v;
    out[off] = h0; out[off + 1] = h1;
    float s = h0 + h1, ss = h0 * h0 + h1 * h1;
#pragma unroll
    for (int m = 1; m < 64; m <<= 1) { s += __shfl_xor(s, m); ss += __shfl_xor(ss, m); }
    if (lane == 0) { int g = nbatch[n]; atomicAdd(&ls1[g], s); atomicAdd(&ls2[g], ss); }
  }
  __syncthreads();
  if (threadIdx.x < NG) {
    atomicAdd(&gs1[threadIdx.x], ls1[threadIdx.x]);
    atomicAdd(&gs2[threadIdx.x], ls2[threadIdx.x]);
  }
}

// ---- affine table construction ----
__global__ __launch_bounds__(256) void k_mkaff(
    const float* __restrict__ s1, const float* __restrict__ s2,
    const float* __restrict__ cnt, int F,
    const float* __restrict__ w, const float* __restrict__ b,
    float* __restrict__ A, float* __restrict__ B)
{
  int idx = blockIdx.x * 256 + threadIdx.x;
  if (idx >= NG * F) return;
  int g = idx / F, f = idx - g * F;
  float norm = fmaxf(cnt[g], 1.f) * (float)F;
  float m = s1[g] / norm;
  float var = s2[g] / norm - m * m;
  float inv = rsqrtf(var + EPS);
  float a = inv * w[f];
  A[idx] = a;
  B[idx] = b[f] - m * a;
}

__global__ __launch_bounds__(256) void k_idaff(float* __restrict__ A, float* __restrict__ B, int n)
{
  int idx = blockIdx.x * 256 + threadIdx.x;
  if (idx < n) { A[idx] = 1.f; B[idx] = 0.f; }
}

// ---- stream: eB1 = bf16(affE1(eA)) ----
__global__ __launch_bounds__(256) void k_norm_ebf(
    const float* __restrict__ e, const int* __restrict__ ebatch,
    const float* __restrict__ afA, const float* __restrict__ afB,
    unsigned short* __restrict__ eB, int nE)
{
  int total = nE * 8;
  int stride = gridDim.x * 256;
  for (int idx = blockIdx.x * 256 + threadIdx.x; idx < total; idx += stride) {
    int row = idx >> 3, q = (idx & 7) * 8;
    int g = ebatch[row];
    const float* er = e + (size_t)row * 64 + q;
    float4 f0 = *(const float4*)er;
    float4 f1 = *(const float4*)(er + 4);
    float vv[8] = {f0.x,f0.y,f0.z,f0.w,f1.x,f1.y,f1.z,f1.w};
    bf16x8_t o;
#pragma unroll
    for (int k = 0; k < 8; ++k) o[k] = (short)f2bf(vv[k] * afA[g*64 + q + k] + afB[g*64 + q + k]);
    *(bf16x8_t*)(eB + (size_t)row * 64 + q) = o;
  }
}

// ---- apply norm to x (in-place) ----
__global__ __launch_bounds__(256) void k_apply(
    float* h, const int* __restrict__ batch,
    const float* __restrict__ A, const float* __restrict__ B, int nN)
{
  int total = nN * 16;
  int stride = gridDim.x * 256;
  for (int idx = blockIdx.x * 256 + threadIdx.x; idx < total; idx += stride) {
    int row = idx >> 4, q = (idx & 15) * 8;
    int g = batch[row];
    float* hp = h + (size_t)row * 128 + q;
    float4 f0 = *(const float4*)hp;
    float4 f1 = *(const float4*)(hp + 4);
    float vv[8] = {f0.x,f0.y,f0.z,f0.w,f1.x,f1.y,f1.z,f1.w};
#pragma unroll
    for (int k = 0; k < 8; ++k) vv[k] = vv[k] * A[(g << 7) + q + k] + B[(g << 7) + q + k];
    float4 g0 = {vv[0],vv[1],vv[2],vv[3]}, g1 = {vv[4],vv[5],vv[6],vv[7]};
    *(float4*)hp = g0;
    *(float4*)(hp + 4) = g1;
  }
}

__global__ __launch_bounds__(256) void k_count(
    const int* __restrict__ batch, int n, float* __restrict__ cnt)
{
  __shared__ float lc[NG];
  if (threadIdx.x < NG) lc[threadIdx.x] = 0.f;
  __syncthreads();
  for (int i = blockIdx.x * 256 + threadIdx.x; i < n; i += gridDim.x * 256)
    atomicAdd(&lc[batch[i]], 1.f);
  __syncthreads();
  if (threadIdx.x < NG) atomicAdd(&cnt[threadIdx.x], lc[threadIdx.x]);
}

// ---- CSR build ----
__global__ __launch_bounds__(256) void k_hist(
    const int* __restrict__ dst, int n, int* __restrict__ cnt)
{
  for (int i = blockIdx.x * 256 + threadIdx.x; i < n; i += gridDim.x * 256)
    atomicAdd(&cnt[dst[i]], 1);
}

__global__ __launch_bounds__(256) void k_scan1(
    const int* __restrict__ in, int* __restrict__ out, int* __restrict__ bsum, int n)
{
  __shared__ int wtot[4];
  int tid = threadIdx.x, lane = tid & 63, wid = tid >> 6;
  int base = blockIdx.x * 1024 + tid * 4;
  int v[4];
#pragma unroll
  for (int k = 0; k < 4; ++k) v[k] = (base + k < n) ? in[base + k] : 0;
  int tsum = v[0] + v[1] + v[2] + v[3];
  int incl = tsum;
#pragma unroll
  for (int off = 1; off < 64; off <<= 1) {
    int up = __shfl_up(incl, off);
    if (lane >= off) incl += up;
  }
  if (lane == 63) wtot[wid] = incl;
  __syncthreads();
  if (tid == 0) {
    int r = 0;
#pragma unroll
    for (int w2 = 0; w2 < 4; ++w2) { int t = wtot[w2]; wtot[w2] = r; r += t; }
    bsum[blockIdx.x] = r;
  }
  __syncthreads();
  int excl = wtot[wid] + incl - tsum;
#pragma unroll
  for (int k = 0; k < 4; ++k) {
    if (base + k < n) out[base + k] = excl;
    excl += v[k];
  }
}

__global__ __launch_bounds__(256) void k_scan2(int* __restrict__ bsum, int nb, int* __restrict__ total_out)
{
  __shared__ int wtot[4];
  int tid = threadIdx.x, lane = tid & 63, wid = tid >> 6;
  int base = tid * 4;
  int v[4];
#pragma unroll
  for (int k = 0; k < 4; ++k) v[k] = (base + k < nb) ? bsum[base + k] : 0;
  int tsum = v[0] + v[1] + v[2] + v[3];
  int incl = tsum;
#pragma unroll
  for (int off = 1; off < 64; off <<= 1) {
    int up = __shfl_up(incl, off);
    if (lane >= off) incl += up;
  }
  if (lane == 63) wtot[wid] = incl;
  __syncthreads();
  if (tid == 0) {
    int r = 0;
#pragma unroll
    for (int w2 = 0; w2 < 4; ++w2) { int t = wtot[w2]; wtot[w2] = r; r += t; }
    *total_out = r;
  }
  __syncthreads();
  int excl = wtot[wid] + incl - tsum;
#pragma unroll
  for (int k = 0; k < 4; ++k) {
    if (base + k < nb) bsum[base + k] = excl;
    excl += v[k];
  }
}

__global__ __launch_bounds__(256) void k_scan3(
    int* __restrict__ ptr, int* __restrict__ cur, const int* __restrict__ bsum, int n)
{
  for (int i = blockIdx.x * 256 + threadIdx.x; i < n; i += gridDim.x * 256) {
    int v = ptr[i] + bsum[i >> 10];
    ptr[i] = v; cur[i] = v;
  }
}

__global__ __launch_bounds__(256) void k_scatter(
    const int* __restrict__ dst, int* __restrict__ cur, int* __restrict__ perm, int n)
{
  for (int i = blockIdx.x * 256 + threadIdx.x; i < n; i += gridDim.x * 256) {
    int d = dst[i];
    int p = atomicAdd(&cur[d], 1);
    perm[p] = i;
  }
}

// ---- weight prep ----
__global__ __launch_bounds__(256) void k_wt(
    const float* __restrict__ W, unsigned short* __restrict__ Wt, int K, int NO)
{
  int idx = blockIdx.x * 256 + threadIdx.x;
  if (idx >= K * NO) return;
  int k = idx / NO, j = idx - k * NO;
  Wt[(size_t)j * K + k] = f2bf(W[idx]);
}

extern "C" void kernel_launch(void* const* d_in, const int* in_sizes, int n_in,
                              void* d_out, int out_size, void* d_ws, size_t ws_size,
                              hipStream_t stream)
{
  const float* x0    = (const float*)d_in[0];
  const float* e0    = (const float*)d_in[1];
  const float* a0    = (const float*)d_in[2];
  const float* W_ne  = (const float*)d_in[3];
  const float* b_ne  = (const float*)d_in[4];
  const float* g_e   = (const float*)d_in[5];
  const float* be_e  = (const float*)d_in[6];
  const float* W_ea  = (const float*)d_in[7];
  const float* b_ea  = (const float*)d_in[8];
  const float* g_a   = (const float*)d_in[9];
  const float* be_a  = (const float*)d_in[10];
  const float* W_emp = (const float*)d_in[11];
  const float* b_emp = (const float*)d_in[12];
  const float* g_emp = (const float*)d_in[13];
  const float* be_emp= (const float*)d_in[14];
  const float* W_nmp = (const float*)d_in[15];
  const float* b_nmp = (const float*)d_in[16];
  const float* g_nmp = (const float*)d_in[17];
  const float* be_nmp= (const float*)d_in[18];
  const int* node_batch  = (const int*)d_in[19];
  const int* edge_index  = (const int*)d_in[20];
  const int* edge_batch  = (const int*)d_in[21];
  const int* tb_index    = (const int*)d_in[22];
  const int* angle_batch = (const int*)d_in[23];

  const int N = in_sizes[0] / 128;
  const int E = in_sizes[1] / 64;
  const int A = in_sizes[2] / 64;

  // ---- workspace layout (bytes, 256-aligned) ----
  char* wsp = (char*)d_ws;
  auto alloc = [&](size_t bytes) { char* p = wsp; wsp += (bytes + 255) & ~(size_t)255; return p; };
  float*          eA     = (float*)alloc((size_t)E * 64 * 4);
  float*          aA     = (float*)alloc((size_t)A * 64 * 4);
  unsigned short* msg    = (unsigned short*)alloc((size_t)A * 64 * 2);  // hosts P, then msg_e, then msg_n
  unsigned short* pn     = (unsigned short*)alloc((size_t)E * 128 * 2); // nmp x-partial (swizzled)
  unsigned short* eB1    = (unsigned short*)alloc((size_t)E * 64 * 2);  // bf16 affE1(e) gather table
  int* ptr_n  = (int*)alloc((size_t)(N + 1) * 4);
  int* cur_n  = (int*)alloc((size_t)N * 4);
  int* perm_n = (int*)alloc((size_t)E * 4);
  int* ptr_e  = (int*)alloc((size_t)(E + 1) * 4);
  int* cur_e  = (int*)alloc((size_t)E * 4);
  int* perm_e = (int*)alloc((size_t)A * 4);
  int* bsum   = (int*)alloc(4096 * 4);
  // stats: ONE contiguous block (memset correctness depends on adjacency)
  float* stats = (float*)alloc(5 * NG * 4);
  float* s1    = stats;
  float* s2    = stats + NG;
  float* cnt_n = stats + 2 * NG;
  float* cnt_e = stats + 3 * NG;
  float* cnt_a = stats + 4 * NG;
  float* afE_idA = (float*)alloc(1024 * 4); float* afE_idB = (float*)alloc(1024 * 4);
  float* afA_idA = (float*)alloc(1024 * 4); float* afA_idB = (float*)alloc(1024 * 4);
  float* afE1A   = (float*)alloc(1024 * 4); float* afE1B   = (float*)alloc(1024 * 4);
  float* afE2A   = (float*)alloc(1024 * 4); float* afE2B   = (float*)alloc(1024 * 4);
  float* afA1A   = (float*)alloc(1024 * 4); float* afA1B   = (float*)alloc(1024 * 4);
  float* afXA    = (float*)alloc(2048 * 4); float* afXB    = (float*)alloc(2048 * 4);
  unsigned short* wt_ne  = (unsigned short*)alloc((size_t)2 * 320 * 64 * 2);
  unsigned short* wt_ea  = (unsigned short*)alloc((size_t)2 * 192 * 64 * 2);
  unsigned short* wt_emp = (unsigned short*)alloc((size_t)2 * 192 * 64 * 2);
  unsigned short* wt_nmp = (unsigned short*)alloc((size_t)2 * 320 * 128 * 2);

  unsigned short* P = msg;   // P (N*384 bf16 = 38.4MB) lives in msg (76.8MB); dead before msg written
  float* x_out = (float*)d_out;

  // ---- one-time prep ----
  for (int i = 0; i < 2; ++i) {
    k_wt<<<(320*64 + 255)/256, 256, 0, stream>>>(W_ne  + (size_t)i*320*64,  wt_ne  + (size_t)i*320*64,  320, 64);
    k_wt<<<(192*64 + 255)/256, 256, 0, stream>>>(W_ea  + (size_t)i*192*64,  wt_ea  + (size_t)i*192*64,  192, 64);
    k_wt<<<(192*64 + 255)/256, 256, 0, stream>>>(W_emp + (size_t)i*192*64,  wt_emp + (size_t)i*192*64,  192, 64);
    k_wt<<<(320*128 + 255)/256, 256, 0, stream>>>(W_nmp + (size_t)i*320*128, wt_nmp + (size_t)i*320*128, 320, 128);
  }
  hipMemsetAsync(stats, 0, 5 * NG * 4, stream);
  k_count<<<512, 256, 0, stream>>>(node_batch, N, cnt_n);
  k_count<<<512, 256, 0, stream>>>(edge_batch, E, cnt_e);
  k_count<<<512, 256, 0, stream>>>(angle_batch, A, cnt_a);
  k_idaff<<<4, 256, 0, stream>>>(afE_idA, afE_idB, 1024);
  k_idaff<<<4, 256, 0, stream>>>(afA_idA, afA_idB, 1024);

  // CSR over nodes (dst of edge_index) and over edges (dst of threebody)
  hipMemsetAsync(cur_n, 0, (size_t)N * 4, stream);
  hipMemsetAsync(cur_e, 0, (size_t)E * 4, stream);
  k_hist<<<1024, 256, 0, stream>>>(edge_index + E, E, cur_n);
  k_hist<<<1024, 256, 0, stream>>>(tb_index + A, A, cur_e);
  int nbN = (N + 1023) / 1024, nbE = (E + 1023) / 1024;
  k_scan1<<<nbN, 256, 0, stream>>>(cur_n, ptr_n, bsum, N);
  k_scan2<<<1, 256, 0, stream>>>(bsum, nbN, ptr_n + N);
  k_scan3<<<1024, 256, 0, stream>>>(ptr_n, cur_n, bsum, N);
  k_scatter<<<1024, 256, 0, stream>>>(edge_index + E, cur_n, perm_n, E);
  k_scan1<<<nbE, 256, 0, stream>>>(cur_e, ptr_e, bsum, E);
  k_scan2<<<1, 256, 0, stream>>>(bsum, nbE, ptr_e + E);
  k_scan3<<<1024, 256, 0, stream>>>(ptr_e, cur_e, bsum, E);
  k_scatter<<<1024, 256, 0, stream>>>(tb_index + A, cur_e, perm_e, A);

  const float* x_cur = x0;
  int blkE = (E / 16 + 3) / 4;
  int blkA = (A / 16 + 3) / 4;
  int blkN = (N / 16 + 3) / 4;

  for (int i = 0; i < 2; ++i) {
    const float* e_in  = (i == 0) ? e0 : eA;
    const float* a_in  = (i == 0) ? a0 : aA;
    const float* fEinA = (i == 0) ? afE_idA : afE2A;
    const float* fEinB = (i == 0) ? afE_idB : afE2B;
    const float* fAinA = (i == 0) ? afA_idA : afA1A;
    const float* fAinB = (i == 0) ? afA_idB : afA1B;

    // 0. dense x-partials (coalesced GEMM, writes P into msg-space)
    k_dense_x<<<blkN, 256, 0, stream>>>(x_cur, wt_ne + (size_t)i*320*64,
                                        wt_nmp + (size_t)i*320*128, P, N);

    // 1. edge stage: one gather pass for stage-1 AND stage-4 x-parts
    hipMemsetAsync(s1, 0, 2 * NG * 4, stream);
    k_edge<<<blkE, 256, 0, stream>>>(P, e_in, eA, edge_index, edge_batch,
                                     wt_ne + (size_t)i*320*64, b_ne + i*64,
                                     fEinA, fEinB, s1, s2, pn, E);
    k_mkaff<<<4, 256, 0, stream>>>(s1, s2, cnt_e, 64, g_e + i*64, be_e + i*64, afE1A, afE1B);
    k_norm_ebf<<<2048, 256, 0, stream>>>(eA, edge_batch, afE1A, afE1B, eB1, E);

    // 2. angle update -> affA1
    hipMemsetAsync(s1, 0, 2 * NG * 4, stream);
    k_mm_angle<<<blkA, 256, 0, stream>>>(eB1, a_in, aA, tb_index, angle_batch,
                                         wt_ea + (size_t)i*192*64, b_ea + i*64,
                                         fAinA, fAinB, s1, s2, A);
    k_mkaff<<<4, 256, 0, stream>>>(s1, s2, cnt_a, 64, g_a + i*64, be_a + i*64, afA1A, afA1B);

    // 3. edge_graph_mp: messages (gathers eB1; overwrites P region — P dead) -> CSR reduce -> affE2
    k_mm_emp<<<blkA, 256, 0, stream>>>(eB1, aA, tb_index, angle_batch,
                                       wt_emp + (size_t)i*192*64, b_emp + i*64,
                                       afA1A, afA1B, msg, A);
    hipMemsetAsync(s1, 0, 2 * NG * 4, stream);
    k_red_e<<<2048, 256, 0, stream>>>(msg, eA, eA, ptr_e, perm_e, edge_batch,
                                      afE1A, afE1B, s1, s2, E);
    k_mkaff<<<4, 256, 0, stream>>>(s1, s2, cnt_e, 64, g_emp + i*64, be_emp + i*64, afE2A, afE2B);

    // 4. nmp finish (stream: pn + e-part) -> msg; CSR reduce; apply
    k_fin_nmp<<<blkE, 256, 0, stream>>>(eA, edge_batch, wt_nmp + (size_t)i*320*128,
                                        b_nmp + i*128, afE2A, afE2B, pn, msg, E);
    hipMemsetAsync(s1, 0, 2 * NG * 4, stream);
    k_red_n<<<2048, 256, 0, stream>>>(msg, x_cur, x_out, ptr_n, perm_n, node_batch,
                                      s1, s2, N);
    k_mkaff<<<8, 256, 0, stream>>>(s1, s2, cnt_n, 128, g_nmp + i*128, be_nmp + i*128, afXA, afXB);
    k_apply<<<2048, 256, 0, stream>>>(x_out, node_batch, afXA, afXB, N);

    x_cur = x_out;
  }
}

// Round 7
// 1840.256 us; speedup vs baseline: 1.2647x; 1.0142x over previous
//
#include <hip/hip_runtime.h>

typedef __attribute__((ext_vector_type(8))) short bf16x8_t;
typedef __attribute__((ext_vector_type(4))) short bf16x4_t;
typedef __attribute__((ext_vector_type(4))) float f32x4_t;

constexpr int NG = 16;
constexpr float EPS = 1e-5f;

__device__ inline unsigned short f2bf(float f) {
  unsigned u = __builtin_bit_cast(unsigned, f);
  u += 0x7FFFu + ((u >> 16) & 1u);
  return (unsigned short)(u >> 16);
}
__device__ inline float bf2f(unsigned short u) {
  unsigned x = ((unsigned)u) << 16;
  return __builtin_bit_cast(float, x);
}

// =====================================================================
// Dense partial GEMM over nodes (coalesced):
//   P[n] = x[n] @ [Wne_s | Wne_d | Wnmp_s | Wnmp_d]  (N x 384 bf16, swizzled)
// =====================================================================
__global__ __launch_bounds__(256) void k_dense_x(
    const float* __restrict__ x,
    const unsigned short* __restrict__ WtNE,   // [64][320]
    const unsigned short* __restrict__ WtNM,   // [128][320]
    unsigned short* __restrict__ P, int nN)
{
  int gw = (int)((blockIdx.x * 256u + threadIdx.x) >> 6);
  int ntile = nN >> 4;
  if (gw >= ntile) return;
  int lane = threadIdx.x & 63;
  int colb = lane & 15;
  int ko = (lane >> 4) << 3;
  int rowb = (lane >> 4) << 2;
  int row = (gw << 4) + colb;
  const float* xr = x + (size_t)row * 128;
  f32x4_t a1[4] = {}, a2[4] = {}, a3[8] = {}, a4[8] = {};
#pragma unroll
  for (int c = 0; c < 4; ++c) {
    float4 f0 = *(const float4*)(xr + c * 32 + ko);
    float4 f1 = *(const float4*)(xr + c * 32 + ko + 4);
    float vv[8] = {f0.x,f0.y,f0.z,f0.w,f1.x,f1.y,f1.z,f1.w};
    bf16x8_t a;
#pragma unroll
    for (int k = 0; k < 8; ++k) a[k] = (short)f2bf(vv[k]);
#pragma unroll
    for (int nb = 0; nb < 4; ++nb) {
      bf16x8_t b1 = *(const bf16x8_t*)(WtNE + (size_t)(nb * 16 + colb) * 320 + c * 32 + ko);
      a1[nb] = __builtin_amdgcn_mfma_f32_16x16x32_bf16(a, b1, a1[nb], 0, 0, 0);
      bf16x8_t b2 = *(const bf16x8_t*)(WtNE + (size_t)(nb * 16 + colb) * 320 + (c + 4) * 32 + ko);
      a2[nb] = __builtin_amdgcn_mfma_f32_16x16x32_bf16(a, b2, a2[nb], 0, 0, 0);
    }
#pragma unroll
    for (int nb = 0; nb < 8; ++nb) {
      bf16x8_t b3 = *(const bf16x8_t*)(WtNM + (size_t)(nb * 16 + colb) * 320 + c * 32 + ko);
      a3[nb] = __builtin_amdgcn_mfma_f32_16x16x32_bf16(a, b3, a3[nb], 0, 0, 0);
      bf16x8_t b4 = *(const bf16x8_t*)(WtNM + (size_t)(nb * 16 + colb) * 320 + (c + 4) * 32 + ko);
      a4[nb] = __builtin_amdgcn_mfma_f32_16x16x32_bf16(a, b4, a4[nb], 0, 0, 0);
    }
  }
#pragma unroll
  for (int r = 0; r < 4; ++r) {
    size_t ro = (size_t)((gw << 4) + rowb + r) * 384;
    bf16x4_t t1, t2;
#pragma unroll
    for (int nb = 0; nb < 4; ++nb) { t1[nb] = (short)f2bf(a1[nb][r]); t2[nb] = (short)f2bf(a2[nb][r]); }
    *(bf16x4_t*)(P + ro + colb * 4) = t1;
    *(bf16x4_t*)(P + ro + 64 + colb * 4) = t2;
    bf16x8_t t3, t4;
#pragma unroll
    for (int nb = 0; nb < 8; ++nb) { t3[nb] = (short)f2bf(a3[nb][r]); t4[nb] = (short)f2bf(a4[nb][r]); }
    *(bf16x8_t*)(P + ro + 128 + colb * 8) = t3;
    *(bf16x8_t*)(P + ro + 256 + colb * 8) = t4;
  }
}

// =====================================================================
// Dense emp partials over edges (coalesced):
//   PE[e] = eB1[e] @ [Wemp_s | Wemp_d]   (E x 128 bf16, swizzled: T3 base 0, T4 base 64)
// =====================================================================
__global__ __launch_bounds__(256) void k_dense_e(
    const unsigned short* __restrict__ eB1,
    const unsigned short* __restrict__ WtP,    // wt_emp [64][192]
    unsigned short* __restrict__ PE, int nE)
{
  int gw = (int)((blockIdx.x * 256u + threadIdx.x) >> 6);
  int ntile = nE >> 4;
  if (gw >= ntile) return;
  int lane = threadIdx.x & 63;
  int colb = lane & 15;
  int ko = (lane >> 4) << 3;
  int rowb = (lane >> 4) << 2;
  int row = (gw << 4) + colb;
  const unsigned short* er = eB1 + (size_t)row * 64;
  f32x4_t a3[4] = {}, a4[4] = {};
#pragma unroll
  for (int c2 = 0; c2 < 2; ++c2) {
    bf16x8_t a = *(const bf16x8_t*)(er + c2 * 32 + ko);
#pragma unroll
    for (int nb = 0; nb < 4; ++nb) {
      bf16x8_t b3 = *(const bf16x8_t*)(WtP + (size_t)(nb * 16 + colb) * 192 + c2 * 32 + ko);
      a3[nb] = __builtin_amdgcn_mfma_f32_16x16x32_bf16(a, b3, a3[nb], 0, 0, 0);
      bf16x8_t b4 = *(const bf16x8_t*)(WtP + (size_t)(nb * 16 + colb) * 192 + 64 + c2 * 32 + ko);
      a4[nb] = __builtin_amdgcn_mfma_f32_16x16x32_bf16(a, b4, a4[nb], 0, 0, 0);
    }
  }
#pragma unroll
  for (int r = 0; r < 4; ++r) {
    size_t ro = (size_t)((gw << 4) + rowb + r) * 128;
    bf16x4_t t3, t4;
#pragma unroll
    for (int nb = 0; nb < 4; ++nb) { t3[nb] = (short)f2bf(a3[nb][r]); t4[nb] = (short)f2bf(a4[nb][r]); }
    *(bf16x4_t*)(PE + ro + colb * 4) = t3;
    *(bf16x4_t*)(PE + ro + 64 + colb * 4) = t4;
  }
}

// =====================================================================
// EDGE stage: e_out = affEin(e_in) + P_T1[s]+P_T2[d] + affEin(e_in)@Wne_e + b (+stats)
//             pn = P_T3[s] + P_T4[d]   (bf16, swizzled)
// =====================================================================
__global__ __launch_bounds__(256) void k_edge(
    const unsigned short* __restrict__ P, const float* e_in, float* e_out,
    const int* __restrict__ ei, const int* __restrict__ ebatch,
    const unsigned short* __restrict__ Wt,    // wt_ne [64][320]
    const float* __restrict__ bias,
    const float* __restrict__ afA, const float* __restrict__ afB,
    float* __restrict__ gs1, float* __restrict__ gs2,
    unsigned short* __restrict__ pn, int nE)
{
  __shared__ float lA[1024], lB[1024];
  __shared__ float ls1[NG], ls2[NG];
  for (int i = threadIdx.x; i < 1024; i += 256) { lA[i] = afA[i]; lB[i] = afB[i]; }
  if (threadIdx.x < NG) { ls1[threadIdx.x] = 0.f; ls2[threadIdx.x] = 0.f; }
  __syncthreads();
  int gw = (int)((blockIdx.x * 256u + threadIdx.x) >> 6);
  int ntile = nE >> 4;
  bool act = gw < ntile;
  int lane = threadIdx.x & 63;
  int colb = lane & 15;
  int ko = (lane >> 4) << 3;
  int rowb = (lane >> 4) << 2;
  float sr[4] = {0.f,0.f,0.f,0.f}, ssr[4] = {0.f,0.f,0.f,0.f};
  if (act) {
    int sI[4], dI[4];
#pragma unroll
    for (int r = 0; r < 4; ++r) {
      int e_r = (gw << 4) + rowb + r;
      sI[r] = ei[e_r]; dI[r] = ei[nE + e_r];
    }
    bf16x4_t g1[4], g2[4]; bf16x8_t g3[4], g4[4];
#pragma unroll
    for (int r = 0; r < 4; ++r) {
      g1[r] = *(const bf16x4_t*)(P + (size_t)sI[r] * 384 + colb * 4);
      g2[r] = *(const bf16x4_t*)(P + (size_t)dI[r] * 384 + 64 + colb * 4);
      g3[r] = *(const bf16x8_t*)(P + (size_t)sI[r] * 384 + 128 + colb * 8);
      g4[r] = *(const bf16x8_t*)(P + (size_t)dI[r] * 384 + 256 + colb * 8);
    }
    int row = (gw << 4) + colb;
    int ge = ebatch[row];
    const float* er = e_in + (size_t)row * 64;
    f32x4_t acc[4] = {};
#pragma unroll
    for (int c2 = 0; c2 < 2; ++c2) {
      int fb = c2 * 32 + ko;
      float4 f0 = *(const float4*)(er + fb);
      float4 f1 = *(const float4*)(er + fb + 4);
      float vv[8] = {f0.x,f0.y,f0.z,f0.w,f1.x,f1.y,f1.z,f1.w};
      bf16x8_t a;
#pragma unroll
      for (int k = 0; k < 8; ++k) a[k] = (short)f2bf(vv[k] * lA[ge*64 + fb + k] + lB[ge*64 + fb + k]);
#pragma unroll
      for (int nb = 0; nb < 4; ++nb) {
        bf16x8_t b = *(const bf16x8_t*)(Wt + (size_t)(nb * 16 + colb) * 320 + (8 + c2) * 32 + ko);
        acc[nb] = __builtin_amdgcn_mfma_f32_16x16x32_bf16(a, b, acc[nb], 0, 0, 0);
      }
    }
#pragma unroll
    for (int r = 0; r < 4; ++r) {
      int e_ = (gw << 4) + rowb + r;
      int gr = ebatch[e_];
#pragma unroll
      for (int nb = 0; nb < 4; ++nb) {
        int col = nb * 16 + colb;
        size_t off = (size_t)e_ * 64 + col;
        float vv = e_in[off] * lA[gr*64 + col] + lB[gr*64 + col] + bias[col]
                 + acc[nb][r] + bf2f((unsigned short)g1[r][nb]) + bf2f((unsigned short)g2[r][nb]);
        e_out[off] = vv;
        sr[r] += vv; ssr[r] += vv * vv;
      }
      bf16x8_t pv;
#pragma unroll
      for (int k = 0; k < 8; ++k)
        pv[k] = (short)f2bf(bf2f((unsigned short)g3[r][k]) + bf2f((unsigned short)g4[r][k]));
      *(bf16x8_t*)(pn + (size_t)e_ * 128 + colb * 8) = pv;
    }
  }
#pragma unroll
  for (int m = 1; m <= 8; m <<= 1)
#pragma unroll
    for (int r = 0; r < 4; ++r) { sr[r] += __shfl_xor(sr[r], m); ssr[r] += __shfl_xor(ssr[r], m); }
  if (act && colb == 0) {
#pragma unroll
    for (int r = 0; r < 4; ++r) {
      int g = ebatch[(gw << 4) + rowb + r];
      atomicAdd(&ls1[g], sr[r]); atomicAdd(&ls2[g], ssr[r]);
    }
  }
  __syncthreads();
  if (threadIdx.x < NG) {
    atomicAdd(&gs1[threadIdx.x], ls1[threadIdx.x]);
    atomicAdd(&gs2[threadIdx.x], ls2[threadIdx.x]);
  }
}

// =====================================================================
// ANGLE stage (PE path): a_out = affAin(a_in)+[eB1_s|eB1_d|affAin(a_in)]@Wea+b (+stats)
//                        pe = PE_T3[s] + PE_T4[d]  -> msg (swizzled)
// =====================================================================
__global__ __launch_bounds__(256) void k_angle(
    const unsigned short* __restrict__ eB1, const unsigned short* __restrict__ PE,
    const float* a_in, float* a_out,
    const int* __restrict__ ti, const int* __restrict__ abatch,
    const unsigned short* __restrict__ Wt, const float* __restrict__ bias,
    const float* __restrict__ afAA, const float* __restrict__ afAB,
    float* __restrict__ gs1, float* __restrict__ gs2,
    unsigned short* __restrict__ pe, int nA)
{
  __shared__ float lAA[1024], lAB[1024];
  __shared__ float ls1[NG], ls2[NG];
  for (int i = threadIdx.x; i < 1024; i += 256) { lAA[i] = afAA[i]; lAB[i] = afAB[i]; }
  if (threadIdx.x < NG) { ls1[threadIdx.x] = 0.f; ls2[threadIdx.x] = 0.f; }
  __syncthreads();
  int gw = (int)((blockIdx.x * 256u + threadIdx.x) >> 6);
  int ntile = nA >> 4;
  bool act = gw < ntile;
  int lane = threadIdx.x & 63;
  int colb = lane & 15;
  int ko = (lane >> 4) << 3;
  int rowb = (lane >> 4) << 2;
  float sr[4] = {0.f,0.f,0.f,0.f}, ssr[4] = {0.f,0.f,0.f,0.f};
  if (act) {
    int sI[4], dI[4];
#pragma unroll
    for (int r = 0; r < 4; ++r) {
      int a_r = (gw << 4) + rowb + r;
      sI[r] = ti[a_r]; dI[r] = ti[nA + a_r];
    }
    bf16x4_t g3[4], g4[4];
#pragma unroll
    for (int r = 0; r < 4; ++r) {
      g3[r] = *(const bf16x4_t*)(PE + (size_t)sI[r] * 128 + colb * 4);
      g4[r] = *(const bf16x4_t*)(PE + (size_t)dI[r] * 128 + 64 + colb * 4);
    }
    int row = (gw << 4) + colb;
    int s = ti[row], d = ti[nA + row];
    int ga = abatch[row];
    const unsigned short* es = eB1 + (size_t)s * 64;
    const unsigned short* ed = eB1 + (size_t)d * 64;
    const float* ar = a_in + (size_t)row * 64;
    f32x4_t acc[4] = {};
#pragma unroll
    for (int c = 0; c < 6; ++c) {
      bf16x8_t a;
      if (c < 4) {
        const unsigned short* bp = (c < 2) ? es + c * 32 : ed + (c - 2) * 32;
        a = *(const bf16x8_t*)(bp + ko);
      } else {
        int fb = (c - 4) * 32 + ko;
        float4 f0 = *(const float4*)(ar + fb);
        float4 f1 = *(const float4*)(ar + fb + 4);
        float vv[8] = {f0.x,f0.y,f0.z,f0.w,f1.x,f1.y,f1.z,f1.w};
#pragma unroll
        for (int k = 0; k < 8; ++k) a[k] = (short)f2bf(vv[k] * lAA[ga*64 + fb + k] + lAB[ga*64 + fb + k]);
      }
#pragma unroll
      for (int nb = 0; nb < 4; ++nb) {
        bf16x8_t b = *(const bf16x8_t*)(Wt + (size_t)(nb * 16 + colb) * 192 + c * 32 + ko);
        acc[nb] = __builtin_amdgcn_mfma_f32_16x16x32_bf16(a, b, acc[nb], 0, 0, 0);
      }
    }
#pragma unroll
    for (int r = 0; r < 4; ++r) {
      int a_ = (gw << 4) + rowb + r;
      int gr = abatch[a_];
#pragma unroll
      for (int nb = 0; nb < 4; ++nb) {
        int col = nb * 16 + colb;
        size_t off = (size_t)a_ * 64 + col;
        float vv = a_in[off] * lAA[gr*64 + col] + lAB[gr*64 + col] + bias[col] + acc[nb][r];
        a_out[off] = vv;
        sr[r] += vv; ssr[r] += vv * vv;
      }
      bf16x4_t pv;
#pragma unroll
      for (int nb = 0; nb < 4; ++nb)
        pv[nb] = (short)f2bf(bf2f((unsigned short)g3[r][nb]) + bf2f((unsigned short)g4[r][nb]));
      *(bf16x4_t*)(pe + (size_t)a_ * 64 + colb * 4) = pv;
    }
  }
#pragma unroll
  for (int m = 1; m <= 8; m <<= 1)
#pragma unroll
    for (int r = 0; r < 4; ++r) { sr[r] += __shfl_xor(sr[r], m); ssr[r] += __shfl_xor(ssr[r], m); }
  if (act && colb == 0) {
#pragma unroll
    for (int r = 0; r < 4; ++r) {
      int g = abatch[(gw << 4) + rowb + r];
      atomicAdd(&ls1[g], sr[r]); atomicAdd(&ls2[g], ssr[r]);
    }
  }
  __syncthreads();
  if (threadIdx.x < NG) {
    atomicAdd(&gs1[threadIdx.x], ls1[threadIdx.x]);
    atomicAdd(&gs2[threadIdx.x], ls2[threadIdx.x]);
  }
}

// =====================================================================
// emp finish (pure stream): msg = relu(pe + affA1(a1)@Wemp_a + b)
// Reads pe swizzled (8B/lane), writes msg standard layout IN PLACE.
// Safe: per-wave tile-private; loads complete before dependent stores.
// =====================================================================
__global__ __launch_bounds__(256) void k_fin_emp(
    const float* __restrict__ a_, const int* __restrict__ abatch,
    const unsigned short* __restrict__ Wt,    // wt_emp [64][192]
    const float* __restrict__ bias,
    const float* __restrict__ afAA, const float* __restrict__ afAB,
    unsigned short* __restrict__ msg, int nA)
{
  __shared__ float lAA[1024], lAB[1024];
  for (int i = threadIdx.x; i < 1024; i += 256) { lAA[i] = afAA[i]; lAB[i] = afAB[i]; }
  __syncthreads();
  int gw = (int)((blockIdx.x * 256u + threadIdx.x) >> 6);
  int ntile = nA >> 4;
  if (gw >= ntile) return;
  int lane = threadIdx.x & 63;
  int colb = lane & 15;
  int ko = (lane >> 4) << 3;
  int rowb = (lane >> 4) << 2;
  int row = (gw << 4) + colb;
  int ga = abatch[row];
  const float* ar = a_ + (size_t)row * 64;
  f32x4_t acc[4] = {};
#pragma unroll
  for (int c2 = 0; c2 < 2; ++c2) {
    int fb = c2 * 32 + ko;
    float4 f0 = *(const float4*)(ar + fb);
    float4 f1 = *(const float4*)(ar + fb + 4);
    float vv[8] = {f0.x,f0.y,f0.z,f0.w,f1.x,f1.y,f1.z,f1.w};
    bf16x8_t a;
#pragma unroll
    for (int k = 0; k < 8; ++k) a[k] = (short)f2bf(vv[k] * lAA[ga*64 + fb + k] + lAB[ga*64 + fb + k]);
#pragma unroll
    for (int nb = 0; nb < 4; ++nb) {
      bf16x8_t b = *(const bf16x8_t*)(Wt + (size_t)(nb * 16 + colb) * 192 + 128 + c2 * 32 + ko);
      acc[nb] = __builtin_amdgcn_mfma_f32_16x16x32_bf16(a, b, acc[nb], 0, 0, 0);
    }
  }
  bf16x4_t p4[4];
#pragma unroll
  for (int r = 0; r < 4; ++r)
    p4[r] = *(const bf16x4_t*)(msg + (size_t)((gw << 4) + rowb + r) * 64 + colb * 4);
#pragma unroll
  for (int r = 0; r < 4; ++r) {
    int a_idx = (gw << 4) + rowb + r;
#pragma unroll
    for (int nb = 0; nb < 4; ++nb) {
      int col = nb * 16 + colb;
      float v = fmaxf(acc[nb][r] + bf2f((unsigned short)p4[r][nb]) + bias[col], 0.f);
      msg[(size_t)a_idx * 64 + col] = f2bf(v);
    }
  }
}

// =====================================================================
// nmp finish (pure stream): msg = relu(pn + affE2(e2)@Wnmp_e + b)
// =====================================================================
__global__ __launch_bounds__(256) void k_fin_nmp(
    const float* __restrict__ e, const int* __restrict__ ebatch,
    const unsigned short* __restrict__ Wt,    // wt_nmp [128][320]
    const float* __restrict__ bias,
    const float* __restrict__ afEA, const float* __restrict__ afEB,
    const unsigned short* __restrict__ pn,
    unsigned short* __restrict__ msg, int nE)
{
  __shared__ float lEA[1024], lEB[1024];
  for (int i = threadIdx.x; i < 1024; i += 256) { lEA[i] = afEA[i]; lEB[i] = afEB[i]; }
  __syncthreads();
  int gw = (int)((blockIdx.x * 256u + threadIdx.x) >> 6);
  int ntile = nE >> 4;
  if (gw >= ntile) return;
  int lane = threadIdx.x & 63;
  int colb = lane & 15;
  int ko = (lane >> 4) << 3;
  int rowb = (lane >> 4) << 2;
  int row = (gw << 4) + colb;
  int ge = ebatch[row];
  const float* er = e + (size_t)row * 64;
  f32x4_t acc[8] = {};
#pragma unroll
  for (int c2 = 0; c2 < 2; ++c2) {
    int fb = c2 * 32 + ko;
    float4 f0 = *(const float4*)(er + fb);
    float4 f1 = *(const float4*)(er + fb + 4);
    float vv[8] = {f0.x,f0.y,f0.z,f0.w,f1.x,f1.y,f1.z,f1.w};
    bf16x8_t a;
#pragma unroll
    for (int k = 0; k < 8; ++k) a[k] = (short)f2bf(vv[k] * lEA[ge*64 + fb + k] + lEB[ge*64 + fb + k]);
#pragma unroll
    for (int nb = 0; nb < 8; ++nb) {
      bf16x8_t b = *(const bf16x8_t*)(Wt + (size_t)(nb * 16 + colb) * 320 + (8 + c2) * 32 + ko);
      acc[nb] = __builtin_amdgcn_mfma_f32_16x16x32_bf16(a, b, acc[nb], 0, 0, 0);
    }
  }
#pragma unroll
  for (int r = 0; r < 4; ++r) {
    int e_ = (gw << 4) + rowb + r;
    bf16x8_t p8 = *(const bf16x8_t*)(pn + (size_t)e_ * 128 + colb * 8);
#pragma unroll
    for (int nb = 0; nb < 8; ++nb) {
      int col = nb * 16 + colb;
      float v = fmaxf(acc[nb][r] + bf2f((unsigned short)p8[nb]) + bias[col], 0.f);
      msg[(size_t)e_ * 128 + col] = f2bf(v);
    }
  }
}

// =====================================================================
// FALLBACK: ANGLE update MM (R6 version, no PE).
// =====================================================================
__global__ __launch_bounds__(256) void k_mm_angle(
    const unsigned short* __restrict__ eB1, const float* a_in, float* a_out,
    const int* __restrict__ ti, const int* __restrict__ abatch,
    const unsigned short* __restrict__ Wt, const float* __restrict__ bias,
    const float* __restrict__ afAA, const float* __restrict__ afAB,
    float* __restrict__ gs1, float* __restrict__ gs2, int nA)
{
  __shared__ float lAA[1024], lAB[1024];
  __shared__ float ls1[NG], ls2[NG];
  for (int i = threadIdx.x; i < 1024; i += 256) { lAA[i] = afAA[i]; lAB[i] = afAB[i]; }
  if (threadIdx.x < NG) { ls1[threadIdx.x] = 0.f; ls2[threadIdx.x] = 0.f; }
  __syncthreads();
  int gw = (int)((blockIdx.x * 256u + threadIdx.x) >> 6);
  int ntile = nA >> 4;
  bool act = gw < ntile;
  int lane = threadIdx.x & 63;
  int colb = lane & 15;
  int ko = (lane >> 4) << 3;
  int rowb = (lane >> 4) << 2;
  float sr[4] = {0.f,0.f,0.f,0.f}, ssr[4] = {0.f,0.f,0.f,0.f};
  if (act) {
    int row = (gw << 4) + colb;
    int s = ti[row], d = ti[nA + row];
    int ga = abatch[row];
    const unsigned short* es = eB1 + (size_t)s * 64;
    const unsigned short* ed = eB1 + (size_t)d * 64;
    const float* ar = a_in + (size_t)row * 64;
    f32x4_t acc[4] = {};
#pragma unroll
    for (int c = 0; c < 6; ++c) {
      bf16x8_t a;
      if (c < 4) {
        const unsigned short* bp = (c < 2) ? es + c * 32 : ed + (c - 2) * 32;
        a = *(const bf16x8_t*)(bp + ko);
      } else {
        int fb = (c - 4) * 32 + ko;
        float4 f0 = *(const float4*)(ar + fb);
        float4 f1 = *(const float4*)(ar + fb + 4);
        float vv[8] = {f0.x,f0.y,f0.z,f0.w,f1.x,f1.y,f1.z,f1.w};
#pragma unroll
        for (int k = 0; k < 8; ++k) a[k] = (short)f2bf(vv[k] * lAA[ga*64 + fb + k] + lAB[ga*64 + fb + k]);
      }
#pragma unroll
      for (int nb = 0; nb < 4; ++nb) {
        bf16x8_t b = *(const bf16x8_t*)(Wt + (size_t)(nb * 16 + colb) * 192 + c * 32 + ko);
        acc[nb] = __builtin_amdgcn_mfma_f32_16x16x32_bf16(a, b, acc[nb], 0, 0, 0);
      }
    }
#pragma unroll
    for (int r = 0; r < 4; ++r) {
      int a_ = (gw << 4) + rowb + r;
      int gr = abatch[a_];
#pragma unroll
      for (int nb = 0; nb < 4; ++nb) {
        int col = nb * 16 + colb;
        size_t off = (size_t)a_ * 64 + col;
        float vv = a_in[off] * lAA[gr*64 + col] + lAB[gr*64 + col] + bias[col] + acc[nb][r];
        a_out[off] = vv;
        sr[r] += vv; ssr[r] += vv * vv;
      }
    }
  }
#pragma unroll
  for (int m = 1; m <= 8; m <<= 1)
#pragma unroll
    for (int r = 0; r < 4; ++r) { sr[r] += __shfl_xor(sr[r], m); ssr[r] += __shfl_xor(ssr[r], m); }
  if (act && colb == 0) {
#pragma unroll
    for (int r = 0; r < 4; ++r) {
      int g = abatch[(gw << 4) + rowb + r];
      atomicAdd(&ls1[g], sr[r]); atomicAdd(&ls2[g], ssr[r]);
    }
  }
  __syncthreads();
  if (threadIdx.x < NG) {
    atomicAdd(&gs1[threadIdx.x], ls1[threadIdx.x]);
    atomicAdd(&gs2[threadIdx.x], ls2[threadIdx.x]);
  }
}

// =====================================================================
// FALLBACK: edge_graph_mp message MM (R6 version).
// =====================================================================
__global__ __launch_bounds__(256) void k_mm_emp(
    const unsigned short* __restrict__ eB1, const float* __restrict__ a_,
    const int* __restrict__ ti, const int* __restrict__ abatch,
    const unsigned short* __restrict__ Wt, const float* __restrict__ bias,
    const float* __restrict__ afAA, const float* __restrict__ afAB,
    unsigned short* __restrict__ msg, int nA)
{
  __shared__ float lAA[1024], lAB[1024];
  for (int i = threadIdx.x; i < 1024; i += 256) { lAA[i] = afAA[i]; lAB[i] = afAB[i]; }
  __syncthreads();
  int gw = (int)((blockIdx.x * 256u + threadIdx.x) >> 6);
  int ntile = nA >> 4;
  if (gw >= ntile) return;
  int lane = threadIdx.x & 63;
  int colb = lane & 15;
  int ko = (lane >> 4) << 3;
  int rowb = (lane >> 4) << 2;
  int row = (gw << 4) + colb;
  int s = ti[row], d = ti[nA + row];
  int ga = abatch[row];
  const unsigned short* es = eB1 + (size_t)s * 64;
  const unsigned short* ed = eB1 + (size_t)d * 64;
  const float* ar = a_ + (size_t)row * 64;
  f32x4_t acc[4] = {};
#pragma unroll
  for (int c = 0; c < 6; ++c) {
    bf16x8_t a;
    if (c < 4) {
      const unsigned short* bp = (c < 2) ? es + c * 32 : ed + (c - 2) * 32;
      a = *(const bf16x8_t*)(bp + ko);
    } else {
      int fb = (c - 4) * 32 + ko;
      float4 f0 = *(const float4*)(ar + fb);
      float4 f1 = *(const float4*)(ar + fb + 4);
      float vv[8] = {f0.x,f0.y,f0.z,f0.w,f1.x,f1.y,f1.z,f1.w};
#pragma unroll
      for (int k = 0; k < 8; ++k) a[k] = (short)f2bf(vv[k] * lAA[ga*64 + fb + k] + lAB[ga*64 + fb + k]);
    }
#pragma unroll
    for (int nb = 0; nb < 4; ++nb) {
      bf16x8_t b = *(const bf16x8_t*)(Wt + (size_t)(nb * 16 + colb) * 192 + c * 32 + ko);
      acc[nb] = __builtin_amdgcn_mfma_f32_16x16x32_bf16(a, b, acc[nb], 0, 0, 0);
    }
  }
#pragma unroll
  for (int r = 0; r < 4; ++r) {
    int a_idx = (gw << 4) + rowb + r;
#pragma unroll
    for (int nb = 0; nb < 4; ++nb) {
      int col = nb * 16 + colb;
      float v = fmaxf(acc[nb][r] + bias[col], 0.f);
      msg[(size_t)a_idx * 64 + col] = f2bf(v);
    }
  }
}

// =====================================================================
// CSR gather-reduce over edges.
// =====================================================================
__global__ __launch_bounds__(256) void k_red_e(
    const unsigned short* __restrict__ msg, const float* e_in, float* e_out,
    const int* __restrict__ ptr, const int* __restrict__ perm,
    const int* __restrict__ ebatch,
    const float* __restrict__ afA, const float* __restrict__ afB,
    float* __restrict__ gs1, float* __restrict__ gs2, int nE)
{
  __shared__ float lA[1024], lB[1024], ls1[NG], ls2[NG];
  for (int i = threadIdx.x; i < 1024; i += 256) { lA[i] = afA[i]; lB[i] = afB[i]; }
  if (threadIdx.x < NG) { ls1[threadIdx.x] = 0.f; ls2[threadIdx.x] = 0.f; }
  __syncthreads();
  int lane = threadIdx.x & 63;
  int wv = (int)((blockIdx.x * 256u + threadIdx.x) >> 6);
  int nw = (int)((gridDim.x * 256u) >> 6);
  for (int eidx = wv; eidx < nE; eidx += nw) {
    int p0 = ptr[eidx], p1 = ptr[eidx + 1];
    float sum = 0.f;
    for (int j = p0; j < p1; ++j) {
      int aidx = perm[j];
      sum += bf2f(msg[(size_t)aidx * 64 + lane]);
    }
    int g = ebatch[eidx];
    size_t off = (size_t)eidx * 64 + lane;
    float v = e_in[off] * lA[g*64 + lane] + lB[g*64 + lane] + sum;
    e_out[off] = v;
    float s = v, ss = v * v;
#pragma unroll
    for (int m = 1; m < 64; m <<= 1) { s += __shfl_xor(s, m); ss += __shfl_xor(ss, m); }
    if (lane == 0) { atomicAdd(&ls1[g], s); atomicAdd(&ls2[g], ss); }
  }
  __syncthreads();
  if (threadIdx.x < NG) {
    atomicAdd(&gs1[threadIdx.x], ls1[threadIdx.x]);
    atomicAdd(&gs2[threadIdx.x], ls2[threadIdx.x]);
  }
}

// =====================================================================
// CSR gather-reduce over nodes.
// =====================================================================
__global__ __launch_bounds__(256) void k_red_n(
    const unsigned short* __restrict__ msg, const float* x_in, float* out,
    const int* __restrict__ ptr, const int* __restrict__ perm,
    const int* __restrict__ nbatch,
    float* __restrict__ gs1, float* __restrict__ gs2, int nN)
{
  __shared__ float ls1[NG], ls2[NG];
  if (threadIdx.x < NG) { ls1[threadIdx.x] = 0.f; ls2[threadIdx.x] = 0.f; }
  __syncthreads();
  int lane = threadIdx.x & 63;
  int wv = (int)((blockIdx.x * 256u + threadIdx.x) >> 6);
  int nw = (int)((gridDim.x * 256u) >> 6);
  for (int n = wv; n < nN; n += nw) {
    int p0 = ptr[n], p1 = ptr[n + 1];
    float s0 = 0.f, s1v = 0.f;
    for (int j = p0; j < p1; ++j) {
      int e = perm[j];
      unsigned u = *(const unsigned*)(msg + (size_t)e * 128 + lane * 2);
      s0 += bf2f((unsigned short)(u & 0xffffu));
      s1v += bf2f((unsigned short)(u >> 16));
    }
    size_t off = (size_t)n * 128 + lane * 2;
    float h0 = x_in[off] + s0, h1 = x_in[off + 1] + s1v;
    out[off] = h0; out[off + 1] = h1;
    float s = h0 + h1, ss = h0 * h0 + h1 * h1;
#pragma unroll
    for (int m = 1; m < 64; m <<= 1) { s += __shfl_xor(s, m); ss += __shfl_xor(ss, m); }
    if (lane == 0) { int g = nbatch[n]; atomicAdd(&ls1[g], s); atomicAdd(&ls2[g], ss); }
  }
  __syncthreads();
  if (threadIdx.x < NG) {
    atomicAdd(&gs1[threadIdx.x], ls1[threadIdx.x]);
    atomicAdd(&gs2[threadIdx.x], ls2[threadIdx.x]);
  }
}

// ---- affine table construction ----
__global__ __launch_bounds__(256) void k_mkaff(
    const float* __restrict__ s1, const float* __restrict__ s2,
    const float* __restrict__ cnt, int F,
    const float* __restrict__ w, const float* __restrict__ b,
    float* __restrict__ A, float* __restrict__ B)
{
  int idx = blockIdx.x * 256 + threadIdx.x;
  if (idx >= NG * F) return;
  int g = idx / F, f = idx - g * F;
  float norm = fmaxf(cnt[g], 1.f) * (float)F;
  float m = s1[g] / norm;
  float var = s2[g] / norm - m * m;
  float inv = rsqrtf(var + EPS);
  float a = inv * w[f];
  A[idx] = a;
  B[idx] = b[f] - m * a;
}

__global__ __launch_bounds__(256) void k_idaff(float* __restrict__ A, float* __restrict__ B, int n)
{
  int idx = blockIdx.x * 256 + threadIdx.x;
  if (idx < n) { A[idx] = 1.f; B[idx] = 0.f; }
}

// ---- stream: eB1 = bf16(affE1(eA)) ----
__global__ __launch_bounds__(256) void k_norm_ebf(
    const float* __restrict__ e, const int* __restrict__ ebatch,
    const float* __restrict__ afA, const float* __restrict__ afB,
    unsigned short* __restrict__ eB, int nE)
{
  int total = nE * 8;
  int stride = gridDim.x * 256;
  for (int idx = blockIdx.x * 256 + threadIdx.x; idx < total; idx += stride) {
    int row = idx >> 3, q = (idx & 7) * 8;
    int g = ebatch[row];
    const float* er = e + (size_t)row * 64 + q;
    float4 f0 = *(const float4*)er;
    float4 f1 = *(const float4*)(er + 4);
    float vv[8] = {f0.x,f0.y,f0.z,f0.w,f1.x,f1.y,f1.z,f1.w};
    bf16x8_t o;
#pragma unroll
    for (int k = 0; k < 8; ++k) o[k] = (short)f2bf(vv[k] * afA[g*64 + q + k] + afB[g*64 + q + k]);
    *(bf16x8_t*)(eB + (size_t)row * 64 + q) = o;
  }
}

// ---- apply norm to x (in-place) ----
__global__ __launch_bounds__(256) void k_apply(
    float* h, const int* __restrict__ batch,
    const float* __restrict__ A, const float* __restrict__ B, int nN)
{
  int total = nN * 16;
  int stride = gridDim.x * 256;
  for (int idx = blockIdx.x * 256 + threadIdx.x; idx < total; idx += stride) {
    int row = idx >> 4, q = (idx & 15) * 8;
    int g = batch[row];
    float* hp = h + (size_t)row * 128 + q;
    float4 f0 = *(const float4*)hp;
    float4 f1 = *(const float4*)(hp + 4);
    float vv[8] = {f0.x,f0.y,f0.z,f0.w,f1.x,f1.y,f1.z,f1.w};
#pragma unroll
    for (int k = 0; k < 8; ++k) vv[k] = vv[k] * A[(g << 7) + q + k] + B[(g << 7) + q + k];
    float4 g0 = {vv[0],vv[1],vv[2],vv[3]}, g1 = {vv[4],vv[5],vv[6],vv[7]};
    *(float4*)hp = g0;
    *(float4*)(hp + 4) = g1;
  }
}

__global__ __launch_bounds__(256) void k_count(
    const int* __restrict__ batch, int n, float* __restrict__ cnt)
{
  __shared__ float lc[NG];
  if (threadIdx.x < NG) lc[threadIdx.x] = 0.f;
  __syncthreads();
  for (int i = blockIdx.x * 256 + threadIdx.x; i < n; i += gridDim.x * 256)
    atomicAdd(&lc[batch[i]], 1.f);
  __syncthreads();
  if (threadIdx.x < NG) atomicAdd(&cnt[threadIdx.x], lc[threadIdx.x]);
}

// ---- CSR build ----
__global__ __launch_bounds__(256) void k_hist(
    const int* __restrict__ dst, int n, int* __restrict__ cnt)
{
  for (int i = blockIdx.x * 256 + threadIdx.x; i < n; i += gridDim.x * 256)
    atomicAdd(&cnt[dst[i]], 1);
}

__global__ __launch_bounds__(256) void k_scan1(
    const int* __restrict__ in, int* __restrict__ out, int* __restrict__ bsum, int n)
{
  __shared__ int wtot[4];
  int tid = threadIdx.x, lane = tid & 63, wid = tid >> 6;
  int base = blockIdx.x * 1024 + tid * 4;
  int v[4];
#pragma unroll
  for (int k = 0; k < 4; ++k) v[k] = (base + k < n) ? in[base + k] : 0;
  int tsum = v[0] + v[1] + v[2] + v[3];
  int incl = tsum;
#pragma unroll
  for (int off = 1; off < 64; off <<= 1) {
    int up = __shfl_up(incl, off);
    if (lane >= off) incl += up;
  }
  if (lane == 63) wtot[wid] = incl;
  __syncthreads();
  if (tid == 0) {
    int r = 0;
#pragma unroll
    for (int w2 = 0; w2 < 4; ++w2) { int t = wtot[w2]; wtot[w2] = r; r += t; }
    bsum[blockIdx.x] = r;
  }
  __syncthreads();
  int excl = wtot[wid] + incl - tsum;
#pragma unroll
  for (int k = 0; k < 4; ++k) {
    if (base + k < n) out[base + k] = excl;
    excl += v[k];
  }
}

__global__ __launch_bounds__(256) void k_scan2(int* __restrict__ bsum, int nb, int* __restrict__ total_out)
{
  __shared__ int wtot[4];
  int tid = threadIdx.x, lane = tid & 63, wid = tid >> 6;
  int base = tid * 4;
  int v[4];
#pragma unroll
  for (int k = 0; k < 4; ++k) v[k] = (base + k < nb) ? bsum[base + k] : 0;
  int tsum = v[0] + v[1] + v[2] + v[3];
  int incl = tsum;
#pragma unroll
  for (int off = 1; off < 64; off <<= 1) {
    int up = __shfl_up(incl, off);
    if (lane >= off) incl += up;
  }
  if (lane == 63) wtot[wid] = incl;
  __syncthreads();
  if (tid == 0) {
    int r = 0;
#pragma unroll
    for (int w2 = 0; w2 < 4; ++w2) { int t = wtot[w2]; wtot[w2] = r; r += t; }
    *total_out = r;
  }
  __syncthreads();
  int excl = wtot[wid] + incl - tsum;
#pragma unroll
  for (int k = 0; k < 4; ++k) {
    if (base + k < nb) bsum[base + k] = excl;
    excl += v[k];
  }
}

__global__ __launch_bounds__(256) void k_scan3(
    int* __restrict__ ptr, int* __restrict__ cur, const int* __restrict__ bsum, int n)
{
  for (int i = blockIdx.x * 256 + threadIdx.x; i < n; i += gridDim.x * 256) {
    int v = ptr[i] + bsum[i >> 10];
    ptr[i] = v; cur[i] = v;
  }
}

__global__ __launch_bounds__(256) void k_scatter(
    const int* __restrict__ dst, int* __restrict__ cur, int* __restrict__ perm, int n)
{
  for (int i = blockIdx.x * 256 + threadIdx.x; i < n; i += gridDim.x * 256) {
    int d = dst[i];
    int p = atomicAdd(&cur[d], 1);
    perm[p] = i;
  }
}

// ---- weight prep ----
__global__ __launch_bounds__(256) void k_wt(
    const float* __restrict__ W, unsigned short* __restrict__ Wt, int K, int NO)
{
  int idx = blockIdx.x * 256 + threadIdx.x;
  if (idx >= K * NO) return;
  int k = idx / NO, j = idx - k * NO;
  Wt[(size_t)j * K + k] = f2bf(W[idx]);
}

extern "C" void kernel_launch(void* const* d_in, const int* in_sizes, int n_in,
                              void* d_out, int out_size, void* d_ws, size_t ws_size,
                              hipStream_t stream)
{
  const float* x0    = (const float*)d_in[0];
  const float* e0    = (const float*)d_in[1];
  const float* a0    = (const float*)d_in[2];
  const float* W_ne  = (const float*)d_in[3];
  const float* b_ne  = (const float*)d_in[4];
  const float* g_e   = (const float*)d_in[5];
  const float* be_e  = (const float*)d_in[6];
  const float* W_ea  = (const float*)d_in[7];
  const float* b_ea  = (const float*)d_in[8];
  const float* g_a   = (const float*)d_in[9];
  const float* be_a  = (const float*)d_in[10];
  const float* W_emp = (const float*)d_in[11];
  const float* b_emp = (const float*)d_in[12];
  const float* g_emp = (const float*)d_in[13];
  const float* be_emp= (const float*)d_in[14];
  const float* W_nmp = (const float*)d_in[15];
  const float* b_nmp = (const float*)d_in[16];
  const float* g_nmp = (const float*)d_in[17];
  const float* be_nmp= (const float*)d_in[18];
  const int* node_batch  = (const int*)d_in[19];
  const int* edge_index  = (const int*)d_in[20];
  const int* edge_batch  = (const int*)d_in[21];
  const int* tb_index    = (const int*)d_in[22];
  const int* angle_batch = (const int*)d_in[23];

  const int N = in_sizes[0] / 128;
  const int E = in_sizes[1] / 64;
  const int A = in_sizes[2] / 64;

  // ---- workspace layout (bytes, 256-aligned) ----
  char* wsp = (char*)d_ws;
  auto alloc = [&](size_t bytes) { char* p = wsp; wsp += (bytes + 255) & ~(size_t)255; return p; };
  float*          eA     = (float*)alloc((size_t)E * 64 * 4);
  float*          aA     = (float*)alloc((size_t)A * 64 * 4);
  unsigned short* msg    = (unsigned short*)alloc((size_t)A * 64 * 2);  // hosts P, pe, msg_e, msg_n
  unsigned short* pn     = (unsigned short*)alloc((size_t)E * 128 * 2); // nmp x-partial (swizzled)
  unsigned short* eB1    = (unsigned short*)alloc((size_t)E * 64 * 2);  // bf16 affE1(e) gather table
  int* ptr_n  = (int*)alloc((size_t)(N + 1) * 4);
  int* cur_n  = (int*)alloc((size_t)N * 4);
  int* perm_n = (int*)alloc((size_t)E * 4);
  int* ptr_e  = (int*)alloc((size_t)(E + 1) * 4);
  int* cur_e  = (int*)alloc((size_t)E * 4);
  int* perm_e = (int*)alloc((size_t)A * 4);
  int* bsum   = (int*)alloc(4096 * 4);
  float* stats = (float*)alloc(5 * NG * 4);   // contiguous: s1,s2,cnt_n,cnt_e,cnt_a
  float* s1    = stats;
  float* s2    = stats + NG;
  float* cnt_n = stats + 2 * NG;
  float* cnt_e = stats + 3 * NG;
  float* cnt_a = stats + 4 * NG;
  float* afE_idA = (float*)alloc(1024 * 4); float* afE_idB = (float*)alloc(1024 * 4);
  float* afA_idA = (float*)alloc(1024 * 4); float* afA_idB = (float*)alloc(1024 * 4);
  float* afE1A   = (float*)alloc(1024 * 4); float* afE1B   = (float*)alloc(1024 * 4);
  float* afE2A   = (float*)alloc(1024 * 4); float* afE2B   = (float*)alloc(1024 * 4);
  float* afA1A   = (float*)alloc(1024 * 4); float* afA1B   = (float*)alloc(1024 * 4);
  float* afXA    = (float*)alloc(2048 * 4); float* afXB    = (float*)alloc(2048 * 4);
  unsigned short* wt_ne  = (unsigned short*)alloc((size_t)2 * 320 * 64 * 2);
  unsigned short* wt_ea  = (unsigned short*)alloc((size_t)2 * 192 * 64 * 2);
  unsigned short* wt_emp = (unsigned short*)alloc((size_t)2 * 192 * 64 * 2);
  unsigned short* wt_nmp = (unsigned short*)alloc((size_t)2 * 320 * 128 * 2);
  // PE allocated LAST; only used if it fits (fallback = R6 path).
  unsigned short* PE     = (unsigned short*)alloc((size_t)E * 128 * 2);
  bool usePE = ((size_t)(wsp - (char*)d_ws) <= ws_size);

  unsigned short* P = msg;   // P (N*384 bf16) lives in msg; dead before pe/msg written
  float* x_out = (float*)d_out;

  // ---- one-time prep ----
  for (int i = 0; i < 2; ++i) {
    k_wt<<<(320*64 + 255)/256, 256, 0, stream>>>(W_ne  + (size_t)i*320*64,  wt_ne  + (size_t)i*320*64,  320, 64);
    k_wt<<<(192*64 + 255)/256, 256, 0, stream>>>(W_ea  + (size_t)i*192*64,  wt_ea  + (size_t)i*192*64,  192, 64);
    k_wt<<<(192*64 + 255)/256, 256, 0, stream>>>(W_emp + (size_t)i*192*64,  wt_emp + (size_t)i*192*64,  192, 64);
    k_wt<<<(320*128 + 255)/256, 256, 0, stream>>>(W_nmp + (size_t)i*320*128, wt_nmp + (size_t)i*320*128, 320, 128);
  }
  hipMemsetAsync(stats, 0, 5 * NG * 4, stream);
  k_count<<<512, 256, 0, stream>>>(node_batch, N, cnt_n);
  k_count<<<512, 256, 0, stream>>>(edge_batch, E, cnt_e);
  k_count<<<512, 256, 0, stream>>>(angle_batch, A, cnt_a);
  k_idaff<<<4, 256, 0, stream>>>(afE_idA, afE_idB, 1024);
  k_idaff<<<4, 256, 0, stream>>>(afA_idA, afA_idB, 1024);

  // CSR over nodes (dst of edge_index) and edges (dst of threebody)
  hipMemsetAsync(cur_n, 0, (size_t)N * 4, stream);
  hipMemsetAsync(cur_e, 0, (size_t)E * 4, stream);
  k_hist<<<1024, 256, 0, stream>>>(edge_index + E, E, cur_n);
  k_hist<<<1024, 256, 0, stream>>>(tb_index + A, A, cur_e);
  int nbN = (N + 1023) / 1024, nbE = (E + 1023) / 1024;
  k_scan1<<<nbN, 256, 0, stream>>>(cur_n, ptr_n, bsum, N);
  k_scan2<<<1, 256, 0, stream>>>(bsum, nbN, ptr_n + N);
  k_scan3<<<1024, 256, 0, stream>>>(ptr_n, cur_n, bsum, N);
  k_scatter<<<1024, 256, 0, stream>>>(edge_index + E, cur_n, perm_n, E);
  k_scan1<<<nbE, 256, 0, stream>>>(cur_e, ptr_e, bsum, E);
  k_scan2<<<1, 256, 0, stream>>>(bsum, nbE, ptr_e + E);
  k_scan3<<<1024, 256, 0, stream>>>(ptr_e, cur_e, bsum, E);
  k_scatter<<<1024, 256, 0, stream>>>(tb_index + A, cur_e, perm_e, A);

  const float* x_cur = x0;
  int blkE = (E / 16 + 3) / 4;
  int blkA = (A / 16 + 3) / 4;
  int blkN = (N / 16 + 3) / 4;

  for (int i = 0; i < 2; ++i) {
    const float* e_in  = (i == 0) ? e0 : eA;
    const float* a_in  = (i == 0) ? a0 : aA;
    const float* fEinA = (i == 0) ? afE_idA : afE2A;
    const float* fEinB = (i == 0) ? afE_idB : afE2B;
    const float* fAinA = (i == 0) ? afA_idA : afA1A;
    const float* fAinB = (i == 0) ? afA_idB : afA1B;

    // 0. dense x-partials
    k_dense_x<<<blkN, 256, 0, stream>>>(x_cur, wt_ne + (size_t)i*320*64,
                                        wt_nmp + (size_t)i*320*128, P, N);

    // 1. edge stage (co-gathers stage-4 x-partials) -> affE1, eB1
    hipMemsetAsync(s1, 0, 2 * NG * 4, stream);
    k_edge<<<blkE, 256, 0, stream>>>(P, e_in, eA, edge_index, edge_batch,
                                     wt_ne + (size_t)i*320*64, b_ne + i*64,
                                     fEinA, fEinB, s1, s2, pn, E);
    k_mkaff<<<4, 256, 0, stream>>>(s1, s2, cnt_e, 64, g_e + i*64, be_e + i*64, afE1A, afE1B);
    k_norm_ebf<<<2048, 256, 0, stream>>>(eA, edge_batch, afE1A, afE1B, eB1, E);

    // 1.5 dense emp partials over edges (PE path only)
    if (usePE)
      k_dense_e<<<blkE, 256, 0, stream>>>(eB1, wt_emp + (size_t)i*192*64, PE, E);

    // 2. angle stage -> affA1 (PE path co-gathers emp partials -> pe in msg)
    hipMemsetAsync(s1, 0, 2 * NG * 4, stream);
    if (usePE)
      k_angle<<<blkA, 256, 0, stream>>>(eB1, PE, a_in, aA, tb_index, angle_batch,
                                        wt_ea + (size_t)i*192*64, b_ea + i*64,
                                        fAinA, fAinB, s1, s2, msg, A);
    else
      k_mm_angle<<<blkA, 256, 0, stream>>>(eB1, a_in, aA, tb_index, angle_batch,
                                           wt_ea + (size_t)i*192*64, b_ea + i*64,
                                           fAinA, fAinB, s1, s2, A);
    k_mkaff<<<4, 256, 0, stream>>>(s1, s2, cnt_a, 64, g_a + i*64, be_a + i*64, afA1A, afA1B);

    // 3. emp finish (stream if PE, else gather MM) -> msg; CSR reduce -> affE2
    if (usePE)
      k_fin_emp<<<blkA, 256, 0, stream>>>(aA, angle_batch, wt_emp + (size_t)i*192*64,
                                          b_emp + i*64, afA1A, afA1B, msg, A);
    else
      k_mm_emp<<<blkA, 256, 0, stream>>>(eB1, aA, tb_index, angle_batch,
                                         wt_emp + (size_t)i*192*64, b_emp + i*64,
                                         afA1A, afA1B, msg, A);
    hipMemsetAsync(s1, 0, 2 * NG * 4, stream);
    k_red_e<<<2048, 256, 0, stream>>>(msg, eA, eA, ptr_e, perm_e, edge_batch,
                                      afE1A, afE1B, s1, s2, E);
    k_mkaff<<<4, 256, 0, stream>>>(s1, s2, cnt_e, 64, g_emp + i*64, be_emp + i*64, afE2A, afE2B);

    // 4. nmp finish (stream) -> msg; CSR reduce; apply
    k_fin_nmp<<<blkE, 256, 0, stream>>>(eA, edge_batch, wt_nmp + (size_t)i*320*128,
                                        b_nmp + i*128, afE2A, afE2B, pn, msg, E);
    hipMemsetAsync(s1, 0, 2 * NG * 4, stream);
    k_red_n<<<2048, 256, 0, stream>>>(msg, x_cur, x_out, ptr_n, perm_n, node_batch,
                                      s1, s2, N);
    k_mkaff<<<8, 256, 0, stream>>>(s1, s2, cnt_n, 128, g_nmp + i*128, be_nmp + i*128, afXA, afXB);
    k_apply<<<2048, 256, 0, stream>>>(x_out, node_batch, afXA, afXB, N);

    x_cur = x_out;
  }
}

// Round 8
// 1711.589 us; speedup vs baseline: 1.3598x; 1.0752x over previous
//
#include <hip/hip_runtime.h>

typedef __attribute__((ext_vector_type(8))) short bf16x8_t;
typedef __attribute__((ext_vector_type(4))) short bf16x4_t;
typedef __attribute__((ext_vector_type(4))) float f32x4_t;

constexpr int NG = 16;
constexpr float EPS = 1e-5f;

__device__ inline unsigned short f2bf(float f) {
  unsigned u = __builtin_bit_cast(unsigned, f);
  u += 0x7FFFu + ((u >> 16) & 1u);
  return (unsigned short)(u >> 16);
}
__device__ inline float bf2f(unsigned short u) {
  unsigned x = ((unsigned)u) << 16;
  return __builtin_bit_cast(float, x);
}

// load 8 contiguous elements as f32 from fp32 or bf16 storage
template<bool F32>
__device__ inline void ldrow8(const void* base, size_t off, float v[8]) {
  if constexpr (F32) {
    const float* p = (const float*)base + off;
    float4 f0 = *(const float4*)p, f1 = *(const float4*)(p + 4);
    v[0]=f0.x; v[1]=f0.y; v[2]=f0.z; v[3]=f0.w;
    v[4]=f1.x; v[5]=f1.y; v[6]=f1.z; v[7]=f1.w;
  } else {
    bf16x8_t t = *(const bf16x8_t*)((const unsigned short*)base + off);
#pragma unroll
    for (int k = 0; k < 8; ++k) v[k] = bf2f((unsigned short)t[k]);
  }
}
template<bool F32>
__device__ inline float ldel(const void* base, size_t off) {
  if constexpr (F32) return ((const float*)base)[off];
  return bf2f(((const unsigned short*)base)[off]);
}

// =====================================================================
// Dense partial GEMM over nodes (coalesced):
//   P[n] = x[n] @ [Wne_s | Wne_d | Wnmp_s | Wnmp_d]  (N x 384 bf16, swizzled)
// =====================================================================
__global__ __launch_bounds__(256) void k_dense_x(
    const float* __restrict__ x,
    const unsigned short* __restrict__ WtNE,   // [64][320]
    const unsigned short* __restrict__ WtNM,   // [128][320]
    unsigned short* __restrict__ P, int nN)
{
  int gw = (int)((blockIdx.x * 256u + threadIdx.x) >> 6);
  int ntile = nN >> 4;
  if (gw >= ntile) return;
  int lane = threadIdx.x & 63;
  int colb = lane & 15;
  int ko = (lane >> 4) << 3;
  int rowb = (lane >> 4) << 2;
  int row = (gw << 4) + colb;
  const float* xr = x + (size_t)row * 128;
  f32x4_t a1[4] = {}, a2[4] = {}, a3[8] = {}, a4[8] = {};
#pragma unroll
  for (int c = 0; c < 4; ++c) {
    float4 f0 = *(const float4*)(xr + c * 32 + ko);
    float4 f1 = *(const float4*)(xr + c * 32 + ko + 4);
    float vv[8] = {f0.x,f0.y,f0.z,f0.w,f1.x,f1.y,f1.z,f1.w};
    bf16x8_t a;
#pragma unroll
    for (int k = 0; k < 8; ++k) a[k] = (short)f2bf(vv[k]);
#pragma unroll
    for (int nb = 0; nb < 4; ++nb) {
      bf16x8_t b1 = *(const bf16x8_t*)(WtNE + (size_t)(nb * 16 + colb) * 320 + c * 32 + ko);
      a1[nb] = __builtin_amdgcn_mfma_f32_16x16x32_bf16(a, b1, a1[nb], 0, 0, 0);
      bf16x8_t b2 = *(const bf16x8_t*)(WtNE + (size_t)(nb * 16 + colb) * 320 + (c + 4) * 32 + ko);
      a2[nb] = __builtin_amdgcn_mfma_f32_16x16x32_bf16(a, b2, a2[nb], 0, 0, 0);
    }
#pragma unroll
    for (int nb = 0; nb < 8; ++nb) {
      bf16x8_t b3 = *(const bf16x8_t*)(WtNM + (size_t)(nb * 16 + colb) * 320 + c * 32 + ko);
      a3[nb] = __builtin_amdgcn_mfma_f32_16x16x32_bf16(a, b3, a3[nb], 0, 0, 0);
      bf16x8_t b4 = *(const bf16x8_t*)(WtNM + (size_t)(nb * 16 + colb) * 320 + (c + 4) * 32 + ko);
      a4[nb] = __builtin_amdgcn_mfma_f32_16x16x32_bf16(a, b4, a4[nb], 0, 0, 0);
    }
  }
#pragma unroll
  for (int r = 0; r < 4; ++r) {
    size_t ro = (size_t)((gw << 4) + rowb + r) * 384;
    bf16x4_t t1, t2;
#pragma unroll
    for (int nb = 0; nb < 4; ++nb) { t1[nb] = (short)f2bf(a1[nb][r]); t2[nb] = (short)f2bf(a2[nb][r]); }
    *(bf16x4_t*)(P + ro + colb * 4) = t1;
    *(bf16x4_t*)(P + ro + 64 + colb * 4) = t2;
    bf16x8_t t3, t4;
#pragma unroll
    for (int nb = 0; nb < 8; ++nb) { t3[nb] = (short)f2bf(a3[nb][r]); t4[nb] = (short)f2bf(a4[nb][r]); }
    *(bf16x8_t*)(P + ro + 128 + colb * 8) = t3;
    *(bf16x8_t*)(P + ro + 256 + colb * 8) = t4;
  }
}

// =====================================================================
// Merged e-prep (one read of eAB):
//   eB1[e] = bf16(affE1(e1));  PE[e] = eB1[e] @ [Wemp_s | Wemp_d] (swizzled)
// =====================================================================
__global__ __launch_bounds__(256) void k_prep_e(
    const unsigned short* __restrict__ eA, const int* __restrict__ ebatch,
    const float* __restrict__ afA, const float* __restrict__ afB,
    const unsigned short* __restrict__ WtP,    // wt_emp [64][192]
    unsigned short* __restrict__ eB1, unsigned short* __restrict__ PE, int nE)
{
  __shared__ float lA[1024], lB[1024];
  for (int i = threadIdx.x; i < 1024; i += 256) { lA[i] = afA[i]; lB[i] = afB[i]; }
  __syncthreads();
  int gw = (int)((blockIdx.x * 256u + threadIdx.x) >> 6);
  int ntile = nE >> 4;
  if (gw >= ntile) return;
  int lane = threadIdx.x & 63;
  int colb = lane & 15;
  int ko = (lane >> 4) << 3;
  int rowb = (lane >> 4) << 2;
  int row = (gw << 4) + colb;
  int ge = ebatch[row];
  f32x4_t a3[4] = {}, a4[4] = {};
#pragma unroll
  for (int c2 = 0; c2 < 2; ++c2) {
    int fb = c2 * 32 + ko;
    bf16x8_t t = *(const bf16x8_t*)(eA + (size_t)row * 64 + fb);
    bf16x8_t an;
#pragma unroll
    for (int k = 0; k < 8; ++k)
      an[k] = (short)f2bf(bf2f((unsigned short)t[k]) * lA[ge*64 + fb + k] + lB[ge*64 + fb + k]);
    *(bf16x8_t*)(eB1 + (size_t)row * 64 + fb) = an;
#pragma unroll
    for (int nb = 0; nb < 4; ++nb) {
      bf16x8_t b3 = *(const bf16x8_t*)(WtP + (size_t)(nb * 16 + colb) * 192 + c2 * 32 + ko);
      a3[nb] = __builtin_amdgcn_mfma_f32_16x16x32_bf16(an, b3, a3[nb], 0, 0, 0);
      bf16x8_t b4 = *(const bf16x8_t*)(WtP + (size_t)(nb * 16 + colb) * 192 + 64 + c2 * 32 + ko);
      a4[nb] = __builtin_amdgcn_mfma_f32_16x16x32_bf16(an, b4, a4[nb], 0, 0, 0);
    }
  }
#pragma unroll
  for (int r = 0; r < 4; ++r) {
    size_t ro = (size_t)((gw << 4) + rowb + r) * 128;
    bf16x4_t t3, t4;
#pragma unroll
    for (int nb = 0; nb < 4; ++nb) { t3[nb] = (short)f2bf(a3[nb][r]); t4[nb] = (short)f2bf(a4[nb][r]); }
    *(bf16x4_t*)(PE + ro + colb * 4) = t3;
    *(bf16x4_t*)(PE + ro + 64 + colb * 4) = t4;
  }
}

// =====================================================================
// EDGE stage: e_out(bf16) = affEin(e_in) + P_T1[s]+P_T2[d] + affEin(e_in)@Wne_e + b
//             pn = P_T3[s] + P_T4[d]   (bf16, swizzled)    (+stats)
// EF32: e_in storage type (layer0 fp32 input, layer1 bf16 ws; may alias e_out)
// =====================================================================
template<bool EF32>
__global__ __launch_bounds__(256) void k_edge(
    const unsigned short* __restrict__ P, const void* e_in, unsigned short* e_out,
    const int* __restrict__ ei, const int* __restrict__ ebatch,
    const unsigned short* __restrict__ Wt,    // wt_ne [64][320]
    const float* __restrict__ bias,
    const float* __restrict__ afA, const float* __restrict__ afB,
    float* __restrict__ gs1, float* __restrict__ gs2,
    unsigned short* __restrict__ pn, int nE)
{
  __shared__ float lA[1024], lB[1024];
  __shared__ float ls1[NG], ls2[NG];
  for (int i = threadIdx.x; i < 1024; i += 256) { lA[i] = afA[i]; lB[i] = afB[i]; }
  if (threadIdx.x < NG) { ls1[threadIdx.x] = 0.f; ls2[threadIdx.x] = 0.f; }
  __syncthreads();
  int gw = (int)((blockIdx.x * 256u + threadIdx.x) >> 6);
  int ntile = nE >> 4;
  bool act = gw < ntile;
  int lane = threadIdx.x & 63;
  int colb = lane & 15;
  int ko = (lane >> 4) << 3;
  int rowb = (lane >> 4) << 2;
  float sr[4] = {0.f,0.f,0.f,0.f}, ssr[4] = {0.f,0.f,0.f,0.f};
  if (act) {
    int sI[4], dI[4];
#pragma unroll
    for (int r = 0; r < 4; ++r) {
      int e_r = (gw << 4) + rowb + r;
      sI[r] = ei[e_r]; dI[r] = ei[nE + e_r];
    }
    bf16x4_t g1[4], g2[4]; bf16x8_t g3[4], g4[4];
#pragma unroll
    for (int r = 0; r < 4; ++r) {
      g1[r] = *(const bf16x4_t*)(P + (size_t)sI[r] * 384 + colb * 4);
      g2[r] = *(const bf16x4_t*)(P + (size_t)dI[r] * 384 + 64 + colb * 4);
      g3[r] = *(const bf16x8_t*)(P + (size_t)sI[r] * 384 + 128 + colb * 8);
      g4[r] = *(const bf16x8_t*)(P + (size_t)dI[r] * 384 + 256 + colb * 8);
    }
    int row = (gw << 4) + colb;
    int ge = ebatch[row];
    f32x4_t acc[4] = {};
#pragma unroll
    for (int c2 = 0; c2 < 2; ++c2) {
      int fb = c2 * 32 + ko;
      float vv[8];
      ldrow8<EF32>(e_in, (size_t)row * 64 + fb, vv);
      bf16x8_t a;
#pragma unroll
      for (int k = 0; k < 8; ++k) a[k] = (short)f2bf(vv[k] * lA[ge*64 + fb + k] + lB[ge*64 + fb + k]);
#pragma unroll
      for (int nb = 0; nb < 4; ++nb) {
        bf16x8_t b = *(const bf16x8_t*)(Wt + (size_t)(nb * 16 + colb) * 320 + (8 + c2) * 32 + ko);
        acc[nb] = __builtin_amdgcn_mfma_f32_16x16x32_bf16(a, b, acc[nb], 0, 0, 0);
      }
    }
#pragma unroll
    for (int r = 0; r < 4; ++r) {
      int e_ = (gw << 4) + rowb + r;
      int gr = ebatch[e_];
#pragma unroll
      for (int nb = 0; nb < 4; ++nb) {
        int col = nb * 16 + colb;
        size_t off = (size_t)e_ * 64 + col;
        float ev = ldel<EF32>(e_in, off);
        float vv = ev * lA[gr*64 + col] + lB[gr*64 + col] + bias[col]
                 + acc[nb][r] + bf2f((unsigned short)g1[r][nb]) + bf2f((unsigned short)g2[r][nb]);
        e_out[off] = f2bf(vv);
        sr[r] += vv; ssr[r] += vv * vv;
      }
      bf16x8_t pv;
#pragma unroll
      for (int k = 0; k < 8; ++k)
        pv[k] = (short)f2bf(bf2f((unsigned short)g3[r][k]) + bf2f((unsigned short)g4[r][k]));
      *(bf16x8_t*)(pn + (size_t)e_ * 128 + colb * 8) = pv;
    }
  }
#pragma unroll
  for (int m = 1; m <= 8; m <<= 1)
#pragma unroll
    for (int r = 0; r < 4; ++r) { sr[r] += __shfl_xor(sr[r], m); ssr[r] += __shfl_xor(ssr[r], m); }
  if (act && colb == 0) {
#pragma unroll
    for (int r = 0; r < 4; ++r) {
      int g = ebatch[(gw << 4) + rowb + r];
      atomicAdd(&ls1[g], sr[r]); atomicAdd(&ls2[g], ssr[r]);
    }
  }
  __syncthreads();
  if (threadIdx.x < NG) {
    atomicAdd(&gs1[threadIdx.x], ls1[threadIdx.x]);
    atomicAdd(&gs2[threadIdx.x], ls2[threadIdx.x]);
  }
}

// =====================================================================
// ANGLE stage: a_out(bf16) = affAin(a_in)+[eB1_s|eB1_d|affAin(a_in)]@Wea+b (+stats)
//              pe = PE_T3[s] + PE_T4[d]  -> msg (swizzled)
// AF32: a_in storage type (layer0 fp32 input, layer1 bf16 ws; may alias a_out)
// =====================================================================
template<bool AF32>
__global__ __launch_bounds__(256) void k_angle(
    const unsigned short* __restrict__ eB1, const unsigned short* __restrict__ PE,
    const void* a_in, unsigned short* a_out,
    const int* __restrict__ ti, const int* __restrict__ abatch,
    const unsigned short* __restrict__ Wt, const float* __restrict__ bias,
    const float* __restrict__ afAA, const float* __restrict__ afAB,
    float* __restrict__ gs1, float* __restrict__ gs2,
    unsigned short* __restrict__ pe, int nA)
{
  __shared__ float lAA[1024], lAB[1024];
  __shared__ float ls1[NG], ls2[NG];
  for (int i = threadIdx.x; i < 1024; i += 256) { lAA[i] = afAA[i]; lAB[i] = afAB[i]; }
  if (threadIdx.x < NG) { ls1[threadIdx.x] = 0.f; ls2[threadIdx.x] = 0.f; }
  __syncthreads();
  int gw = (int)((blockIdx.x * 256u + threadIdx.x) >> 6);
  int ntile = nA >> 4;
  bool act = gw < ntile;
  int lane = threadIdx.x & 63;
  int colb = lane & 15;
  int ko = (lane >> 4) << 3;
  int rowb = (lane >> 4) << 2;
  float sr[4] = {0.f,0.f,0.f,0.f}, ssr[4] = {0.f,0.f,0.f,0.f};
  if (act) {
    int sI[4], dI[4];
#pragma unroll
    for (int r = 0; r < 4; ++r) {
      int a_r = (gw << 4) + rowb + r;
      sI[r] = ti[a_r]; dI[r] = ti[nA + a_r];
    }
    bf16x4_t g3[4], g4[4];
#pragma unroll
    for (int r = 0; r < 4; ++r) {
      g3[r] = *(const bf16x4_t*)(PE + (size_t)sI[r] * 128 + colb * 4);
      g4[r] = *(const bf16x4_t*)(PE + (size_t)dI[r] * 128 + 64 + colb * 4);
    }
    int row = (gw << 4) + colb;
    int s = ti[row], d = ti[nA + row];
    int ga = abatch[row];
    const unsigned short* es = eB1 + (size_t)s * 64;
    const unsigned short* ed = eB1 + (size_t)d * 64;
    f32x4_t acc[4] = {};
#pragma unroll
    for (int c = 0; c < 6; ++c) {
      bf16x8_t a;
      if (c < 4) {
        const unsigned short* bp = (c < 2) ? es + c * 32 : ed + (c - 2) * 32;
        a = *(const bf16x8_t*)(bp + ko);
      } else {
        int fb = (c - 4) * 32 + ko;
        float vv[8];
        ldrow8<AF32>(a_in, (size_t)row * 64 + fb, vv);
#pragma unroll
        for (int k = 0; k < 8; ++k) a[k] = (short)f2bf(vv[k] * lAA[ga*64 + fb + k] + lAB[ga*64 + fb + k]);
      }
#pragma unroll
      for (int nb = 0; nb < 4; ++nb) {
        bf16x8_t b = *(const bf16x8_t*)(Wt + (size_t)(nb * 16 + colb) * 192 + c * 32 + ko);
        acc[nb] = __builtin_amdgcn_mfma_f32_16x16x32_bf16(a, b, acc[nb], 0, 0, 0);
      }
    }
#pragma unroll
    for (int r = 0; r < 4; ++r) {
      int a_ = (gw << 4) + rowb + r;
      int gr = abatch[a_];
#pragma unroll
      for (int nb = 0; nb < 4; ++nb) {
        int col = nb * 16 + colb;
        size_t off = (size_t)a_ * 64 + col;
        float av = ldel<AF32>(a_in, off);
        float vv = av * lAA[gr*64 + col] + lAB[gr*64 + col] + bias[col] + acc[nb][r];
        a_out[off] = f2bf(vv);
        sr[r] += vv; ssr[r] += vv * vv;
      }
      bf16x4_t pv;
#pragma unroll
      for (int nb = 0; nb < 4; ++nb)
        pv[nb] = (short)f2bf(bf2f((unsigned short)g3[r][nb]) + bf2f((unsigned short)g4[r][nb]));
      *(bf16x4_t*)(pe + (size_t)a_ * 64 + colb * 4) = pv;
    }
  }
#pragma unroll
  for (int m = 1; m <= 8; m <<= 1)
#pragma unroll
    for (int r = 0; r < 4; ++r) { sr[r] += __shfl_xor(sr[r], m); ssr[r] += __shfl_xor(ssr[r], m); }
  if (act && colb == 0) {
#pragma unroll
    for (int r = 0; r < 4; ++r) {
      int g = abatch[(gw << 4) + rowb + r];
      atomicAdd(&ls1[g], sr[r]); atomicAdd(&ls2[g], ssr[r]);
    }
  }
  __syncthreads();
  if (threadIdx.x < NG) {
    atomicAdd(&gs1[threadIdx.x], ls1[threadIdx.x]);
    atomicAdd(&gs2[threadIdx.x], ls2[threadIdx.x]);
  }
}

// =====================================================================
// emp finish (pure stream): msg = relu(pe + affA1(a1)@Wemp_a + b)
// a1 is bf16 ws. Reads pe swizzled in-place, writes standard layout.
// =====================================================================
__global__ __launch_bounds__(256) void k_fin_emp(
    const unsigned short* __restrict__ a_, const int* __restrict__ abatch,
    const unsigned short* __restrict__ Wt,    // wt_emp [64][192]
    const float* __restrict__ bias,
    const float* __restrict__ afAA, const float* __restrict__ afAB,
    unsigned short* __restrict__ msg, int nA)
{
  __shared__ float lAA[1024], lAB[1024];
  for (int i = threadIdx.x; i < 1024; i += 256) { lAA[i] = afAA[i]; lAB[i] = afAB[i]; }
  __syncthreads();
  int gw = (int)((blockIdx.x * 256u + threadIdx.x) >> 6);
  int ntile = nA >> 4;
  if (gw >= ntile) return;
  int lane = threadIdx.x & 63;
  int colb = lane & 15;
  int ko = (lane >> 4) << 3;
  int rowb = (lane >> 4) << 2;
  int row = (gw << 4) + colb;
  int ga = abatch[row];
  f32x4_t acc[4] = {};
#pragma unroll
  for (int c2 = 0; c2 < 2; ++c2) {
    int fb = c2 * 32 + ko;
    bf16x8_t t = *(const bf16x8_t*)(a_ + (size_t)row * 64 + fb);
    bf16x8_t a;
#pragma unroll
    for (int k = 0; k < 8; ++k)
      a[k] = (short)f2bf(bf2f((unsigned short)t[k]) * lAA[ga*64 + fb + k] + lAB[ga*64 + fb + k]);
#pragma unroll
    for (int nb = 0; nb < 4; ++nb) {
      bf16x8_t b = *(const bf16x8_t*)(Wt + (size_t)(nb * 16 + colb) * 192 + 128 + c2 * 32 + ko);
      acc[nb] = __builtin_amdgcn_mfma_f32_16x16x32_bf16(a, b, acc[nb], 0, 0, 0);
    }
  }
  bf16x4_t p4[4];
#pragma unroll
  for (int r = 0; r < 4; ++r)
    p4[r] = *(const bf16x4_t*)(msg + (size_t)((gw << 4) + rowb + r) * 64 + colb * 4);
#pragma unroll
  for (int r = 0; r < 4; ++r) {
    int a_idx = (gw << 4) + rowb + r;
#pragma unroll
    for (int nb = 0; nb < 4; ++nb) {
      int col = nb * 16 + colb;
      float v = fmaxf(acc[nb][r] + bf2f((unsigned short)p4[r][nb]) + bias[col], 0.f);
      msg[(size_t)a_idx * 64 + col] = f2bf(v);
    }
  }
}

// =====================================================================
// nmp finish (pure stream): msg = relu(pn + affE2(e2)@Wnmp_e + b); e2 bf16 ws
// =====================================================================
__global__ __launch_bounds__(256) void k_fin_nmp(
    const unsigned short* __restrict__ e, const int* __restrict__ ebatch,
    const unsigned short* __restrict__ Wt,    // wt_nmp [128][320]
    const float* __restrict__ bias,
    const float* __restrict__ afEA, const float* __restrict__ afEB,
    const unsigned short* __restrict__ pn,
    unsigned short* __restrict__ msg, int nE)
{
  __shared__ float lEA[1024], lEB[1024];
  for (int i = threadIdx.x; i < 1024; i += 256) { lEA[i] = afEA[i]; lEB[i] = afEB[i]; }
  __syncthreads();
  int gw = (int)((blockIdx.x * 256u + threadIdx.x) >> 6);
  int ntile = nE >> 4;
  if (gw >= ntile) return;
  int lane = threadIdx.x & 63;
  int colb = lane & 15;
  int ko = (lane >> 4) << 3;
  int rowb = (lane >> 4) << 2;
  int row = (gw << 4) + colb;
  int ge = ebatch[row];
  f32x4_t acc[8] = {};
#pragma unroll
  for (int c2 = 0; c2 < 2; ++c2) {
    int fb = c2 * 32 + ko;
    bf16x8_t t = *(const bf16x8_t*)(e + (size_t)row * 64 + fb);
    bf16x8_t a;
#pragma unroll
    for (int k = 0; k < 8; ++k)
      a[k] = (short)f2bf(bf2f((unsigned short)t[k]) * lEA[ge*64 + fb + k] + lEB[ge*64 + fb + k]);
#pragma unroll
    for (int nb = 0; nb < 8; ++nb) {
      bf16x8_t b = *(const bf16x8_t*)(Wt + (size_t)(nb * 16 + colb) * 320 + (8 + c2) * 32 + ko);
      acc[nb] = __builtin_amdgcn_mfma_f32_16x16x32_bf16(a, b, acc[nb], 0, 0, 0);
    }
  }
#pragma unroll
  for (int r = 0; r < 4; ++r) {
    int e_ = (gw << 4) + rowb + r;
    bf16x8_t p8 = *(const bf16x8_t*)(pn + (size_t)e_ * 128 + colb * 8);
#pragma unroll
    for (int nb = 0; nb < 8; ++nb) {
      int col = nb * 16 + colb;
      float v = fmaxf(acc[nb][r] + bf2f((unsigned short)p8[nb]) + bias[col], 0.f);
      msg[(size_t)e_ * 128 + col] = f2bf(v);
    }
  }
}

// =====================================================================
// CSR gather-reduce over edges: e2(bf16) = affE1(e1) + sum(msg rows); fused stats.
// =====================================================================
__global__ __launch_bounds__(256) void k_red_e(
    const unsigned short* __restrict__ msg, const unsigned short* e_in, unsigned short* e_out,
    const int* __restrict__ ptr, const int* __restrict__ perm,
    const int* __restrict__ ebatch,
    const float* __restrict__ afA, const float* __restrict__ afB,
    float* __restrict__ gs1, float* __restrict__ gs2, int nE)
{
  __shared__ float lA[1024], lB[1024], ls1[NG], ls2[NG];
  for (int i = threadIdx.x; i < 1024; i += 256) { lA[i] = afA[i]; lB[i] = afB[i]; }
  if (threadIdx.x < NG) { ls1[threadIdx.x] = 0.f; ls2[threadIdx.x] = 0.f; }
  __syncthreads();
  int lane = threadIdx.x & 63;
  int wv = (int)((blockIdx.x * 256u + threadIdx.x) >> 6);
  int nw = (int)((gridDim.x * 256u) >> 6);
  for (int eidx = wv; eidx < nE; eidx += nw) {
    int p0 = ptr[eidx], p1 = ptr[eidx + 1];
    float sum = 0.f;
    for (int j = p0; j < p1; ++j) {
      int aidx = perm[j];
      sum += bf2f(msg[(size_t)aidx * 64 + lane]);
    }
    int g = ebatch[eidx];
    size_t off = (size_t)eidx * 64 + lane;
    float v = bf2f(e_in[off]) * lA[g*64 + lane] + lB[g*64 + lane] + sum;
    e_out[off] = f2bf(v);
    float s = v, ss = v * v;
#pragma unroll
    for (int m = 1; m < 64; m <<= 1) { s += __shfl_xor(s, m); ss += __shfl_xor(ss, m); }
    if (lane == 0) { atomicAdd(&ls1[g], s); atomicAdd(&ls2[g], ss); }
  }
  __syncthreads();
  if (threadIdx.x < NG) {
    atomicAdd(&gs1[threadIdx.x], ls1[threadIdx.x]);
    atomicAdd(&gs2[threadIdx.x], ls2[threadIdx.x]);
  }
}

// =====================================================================
// CSR gather-reduce over nodes: h = x + sum(msg rows); fused stats. (x fp32)
// =====================================================================
__global__ __launch_bounds__(256) void k_red_n(
    const unsigned short* __restrict__ msg, const float* x_in, float* out,
    const int* __restrict__ ptr, const int* __restrict__ perm,
    const int* __restrict__ nbatch,
    float* __restrict__ gs1, float* __restrict__ gs2, int nN)
{
  __shared__ float ls1[NG], ls2[NG];
  if (threadIdx.x < NG) { ls1[threadIdx.x] = 0.f; ls2[threadIdx.x] = 0.f; }
  __syncthreads();
  int lane = threadIdx.x & 63;
  int wv = (int)((blockIdx.x * 256u + threadIdx.x) >> 6);
  int nw = (int)((gridDim.x * 256u) >> 6);
  for (int n = wv; n < nN; n += nw) {
    int p0 = ptr[n], p1 = ptr[n + 1];
    float s0 = 0.f, s1v = 0.f;
    for (int j = p0; j < p1; ++j) {
      int e = perm[j];
      unsigned u = *(const unsigned*)(msg + (size_t)e * 128 + lane * 2);
      s0 += bf2f((unsigned short)(u & 0xffffu));
      s1v += bf2f((unsigned short)(u >> 16));
    }
    size_t off = (size_t)n * 128 + lane * 2;
    float h0 = x_in[off] + s0, h1 = x_in[off + 1] + s1v;
    out[off] = h0; out[off + 1] = h1;
    float s = h0 + h1, ss = h0 * h0 + h1 * h1;
#pragma unroll
    for (int m = 1; m < 64; m <<= 1) { s += __shfl_xor(s, m); ss += __shfl_xor(ss, m); }
    if (lane == 0) { int g = nbatch[n]; atomicAdd(&ls1[g], s); atomicAdd(&ls2[g], ss); }
  }
  __syncthreads();
  if (threadIdx.x < NG) {
    atomicAdd(&gs1[threadIdx.x], ls1[threadIdx.x]);
    atomicAdd(&gs2[threadIdx.x], ls2[threadIdx.x]);
  }
}

// ---- affine table construction ----
__global__ __launch_bounds__(256) void k_mkaff(
    const float* __restrict__ s1, const float* __restrict__ s2,
    const float* __restrict__ cnt, int F,
    const float* __restrict__ w, const float* __restrict__ b,
    float* __restrict__ A, float* __restrict__ B)
{
  int idx = blockIdx.x * 256 + threadIdx.x;
  if (idx >= NG * F) return;
  int g = idx / F, f = idx - g * F;
  float norm = fmaxf(cnt[g], 1.f) * (float)F;
  float m = s1[g] / norm;
  float var = s2[g] / norm - m * m;
  float inv = rsqrtf(var + EPS);
  float a = inv * w[f];
  A[idx] = a;
  B[idx] = b[f] - m * a;
}

__global__ __launch_bounds__(256) void k_idaff(float* __restrict__ A, float* __restrict__ B, int n)
{
  int idx = blockIdx.x * 256 + threadIdx.x;
  if (idx < n) { A[idx] = 1.f; B[idx] = 0.f; }
}

// ---- apply norm to x (in-place, fp32) ----
__global__ __launch_bounds__(256) void k_apply(
    float* h, const int* __restrict__ batch,
    const float* __restrict__ A, const float* __restrict__ B, int nN)
{
  int total = nN * 16;
  int stride = gridDim.x * 256;
  for (int idx = blockIdx.x * 256 + threadIdx.x; idx < total; idx += stride) {
    int row = idx >> 4, q = (idx & 15) * 8;
    int g = batch[row];
    float* hp = h + (size_t)row * 128 + q;
    float4 f0 = *(const float4*)hp;
    float4 f1 = *(const float4*)(hp + 4);
    float vv[8] = {f0.x,f0.y,f0.z,f0.w,f1.x,f1.y,f1.z,f1.w};
#pragma unroll
    for (int k = 0; k < 8; ++k) vv[k] = vv[k] * A[(g << 7) + q + k] + B[(g << 7) + q + k];
    float4 g0 = {vv[0],vv[1],vv[2],vv[3]}, g1 = {vv[4],vv[5],vv[6],vv[7]};
    *(float4*)hp = g0;
    *(float4*)(hp + 4) = g1;
  }
}

__global__ __launch_bounds__(256) void k_count(
    const int* __restrict__ batch, int n, float* __restrict__ cnt)
{
  __shared__ float lc[NG];
  if (threadIdx.x < NG) lc[threadIdx.x] = 0.f;
  __syncthreads();
  for (int i = blockIdx.x * 256 + threadIdx.x; i < n; i += gridDim.x * 256)
    atomicAdd(&lc[batch[i]], 1.f);
  __syncthreads();
  if (threadIdx.x < NG) atomicAdd(&cnt[threadIdx.x], lc[threadIdx.x]);
}

// ---- CSR build ----
__global__ __launch_bounds__(256) void k_hist(
    const int* __restrict__ dst, int n, int* __restrict__ cnt)
{
  for (int i = blockIdx.x * 256 + threadIdx.x; i < n; i += gridDim.x * 256)
    atomicAdd(&cnt[dst[i]], 1);
}

__global__ __launch_bounds__(256) void k_scan1(
    const int* __restrict__ in, int* __restrict__ out, int* __restrict__ bsum, int n)
{
  __shared__ int wtot[4];
  int tid = threadIdx.x, lane = tid & 63, wid = tid >> 6;
  int base = blockIdx.x * 1024 + tid * 4;
  int v[4];
#pragma unroll
  for (int k = 0; k < 4; ++k) v[k] = (base + k < n) ? in[base + k] : 0;
  int tsum = v[0] + v[1] + v[2] + v[3];
  int incl = tsum;
#pragma unroll
  for (int off = 1; off < 64; off <<= 1) {
    int up = __shfl_up(incl, off);
    if (lane >= off) incl += up;
  }
  if (lane == 63) wtot[wid] = incl;
  __syncthreads();
  if (tid == 0) {
    int r = 0;
#pragma unroll
    for (int w2 = 0; w2 < 4; ++w2) { int t = wtot[w2]; wtot[w2] = r; r += t; }
    bsum[blockIdx.x] = r;
  }
  __syncthreads();
  int excl = wtot[wid] + incl - tsum;
#pragma unroll
  for (int k = 0; k < 4; ++k) {
    if (base + k < n) out[base + k] = excl;
    excl += v[k];
  }
}

__global__ __launch_bounds__(256) void k_scan2(int* __restrict__ bsum, int nb, int* __restrict__ total_out)
{
  __shared__ int wtot[4];
  int tid = threadIdx.x, lane = tid & 63, wid = tid >> 6;
  int base = tid * 4;
  int v[4];
#pragma unroll
  for (int k = 0; k < 4; ++k) v[k] = (base + k < nb) ? bsum[base + k] : 0;
  int tsum = v[0] + v[1] + v[2] + v[3];
  int incl = tsum;
#pragma unroll
  for (int off = 1; off < 64; off <<= 1) {
    int up = __shfl_up(incl, off);
    if (lane >= off) incl += up;
  }
  if (lane == 63) wtot[wid] = incl;
  __syncthreads();
  if (tid == 0) {
    int r = 0;
#pragma unroll
    for (int w2 = 0; w2 < 4; ++w2) { int t = wtot[w2]; wtot[w2] = r; r += t; }
    *total_out = r;
  }
  __syncthreads();
  int excl = wtot[wid] + incl - tsum;
#pragma unroll
  for (int k = 0; k < 4; ++k) {
    if (base + k < nb) bsum[base + k] = excl;
    excl += v[k];
  }
}

__global__ __launch_bounds__(256) void k_scan3(
    int* __restrict__ ptr, int* __restrict__ cur, const int* __restrict__ bsum, int n)
{
  for (int i = blockIdx.x * 256 + threadIdx.x; i < n; i += gridDim.x * 256) {
    int v = ptr[i] + bsum[i >> 10];
    ptr[i] = v; cur[i] = v;
  }
}

__global__ __launch_bounds__(256) void k_scatter(
    const int* __restrict__ dst, int* __restrict__ cur, int* __restrict__ perm, int n)
{
  for (int i = blockIdx.x * 256 + threadIdx.x; i < n; i += gridDim.x * 256) {
    int d = dst[i];
    int p = atomicAdd(&cur[d], 1);
    perm[p] = i;
  }
}

// ---- weight prep ----
__global__ __launch_bounds__(256) void k_wt(
    const float* __restrict__ W, unsigned short* __restrict__ Wt, int K, int NO)
{
  int idx = blockIdx.x * 256 + threadIdx.x;
  if (idx >= K * NO) return;
  int k = idx / NO, j = idx - k * NO;
  Wt[(size_t)j * K + k] = f2bf(W[idx]);
}

extern "C" void kernel_launch(void* const* d_in, const int* in_sizes, int n_in,
                              void* d_out, int out_size, void* d_ws, size_t ws_size,
                              hipStream_t stream)
{
  const float* x0    = (const float*)d_in[0];
  const float* e0    = (const float*)d_in[1];
  const float* a0    = (const float*)d_in[2];
  const float* W_ne  = (const float*)d_in[3];
  const float* b_ne  = (const float*)d_in[4];
  const float* g_e   = (const float*)d_in[5];
  const float* be_e  = (const float*)d_in[6];
  const float* W_ea  = (const float*)d_in[7];
  const float* b_ea  = (const float*)d_in[8];
  const float* g_a   = (const float*)d_in[9];
  const float* be_a  = (const float*)d_in[10];
  const float* W_emp = (const float*)d_in[11];
  const float* b_emp = (const float*)d_in[12];
  const float* g_emp = (const float*)d_in[13];
  const float* be_emp= (const float*)d_in[14];
  const float* W_nmp = (const float*)d_in[15];
  const float* b_nmp = (const float*)d_in[16];
  const float* g_nmp = (const float*)d_in[17];
  const float* be_nmp= (const float*)d_in[18];
  const int* node_batch  = (const int*)d_in[19];
  const int* edge_index  = (const int*)d_in[20];
  const int* edge_batch  = (const int*)d_in[21];
  const int* tb_index    = (const int*)d_in[22];
  const int* angle_batch = (const int*)d_in[23];

  const int N = in_sizes[0] / 128;
  const int E = in_sizes[1] / 64;
  const int A = in_sizes[2] / 64;

  // ---- workspace layout (bytes, 256-aligned) ----
  char* wsp = (char*)d_ws;
  auto alloc = [&](size_t bytes) { char* p = wsp; wsp += (bytes + 255) & ~(size_t)255; return p; };
  unsigned short* eAB  = (unsigned short*)alloc((size_t)E * 64 * 2);   // e intermediate (bf16)
  unsigned short* aAB  = (unsigned short*)alloc((size_t)A * 64 * 2);   // a intermediate (bf16)
  unsigned short* msg  = (unsigned short*)alloc((size_t)A * 64 * 2);   // hosts P, pe, msg_e, msg_n
  unsigned short* pn   = (unsigned short*)alloc((size_t)E * 128 * 2);  // nmp x-partial (swizzled)
  unsigned short* eB1  = (unsigned short*)alloc((size_t)E * 64 * 2);   // bf16 affE1(e) gather table
  unsigned short* PE   = (unsigned short*)alloc((size_t)E * 128 * 2);  // emp partials (swizzled)
  int* ptr_n  = (int*)alloc((size_t)(N + 1) * 4);
  int* cur_n  = (int*)alloc((size_t)N * 4);
  int* perm_n = (int*)alloc((size_t)E * 4);
  int* ptr_e  = (int*)alloc((size_t)(E + 1) * 4);
  int* cur_e  = (int*)alloc((size_t)E * 4);
  int* perm_e = (int*)alloc((size_t)A * 4);
  int* bsum   = (int*)alloc(4096 * 4);
  float* stats = (float*)alloc(5 * NG * 4);   // contiguous: s1,s2,cnt_n,cnt_e,cnt_a
  float* s1    = stats;
  float* s2    = stats + NG;
  float* cnt_n = stats + 2 * NG;
  float* cnt_e = stats + 3 * NG;
  float* cnt_a = stats + 4 * NG;
  float* afE_idA = (float*)alloc(1024 * 4); float* afE_idB = (float*)alloc(1024 * 4);
  float* afA_idA = (float*)alloc(1024 * 4); float* afA_idB = (float*)alloc(1024 * 4);
  float* afE1A   = (float*)alloc(1024 * 4); float* afE1B   = (float*)alloc(1024 * 4);
  float* afE2A   = (float*)alloc(1024 * 4); float* afE2B   = (float*)alloc(1024 * 4);
  float* afA1A   = (float*)alloc(1024 * 4); float* afA1B   = (float*)alloc(1024 * 4);
  float* afXA    = (float*)alloc(2048 * 4); float* afXB    = (float*)alloc(2048 * 4);
  unsigned short* wt_ne  = (unsigned short*)alloc((size_t)2 * 320 * 64 * 2);
  unsigned short* wt_ea  = (unsigned short*)alloc((size_t)2 * 192 * 64 * 2);
  unsigned short* wt_emp = (unsigned short*)alloc((size_t)2 * 192 * 64 * 2);
  unsigned short* wt_nmp = (unsigned short*)alloc((size_t)2 * 320 * 128 * 2);

  unsigned short* P = msg;   // P (N*384 bf16) lives in msg; dead before pe/msg written
  float* x_out = (float*)d_out;

  // ---- one-time prep ----
  for (int i = 0; i < 2; ++i) {
    k_wt<<<(320*64 + 255)/256, 256, 0, stream>>>(W_ne  + (size_t)i*320*64,  wt_ne  + (size_t)i*320*64,  320, 64);
    k_wt<<<(192*64 + 255)/256, 256, 0, stream>>>(W_ea  + (size_t)i*192*64,  wt_ea  + (size_t)i*192*64,  192, 64);
    k_wt<<<(192*64 + 255)/256, 256, 0, stream>>>(W_emp + (size_t)i*192*64,  wt_emp + (size_t)i*192*64,  192, 64);
    k_wt<<<(320*128 + 255)/256, 256, 0, stream>>>(W_nmp + (size_t)i*320*128, wt_nmp + (size_t)i*320*128, 320, 128);
  }
  hipMemsetAsync(stats, 0, 5 * NG * 4, stream);
  k_count<<<512, 256, 0, stream>>>(node_batch, N, cnt_n);
  k_count<<<512, 256, 0, stream>>>(edge_batch, E, cnt_e);
  k_count<<<512, 256, 0, stream>>>(angle_batch, A, cnt_a);
  k_idaff<<<4, 256, 0, stream>>>(afE_idA, afE_idB, 1024);
  k_idaff<<<4, 256, 0, stream>>>(afA_idA, afA_idB, 1024);

  // CSR over nodes (dst of edge_index) and edges (dst of threebody)
  hipMemsetAsync(cur_n, 0, (size_t)N * 4, stream);
  hipMemsetAsync(cur_e, 0, (size_t)E * 4, stream);
  k_hist<<<1024, 256, 0, stream>>>(edge_index + E, E, cur_n);
  k_hist<<<1024, 256, 0, stream>>>(tb_index + A, A, cur_e);
  int nbN = (N + 1023) / 1024, nbE = (E + 1023) / 1024;
  k_scan1<<<nbN, 256, 0, stream>>>(cur_n, ptr_n, bsum, N);
  k_scan2<<<1, 256, 0, stream>>>(bsum, nbN, ptr_n + N);
  k_scan3<<<1024, 256, 0, stream>>>(ptr_n, cur_n, bsum, N);
  k_scatter<<<1024, 256, 0, stream>>>(edge_index + E, cur_n, perm_n, E);
  k_scan1<<<nbE, 256, 0, stream>>>(cur_e, ptr_e, bsum, E);
  k_scan2<<<1, 256, 0, stream>>>(bsum, nbE, ptr_e + E);
  k_scan3<<<1024, 256, 0, stream>>>(ptr_e, cur_e, bsum, E);
  k_scatter<<<1024, 256, 0, stream>>>(tb_index + A, cur_e, perm_e, A);

  const float* x_cur = x0;
  int blkE = (E / 16 + 3) / 4;
  int blkA = (A / 16 + 3) / 4;
  int blkN = (N / 16 + 3) / 4;

  for (int i = 0; i < 2; ++i) {
    const float* fEinA = (i == 0) ? afE_idA : afE2A;
    const float* fEinB = (i == 0) ? afE_idB : afE2B;
    const float* fAinA = (i == 0) ? afA_idA : afA1A;
    const float* fAinB = (i == 0) ? afA_idB : afA1B;

    // 0. dense x-partials
    k_dense_x<<<blkN, 256, 0, stream>>>(x_cur, wt_ne + (size_t)i*320*64,
                                        wt_nmp + (size_t)i*320*128, P, N);

    // 1. edge stage (co-gathers stage-4 x-partials) -> affE1
    hipMemsetAsync(s1, 0, 2 * NG * 4, stream);
    if (i == 0)
      k_edge<true><<<blkE, 256, 0, stream>>>(P, (const void*)e0, eAB, edge_index, edge_batch,
                                             wt_ne + (size_t)i*320*64, b_ne + i*64,
                                             fEinA, fEinB, s1, s2, pn, E);
    else
      k_edge<false><<<blkE, 256, 0, stream>>>(P, (const void*)eAB, eAB, edge_index, edge_batch,
                                              wt_ne + (size_t)i*320*64, b_ne + i*64,
                                              fEinA, fEinB, s1, s2, pn, E);
    k_mkaff<<<4, 256, 0, stream>>>(s1, s2, cnt_e, 64, g_e + i*64, be_e + i*64, afE1A, afE1B);

    // 1.5 merged e-prep: eB1 (normalized bf16 table) + PE (emp partials)
    k_prep_e<<<blkE, 256, 0, stream>>>(eAB, edge_batch, afE1A, afE1B,
                                       wt_emp + (size_t)i*192*64, eB1, PE, E);

    // 2. angle stage -> affA1 (co-gathers emp partials -> pe in msg)
    hipMemsetAsync(s1, 0, 2 * NG * 4, stream);
    if (i == 0)
      k_angle<true><<<blkA, 256, 0, stream>>>(eB1, PE, (const void*)a0, aAB, tb_index, angle_batch,
                                              wt_ea + (size_t)i*192*64, b_ea + i*64,
                                              fAinA, fAinB, s1, s2, msg, A);
    else
      k_angle<false><<<blkA, 256, 0, stream>>>(eB1, PE, (const void*)aAB, aAB, tb_index, angle_batch,
                                               wt_ea + (size_t)i*192*64, b_ea + i*64,
                                               fAinA, fAinB, s1, s2, msg, A);
    k_mkaff<<<4, 256, 0, stream>>>(s1, s2, cnt_a, 64, g_a + i*64, be_a + i*64, afA1A, afA1B);

    // 3. emp finish (stream) -> msg; CSR reduce -> affE2
    k_fin_emp<<<blkA, 256, 0, stream>>>(aAB, angle_batch, wt_emp + (size_t)i*192*64,
                                        b_emp + i*64, afA1A, afA1B, msg, A);
    hipMemsetAsync(s1, 0, 2 * NG * 4, stream);
    k_red_e<<<2048, 256, 0, stream>>>(msg, eAB, eAB, ptr_e, perm_e, edge_batch,
                                      afE1A, afE1B, s1, s2, E);
    k_mkaff<<<4, 256, 0, stream>>>(s1, s2, cnt_e, 64, g_emp + i*64, be_emp + i*64, afE2A, afE2B);

    // 4. nmp finish (stream) -> msg; CSR reduce; apply
    k_fin_nmp<<<blkE, 256, 0, stream>>>(eAB, edge_batch, wt_nmp + (size_t)i*320*128,
                                        b_nmp + i*128, afE2A, afE2B, pn, msg, E);
    hipMemsetAsync(s1, 0, 2 * NG * 4, stream);
    k_red_n<<<2048, 256, 0, stream>>>(msg, x_cur, x_out, ptr_n, perm_n, node_batch,
                                      s1, s2, N);
    k_mkaff<<<8, 256, 0, stream>>>(s1, s2, cnt_n, 128, g_nmp + i*128, be_nmp + i*128, afXA, afXB);
    k_apply<<<2048, 256, 0, stream>>>(x_out, node_batch, afXA, afXB, N);

    x_cur = x_out;
  }
}

// Round 9
// 1680.800 us; speedup vs baseline: 1.3847x; 1.0183x over previous
//
#include <hip/hip_runtime.h>

typedef __attribute__((ext_vector_type(8))) short bf16x8_t;
typedef __attribute__((ext_vector_type(4))) short bf16x4_t;
typedef __attribute__((ext_vector_type(4))) float f32x4_t;

constexpr int NG = 16;
constexpr float EPS = 1e-5f;

__device__ inline unsigned short f2bf(float f) {
  unsigned u = __builtin_bit_cast(unsigned, f);
  u += 0x7FFFu + ((u >> 16) & 1u);
  return (unsigned short)(u >> 16);
}
__device__ inline float bf2f(unsigned short u) {
  unsigned x = ((unsigned)u) << 16;
  return __builtin_bit_cast(float, x);
}

// load 8 contiguous elements as f32 from fp32 or bf16 storage
template<bool F32>
__device__ inline void ldrow8(const void* base, size_t off, float v[8]) {
  if constexpr (F32) {
    const float* p = (const float*)base + off;
    float4 f0 = *(const float4*)p, f1 = *(const float4*)(p + 4);
    v[0]=f0.x; v[1]=f0.y; v[2]=f0.z; v[3]=f0.w;
    v[4]=f1.x; v[5]=f1.y; v[6]=f1.z; v[7]=f1.w;
  } else {
    bf16x8_t t = *(const bf16x8_t*)((const unsigned short*)base + off);
#pragma unroll
    for (int k = 0; k < 8; ++k) v[k] = bf2f((unsigned short)t[k]);
  }
}
template<bool F32>
__device__ inline float ldel(const void* base, size_t off) {
  if constexpr (F32) return ((const float*)base)[off];
  return bf2f(((const unsigned short*)base)[off]);
}

// =====================================================================
// Dense partial GEMM over nodes (coalesced):
//   P[n] = x[n] @ [Wne_s | Wne_d | Wnmp_s | Wnmp_d]  (N x 384 bf16, swizzled)
// =====================================================================
__global__ __launch_bounds__(256) void k_dense_x(
    const float* __restrict__ x,
    const unsigned short* __restrict__ WtNE,   // [64][320]
    const unsigned short* __restrict__ WtNM,   // [128][320]
    unsigned short* __restrict__ P, int nN)
{
  int gw = (int)((blockIdx.x * 256u + threadIdx.x) >> 6);
  int ntile = nN >> 4;
  if (gw >= ntile) return;
  int lane = threadIdx.x & 63;
  int colb = lane & 15;
  int ko = (lane >> 4) << 3;
  int rowb = (lane >> 4) << 2;
  int row = (gw << 4) + colb;
  const float* xr = x + (size_t)row * 128;
  f32x4_t a1[4] = {}, a2[4] = {}, a3[8] = {}, a4[8] = {};
#pragma unroll
  for (int c = 0; c < 4; ++c) {
    float4 f0 = *(const float4*)(xr + c * 32 + ko);
    float4 f1 = *(const float4*)(xr + c * 32 + ko + 4);
    float vv[8] = {f0.x,f0.y,f0.z,f0.w,f1.x,f1.y,f1.z,f1.w};
    bf16x8_t a;
#pragma unroll
    for (int k = 0; k < 8; ++k) a[k] = (short)f2bf(vv[k]);
#pragma unroll
    for (int nb = 0; nb < 4; ++nb) {
      bf16x8_t b1 = *(const bf16x8_t*)(WtNE + (size_t)(nb * 16 + colb) * 320 + c * 32 + ko);
      a1[nb] = __builtin_amdgcn_mfma_f32_16x16x32_bf16(a, b1, a1[nb], 0, 0, 0);
      bf16x8_t b2 = *(const bf16x8_t*)(WtNE + (size_t)(nb * 16 + colb) * 320 + (c + 4) * 32 + ko);
      a2[nb] = __builtin_amdgcn_mfma_f32_16x16x32_bf16(a, b2, a2[nb], 0, 0, 0);
    }
#pragma unroll
    for (int nb = 0; nb < 8; ++nb) {
      bf16x8_t b3 = *(const bf16x8_t*)(WtNM + (size_t)(nb * 16 + colb) * 320 + c * 32 + ko);
      a3[nb] = __builtin_amdgcn_mfma_f32_16x16x32_bf16(a, b3, a3[nb], 0, 0, 0);
      bf16x8_t b4 = *(const bf16x8_t*)(WtNM + (size_t)(nb * 16 + colb) * 320 + (c + 4) * 32 + ko);
      a4[nb] = __builtin_amdgcn_mfma_f32_16x16x32_bf16(a, b4, a4[nb], 0, 0, 0);
    }
  }
#pragma unroll
  for (int r = 0; r < 4; ++r) {
    size_t ro = (size_t)((gw << 4) + rowb + r) * 384;
    bf16x4_t t1, t2;
#pragma unroll
    for (int nb = 0; nb < 4; ++nb) { t1[nb] = (short)f2bf(a1[nb][r]); t2[nb] = (short)f2bf(a2[nb][r]); }
    *(bf16x4_t*)(P + ro + colb * 4) = t1;
    *(bf16x4_t*)(P + ro + 64 + colb * 4) = t2;
    bf16x8_t t3, t4;
#pragma unroll
    for (int nb = 0; nb < 8; ++nb) { t3[nb] = (short)f2bf(a3[nb][r]); t4[nb] = (short)f2bf(a4[nb][r]); }
    *(bf16x8_t*)(P + ro + 128 + colb * 8) = t3;
    *(bf16x8_t*)(P + ro + 256 + colb * 8) = t4;
  }
}

// =====================================================================
// Dense angle+emp partials over edges (coalesced, one eAB read):
//   ê = affE1(e);  PA1=ê@Wea_s, PA2=ê@Wea_d, PE3=ê@Wemp_s, PE4=ê@Wemp_d
// PAE row (256 elems): s-half at colb*8: [PA1 nb0..3 | PE3 nb0..3];
//                      d-half at 128+colb*8: [PA2 | PE4].
// One 16B gather per side per angle in k_angle.
// =====================================================================
__global__ __launch_bounds__(256) void k_prep_e(
    const unsigned short* __restrict__ eA, const int* __restrict__ ebatch,
    const float* __restrict__ afA, const float* __restrict__ afB,
    const unsigned short* __restrict__ WtA,    // wt_ea  [64][192]
    const unsigned short* __restrict__ WtP,    // wt_emp [64][192]
    unsigned short* __restrict__ PAE, int nE)
{
  __shared__ float lA[1024], lB[1024];
  for (int i = threadIdx.x; i < 1024; i += 256) { lA[i] = afA[i]; lB[i] = afB[i]; }
  __syncthreads();
  int gw = (int)((blockIdx.x * 256u + threadIdx.x) >> 6);
  int ntile = nE >> 4;
  if (gw >= ntile) return;
  int lane = threadIdx.x & 63;
  int colb = lane & 15;
  int ko = (lane >> 4) << 3;
  int rowb = (lane >> 4) << 2;
  int row = (gw << 4) + colb;
  int ge = ebatch[row];
  f32x4_t pa1[4] = {}, pa2[4] = {}, pe3[4] = {}, pe4[4] = {};
#pragma unroll
  for (int c2 = 0; c2 < 2; ++c2) {
    int fb = c2 * 32 + ko;
    bf16x8_t t = *(const bf16x8_t*)(eA + (size_t)row * 64 + fb);
    bf16x8_t an;
#pragma unroll
    for (int k = 0; k < 8; ++k)
      an[k] = (short)f2bf(bf2f((unsigned short)t[k]) * lA[ge*64 + fb + k] + lB[ge*64 + fb + k]);
#pragma unroll
    for (int nb = 0; nb < 4; ++nb) {
      size_t wb = (size_t)(nb * 16 + colb) * 192;
      bf16x8_t b;
      b = *(const bf16x8_t*)(WtA + wb + c2 * 32 + ko);
      pa1[nb] = __builtin_amdgcn_mfma_f32_16x16x32_bf16(an, b, pa1[nb], 0, 0, 0);
      b = *(const bf16x8_t*)(WtA + wb + 64 + c2 * 32 + ko);
      pa2[nb] = __builtin_amdgcn_mfma_f32_16x16x32_bf16(an, b, pa2[nb], 0, 0, 0);
      b = *(const bf16x8_t*)(WtP + wb + c2 * 32 + ko);
      pe3[nb] = __builtin_amdgcn_mfma_f32_16x16x32_bf16(an, b, pe3[nb], 0, 0, 0);
      b = *(const bf16x8_t*)(WtP + wb + 64 + c2 * 32 + ko);
      pe4[nb] = __builtin_amdgcn_mfma_f32_16x16x32_bf16(an, b, pe4[nb], 0, 0, 0);
    }
  }
#pragma unroll
  for (int r = 0; r < 4; ++r) {
    size_t ro = (size_t)((gw << 4) + rowb + r) * 256;
    bf16x8_t sH, dH;
#pragma unroll
    for (int nb = 0; nb < 4; ++nb) {
      sH[nb] = (short)f2bf(pa1[nb][r]); sH[4 + nb] = (short)f2bf(pe3[nb][r]);
      dH[nb] = (short)f2bf(pa2[nb][r]); dH[4 + nb] = (short)f2bf(pe4[nb][r]);
    }
    *(bf16x8_t*)(PAE + ro + colb * 8) = sH;
    *(bf16x8_t*)(PAE + ro + 128 + colb * 8) = dH;
  }
}

// =====================================================================
// EDGE stage: e_out(bf16) = affEin(e_in) + P_T1[s]+P_T2[d] + affEin(e_in)@Wne_e + b
//             pn = P_T3[s] + P_T4[d]   (bf16, swizzled)    (+stats)
// =====================================================================
template<bool EF32>
__global__ __launch_bounds__(256) void k_edge(
    const unsigned short* __restrict__ P, const void* e_in, unsigned short* e_out,
    const int* __restrict__ ei, const int* __restrict__ ebatch,
    const unsigned short* __restrict__ Wt,    // wt_ne [64][320]
    const float* __restrict__ bias,
    const float* __restrict__ afA, const float* __restrict__ afB,
    float* __restrict__ gs1, float* __restrict__ gs2,
    unsigned short* __restrict__ pn, int nE)
{
  __shared__ float lA[1024], lB[1024];
  __shared__ float ls1[NG], ls2[NG];
  for (int i = threadIdx.x; i < 1024; i += 256) { lA[i] = afA[i]; lB[i] = afB[i]; }
  if (threadIdx.x < NG) { ls1[threadIdx.x] = 0.f; ls2[threadIdx.x] = 0.f; }
  __syncthreads();
  int gw = (int)((blockIdx.x * 256u + threadIdx.x) >> 6);
  int ntile = nE >> 4;
  bool act = gw < ntile;
  int lane = threadIdx.x & 63;
  int colb = lane & 15;
  int ko = (lane >> 4) << 3;
  int rowb = (lane >> 4) << 2;
  float sr[4] = {0.f,0.f,0.f,0.f}, ssr[4] = {0.f,0.f,0.f,0.f};
  if (act) {
    int sI[4], dI[4];
#pragma unroll
    for (int r = 0; r < 4; ++r) {
      int e_r = (gw << 4) + rowb + r;
      sI[r] = ei[e_r]; dI[r] = ei[nE + e_r];
    }
    bf16x4_t g1[4], g2[4]; bf16x8_t g3[4], g4[4];
#pragma unroll
    for (int r = 0; r < 4; ++r) {
      g1[r] = *(const bf16x4_t*)(P + (size_t)sI[r] * 384 + colb * 4);
      g2[r] = *(const bf16x4_t*)(P + (size_t)dI[r] * 384 + 64 + colb * 4);
      g3[r] = *(const bf16x8_t*)(P + (size_t)sI[r] * 384 + 128 + colb * 8);
      g4[r] = *(const bf16x8_t*)(P + (size_t)dI[r] * 384 + 256 + colb * 8);
    }
    int row = (gw << 4) + colb;
    int ge = ebatch[row];
    f32x4_t acc[4] = {};
#pragma unroll
    for (int c2 = 0; c2 < 2; ++c2) {
      int fb = c2 * 32 + ko;
      float vv[8];
      ldrow8<EF32>(e_in, (size_t)row * 64 + fb, vv);
      bf16x8_t a;
#pragma unroll
      for (int k = 0; k < 8; ++k) a[k] = (short)f2bf(vv[k] * lA[ge*64 + fb + k] + lB[ge*64 + fb + k]);
#pragma unroll
      for (int nb = 0; nb < 4; ++nb) {
        bf16x8_t b = *(const bf16x8_t*)(Wt + (size_t)(nb * 16 + colb) * 320 + (8 + c2) * 32 + ko);
        acc[nb] = __builtin_amdgcn_mfma_f32_16x16x32_bf16(a, b, acc[nb], 0, 0, 0);
      }
    }
#pragma unroll
    for (int r = 0; r < 4; ++r) {
      int e_ = (gw << 4) + rowb + r;
      int gr = ebatch[e_];
#pragma unroll
      for (int nb = 0; nb < 4; ++nb) {
        int col = nb * 16 + colb;
        size_t off = (size_t)e_ * 64 + col;
        float ev = ldel<EF32>(e_in, off);
        float vv = ev * lA[gr*64 + col] + lB[gr*64 + col] + bias[col]
                 + acc[nb][r] + bf2f((unsigned short)g1[r][nb]) + bf2f((unsigned short)g2[r][nb]);
        e_out[off] = f2bf(vv);
        sr[r] += vv; ssr[r] += vv * vv;
      }
      bf16x8_t pv;
#pragma unroll
      for (int k = 0; k < 8; ++k)
        pv[k] = (short)f2bf(bf2f((unsigned short)g3[r][k]) + bf2f((unsigned short)g4[r][k]));
      *(bf16x8_t*)(pn + (size_t)e_ * 128 + colb * 8) = pv;
    }
  }
#pragma unroll
  for (int m = 1; m <= 8; m <<= 1)
#pragma unroll
    for (int r = 0; r < 4; ++r) { sr[r] += __shfl_xor(sr[r], m); ssr[r] += __shfl_xor(ssr[r], m); }
  if (act && colb == 0) {
#pragma unroll
    for (int r = 0; r < 4; ++r) {
      int g = ebatch[(gw << 4) + rowb + r];
      atomicAdd(&ls1[g], sr[r]); atomicAdd(&ls2[g], ssr[r]);
    }
  }
  __syncthreads();
  if (threadIdx.x < NG) {
    atomicAdd(&gs1[threadIdx.x], ls1[threadIdx.x]);
    atomicAdd(&gs2[threadIdx.x], ls2[threadIdx.x]);
  }
}

// =====================================================================
// ANGLE stage v2: all gathered data pre-multiplied (PAE); gathers feed ADDS only.
//   a_out(bf16) = affAin(a_in) + PA1[s]+PA2[d] + affAin(a_in)@Wea_a + b  (+stats)
//   pe = PE3[s] + PE4[d]  -> msg (swizzled)
// =====================================================================
template<bool AF32>
__global__ __launch_bounds__(256) void k_angle(
    const unsigned short* __restrict__ PAE,
    const void* a_in, unsigned short* a_out,
    const int* __restrict__ ti, const int* __restrict__ abatch,
    const unsigned short* __restrict__ Wt,    // wt_ea [64][192]
    const float* __restrict__ bias,
    const float* __restrict__ afAA, const float* __restrict__ afAB,
    float* __restrict__ gs1, float* __restrict__ gs2,
    unsigned short* __restrict__ pe, int nA)
{
  __shared__ float lAA[1024], lAB[1024];
  __shared__ float ls1[NG], ls2[NG];
  for (int i = threadIdx.x; i < 1024; i += 256) { lAA[i] = afAA[i]; lAB[i] = afAB[i]; }
  if (threadIdx.x < NG) { ls1[threadIdx.x] = 0.f; ls2[threadIdx.x] = 0.f; }
  __syncthreads();
  int gw = (int)((blockIdx.x * 256u + threadIdx.x) >> 6);
  int ntile = nA >> 4;
  bool act = gw < ntile;
  int lane = threadIdx.x & 63;
  int colb = lane & 15;
  int ko = (lane >> 4) << 3;
  int rowb = (lane >> 4) << 2;
  float sr[4] = {0.f,0.f,0.f,0.f}, ssr[4] = {0.f,0.f,0.f,0.f};
  if (act) {
    int sI[4], dI[4];
#pragma unroll
    for (int r = 0; r < 4; ++r) {
      int a_r = (gw << 4) + rowb + r;
      sI[r] = ti[a_r]; dI[r] = ti[nA + a_r];
    }
    bf16x8_t gS[4], gD[4];
#pragma unroll
    for (int r = 0; r < 4; ++r) {
      gS[r] = *(const bf16x8_t*)(PAE + (size_t)sI[r] * 256 + colb * 8);
      gD[r] = *(const bf16x8_t*)(PAE + (size_t)dI[r] * 256 + 128 + colb * 8);
    }
    int row = (gw << 4) + colb;
    int ga = abatch[row];
    f32x4_t acc[4] = {};
#pragma unroll
    for (int c2 = 0; c2 < 2; ++c2) {
      int fb = c2 * 32 + ko;
      float vv[8];
      ldrow8<AF32>(a_in, (size_t)row * 64 + fb, vv);
      bf16x8_t a;
#pragma unroll
      for (int k = 0; k < 8; ++k) a[k] = (short)f2bf(vv[k] * lAA[ga*64 + fb + k] + lAB[ga*64 + fb + k]);
#pragma unroll
      for (int nb = 0; nb < 4; ++nb) {
        bf16x8_t b = *(const bf16x8_t*)(Wt + (size_t)(nb * 16 + colb) * 192 + 128 + c2 * 32 + ko);
        acc[nb] = __builtin_amdgcn_mfma_f32_16x16x32_bf16(a, b, acc[nb], 0, 0, 0);
      }
    }
#pragma unroll
    for (int r = 0; r < 4; ++r) {
      int a_ = (gw << 4) + rowb + r;
      int gr = abatch[a_];
#pragma unroll
      for (int nb = 0; nb < 4; ++nb) {
        int col = nb * 16 + colb;
        size_t off = (size_t)a_ * 64 + col;
        float av = ldel<AF32>(a_in, off);
        float vv = av * lAA[gr*64 + col] + lAB[gr*64 + col] + bias[col] + acc[nb][r]
                 + bf2f((unsigned short)gS[r][nb]) + bf2f((unsigned short)gD[r][nb]);
        a_out[off] = f2bf(vv);
        sr[r] += vv; ssr[r] += vv * vv;
      }
      bf16x4_t pv;
#pragma unroll
      for (int nb = 0; nb < 4; ++nb)
        pv[nb] = (short)f2bf(bf2f((unsigned short)gS[r][4 + nb]) + bf2f((unsigned short)gD[r][4 + nb]));
      *(bf16x4_t*)(pe + (size_t)a_ * 64 + colb * 4) = pv;
    }
  }
#pragma unroll
  for (int m = 1; m <= 8; m <<= 1)
#pragma unroll
    for (int r = 0; r < 4; ++r) { sr[r] += __shfl_xor(sr[r], m); ssr[r] += __shfl_xor(ssr[r], m); }
  if (act && colb == 0) {
#pragma unroll
    for (int r = 0; r < 4; ++r) {
      int g = abatch[(gw << 4) + rowb + r];
      atomicAdd(&ls1[g], sr[r]); atomicAdd(&ls2[g], ssr[r]);
    }
  }
  __syncthreads();
  if (threadIdx.x < NG) {
    atomicAdd(&gs1[threadIdx.x], ls1[threadIdx.x]);
    atomicAdd(&gs2[threadIdx.x], ls2[threadIdx.x]);
  }
}

// =====================================================================
// emp finish (pure stream): msg = relu(pe + affA1(a1)@Wemp_a + b)
// =====================================================================
__global__ __launch_bounds__(256) void k_fin_emp(
    const unsigned short* __restrict__ a_, const int* __restrict__ abatch,
    const unsigned short* __restrict__ Wt,    // wt_emp [64][192]
    const float* __restrict__ bias,
    const float* __restrict__ afAA, const float* __restrict__ afAB,
    unsigned short* __restrict__ msg, int nA)
{
  __shared__ float lAA[1024], lAB[1024];
  for (int i = threadIdx.x; i < 1024; i += 256) { lAA[i] = afAA[i]; lAB[i] = afAB[i]; }
  __syncthreads();
  int gw = (int)((blockIdx.x * 256u + threadIdx.x) >> 6);
  int ntile = nA >> 4;
  if (gw >= ntile) return;
  int lane = threadIdx.x & 63;
  int colb = lane & 15;
  int ko = (lane >> 4) << 3;
  int rowb = (lane >> 4) << 2;
  int row = (gw << 4) + colb;
  int ga = abatch[row];
  f32x4_t acc[4] = {};
#pragma unroll
  for (int c2 = 0; c2 < 2; ++c2) {
    int fb = c2 * 32 + ko;
    bf16x8_t t = *(const bf16x8_t*)(a_ + (size_t)row * 64 + fb);
    bf16x8_t a;
#pragma unroll
    for (int k = 0; k < 8; ++k)
      a[k] = (short)f2bf(bf2f((unsigned short)t[k]) * lAA[ga*64 + fb + k] + lAB[ga*64 + fb + k]);
#pragma unroll
    for (int nb = 0; nb < 4; ++nb) {
      bf16x8_t b = *(const bf16x8_t*)(Wt + (size_t)(nb * 16 + colb) * 192 + 128 + c2 * 32 + ko);
      acc[nb] = __builtin_amdgcn_mfma_f32_16x16x32_bf16(a, b, acc[nb], 0, 0, 0);
    }
  }
  bf16x4_t p4[4];
#pragma unroll
  for (int r = 0; r < 4; ++r)
    p4[r] = *(const bf16x4_t*)(msg + (size_t)((gw << 4) + rowb + r) * 64 + colb * 4);
#pragma unroll
  for (int r = 0; r < 4; ++r) {
    int a_idx = (gw << 4) + rowb + r;
#pragma unroll
    for (int nb = 0; nb < 4; ++nb) {
      int col = nb * 16 + colb;
      float v = fmaxf(acc[nb][r] + bf2f((unsigned short)p4[r][nb]) + bias[col], 0.f);
      msg[(size_t)a_idx * 64 + col] = f2bf(v);
    }
  }
}

// =====================================================================
// nmp finish (pure stream): msg = relu(pn + affE2(e2)@Wnmp_e + b)
// =====================================================================
__global__ __launch_bounds__(256) void k_fin_nmp(
    const unsigned short* __restrict__ e, const int* __restrict__ ebatch,
    const unsigned short* __restrict__ Wt,    // wt_nmp [128][320]
    const float* __restrict__ bias,
    const float* __restrict__ afEA, const float* __restrict__ afEB,
    const unsigned short* __restrict__ pn,
    unsigned short* __restrict__ msg, int nE)
{
  __shared__ float lEA[1024], lEB[1024];
  for (int i = threadIdx.x; i < 1024; i += 256) { lEA[i] = afEA[i]; lEB[i] = afEB[i]; }
  __syncthreads();
  int gw = (int)((blockIdx.x * 256u + threadIdx.x) >> 6);
  int ntile = nE >> 4;
  if (gw >= ntile) return;
  int lane = threadIdx.x & 63;
  int colb = lane & 15;
  int ko = (lane >> 4) << 3;
  int rowb = (lane >> 4) << 2;
  int row = (gw << 4) + colb;
  int ge = ebatch[row];
  f32x4_t acc[8] = {};
#pragma unroll
  for (int c2 = 0; c2 < 2; ++c2) {
    int fb = c2 * 32 + ko;
    bf16x8_t t = *(const bf16x8_t*)(e + (size_t)row * 64 + fb);
    bf16x8_t a;
#pragma unroll
    for (int k = 0; k < 8; ++k)
      a[k] = (short)f2bf(bf2f((unsigned short)t[k]) * lEA[ge*64 + fb + k] + lEB[ge*64 + fb + k]);
#pragma unroll
    for (int nb = 0; nb < 8; ++nb) {
      bf16x8_t b = *(const bf16x8_t*)(Wt + (size_t)(nb * 16 + colb) * 320 + (8 + c2) * 32 + ko);
      acc[nb] = __builtin_amdgcn_mfma_f32_16x16x32_bf16(a, b, acc[nb], 0, 0, 0);
    }
  }
#pragma unroll
  for (int r = 0; r < 4; ++r) {
    int e_ = (gw << 4) + rowb + r;
    bf16x8_t p8 = *(const bf16x8_t*)(pn + (size_t)e_ * 128 + colb * 8);
#pragma unroll
    for (int nb = 0; nb < 8; ++nb) {
      int col = nb * 16 + colb;
      float v = fmaxf(acc[nb][r] + bf2f((unsigned short)p8[nb]) + bias[col], 0.f);
      msg[(size_t)e_ * 128 + col] = f2bf(v);
    }
  }
}

// =====================================================================
// CSR gather-reduce over edges: e2(bf16) = affE1(e1) + sum(msg rows); fused stats.
// =====================================================================
__global__ __launch_bounds__(256) void k_red_e(
    const unsigned short* __restrict__ msg, const unsigned short* e_in, unsigned short* e_out,
    const int* __restrict__ ptr, const int* __restrict__ perm,
    const int* __restrict__ ebatch,
    const float* __restrict__ afA, const float* __restrict__ afB,
    float* __restrict__ gs1, float* __restrict__ gs2, int nE)
{
  __shared__ float lA[1024], lB[1024], ls1[NG], ls2[NG];
  for (int i = threadIdx.x; i < 1024; i += 256) { lA[i] = afA[i]; lB[i] = afB[i]; }
  if (threadIdx.x < NG) { ls1[threadIdx.x] = 0.f; ls2[threadIdx.x] = 0.f; }
  __syncthreads();
  int lane = threadIdx.x & 63;
  int wv = (int)((blockIdx.x * 256u + threadIdx.x) >> 6);
  int nw = (int)((gridDim.x * 256u) >> 6);
  for (int eidx = wv; eidx < nE; eidx += nw) {
    int p0 = ptr[eidx], p1 = ptr[eidx + 1];
    float sum = 0.f;
    for (int j = p0; j < p1; ++j) {
      int aidx = perm[j];
      sum += bf2f(msg[(size_t)aidx * 64 + lane]);
    }
    int g = ebatch[eidx];
    size_t off = (size_t)eidx * 64 + lane;
    float v = bf2f(e_in[off]) * lA[g*64 + lane] + lB[g*64 + lane] + sum;
    e_out[off] = f2bf(v);
    float s = v, ss = v * v;
#pragma unroll
    for (int m = 1; m < 64; m <<= 1) { s += __shfl_xor(s, m); ss += __shfl_xor(ss, m); }
    if (lane == 0) { atomicAdd(&ls1[g], s); atomicAdd(&ls2[g], ss); }
  }
  __syncthreads();
  if (threadIdx.x < NG) {
    atomicAdd(&gs1[threadIdx.x], ls1[threadIdx.x]);
    atomicAdd(&gs2[threadIdx.x], ls2[threadIdx.x]);
  }
}

// =====================================================================
// CSR gather-reduce over nodes: h = x + sum(msg rows); fused stats. (x fp32)
// =====================================================================
__global__ __launch_bounds__(256) void k_red_n(
    const unsigned short* __restrict__ msg, const float* x_in, float* out,
    const int* __restrict__ ptr, const int* __restrict__ perm,
    const int* __restrict__ nbatch,
    float* __restrict__ gs1, float* __restrict__ gs2, int nN)
{
  __shared__ float ls1[NG], ls2[NG];
  if (threadIdx.x < NG) { ls1[threadIdx.x] = 0.f; ls2[threadIdx.x] = 0.f; }
  __syncthreads();
  int lane = threadIdx.x & 63;
  int wv = (int)((blockIdx.x * 256u + threadIdx.x) >> 6);
  int nw = (int)((gridDim.x * 256u) >> 6);
  for (int n = wv; n < nN; n += nw) {
    int p0 = ptr[n], p1 = ptr[n + 1];
    float s0 = 0.f, s1v = 0.f;
    for (int j = p0; j < p1; ++j) {
      int e = perm[j];
      unsigned u = *(const unsigned*)(msg + (size_t)e * 128 + lane * 2);
      s0 += bf2f((unsigned short)(u & 0xffffu));
      s1v += bf2f((unsigned short)(u >> 16));
    }
    size_t off = (size_t)n * 128 + lane * 2;
    float h0 = x_in[off] + s0, h1 = x_in[off + 1] + s1v;
    out[off] = h0; out[off + 1] = h1;
    float s = h0 + h1, ss = h0 * h0 + h1 * h1;
#pragma unroll
    for (int m = 1; m < 64; m <<= 1) { s += __shfl_xor(s, m); ss += __shfl_xor(ss, m); }
    if (lane == 0) { int g = nbatch[n]; atomicAdd(&ls1[g], s); atomicAdd(&ls2[g], ss); }
  }
  __syncthreads();
  if (threadIdx.x < NG) {
    atomicAdd(&gs1[threadIdx.x], ls1[threadIdx.x]);
    atomicAdd(&gs2[threadIdx.x], ls2[threadIdx.x]);
  }
}

// ---- affine table construction ----
__global__ __launch_bounds__(256) void k_mkaff(
    const float* __restrict__ s1, const float* __restrict__ s2,
    const float* __restrict__ cnt, int F,
    const float* __restrict__ w, const float* __restrict__ b,
    float* __restrict__ A, float* __restrict__ B)
{
  int idx = blockIdx.x * 256 + threadIdx.x;
  if (idx >= NG * F) return;
  int g = idx / F, f = idx - g * F;
  float norm = fmaxf(cnt[g], 1.f) * (float)F;
  float m = s1[g] / norm;
  float var = s2[g] / norm - m * m;
  float inv = rsqrtf(var + EPS);
  float a = inv * w[f];
  A[idx] = a;
  B[idx] = b[f] - m * a;
}

__global__ __launch_bounds__(256) void k_idaff(float* __restrict__ A, float* __restrict__ B, int n)
{
  int idx = blockIdx.x * 256 + threadIdx.x;
  if (idx < n) { A[idx] = 1.f; B[idx] = 0.f; }
}

// ---- apply norm to x (in-place, fp32) ----
__global__ __launch_bounds__(256) void k_apply(
    float* h, const int* __restrict__ batch,
    const float* __restrict__ A, const float* __restrict__ B, int nN)
{
  int total = nN * 16;
  int stride = gridDim.x * 256;
  for (int idx = blockIdx.x * 256 + threadIdx.x; idx < total; idx += stride) {
    int row = idx >> 4, q = (idx & 15) * 8;
    int g = batch[row];
    float* hp = h + (size_t)row * 128 + q;
    float4 f0 = *(const float4*)hp;
    float4 f1 = *(const float4*)(hp + 4);
    float vv[8] = {f0.x,f0.y,f0.z,f0.w,f1.x,f1.y,f1.z,f1.w};
#pragma unroll
    for (int k = 0; k < 8; ++k) vv[k] = vv[k] * A[(g << 7) + q + k] + B[(g << 7) + q + k];
    float4 g0 = {vv[0],vv[1],vv[2],vv[3]}, g1 = {vv[4],vv[5],vv[6],vv[7]};
    *(float4*)hp = g0;
    *(float4*)(hp + 4) = g1;
  }
}

__global__ __launch_bounds__(256) void k_count(
    const int* __restrict__ batch, int n, float* __restrict__ cnt)
{
  __shared__ float lc[NG];
  if (threadIdx.x < NG) lc[threadIdx.x] = 0.f;
  __syncthreads();
  for (int i = blockIdx.x * 256 + threadIdx.x; i < n; i += gridDim.x * 256)
    atomicAdd(&lc[batch[i]], 1.f);
  __syncthreads();
  if (threadIdx.x < NG) atomicAdd(&cnt[threadIdx.x], lc[threadIdx.x]);
}

// ---- CSR build ----
__global__ __launch_bounds__(256) void k_hist(
    const int* __restrict__ dst, int n, int* __restrict__ cnt)
{
  for (int i = blockIdx.x * 256 + threadIdx.x; i < n; i += gridDim.x * 256)
    atomicAdd(&cnt[dst[i]], 1);
}

__global__ __launch_bounds__(256) void k_scan1(
    const int* __restrict__ in, int* __restrict__ out, int* __restrict__ bsum, int n)
{
  __shared__ int wtot[4];
  int tid = threadIdx.x, lane = tid & 63, wid = tid >> 6;
  int base = blockIdx.x * 1024 + tid * 4;
  int v[4];
#pragma unroll
  for (int k = 0; k < 4; ++k) v[k] = (base + k < n) ? in[base + k] : 0;
  int tsum = v[0] + v[1] + v[2] + v[3];
  int incl = tsum;
#pragma unroll
  for (int off = 1; off < 64; off <<= 1) {
    int up = __shfl_up(incl, off);
    if (lane >= off) incl += up;
  }
  if (lane == 63) wtot[wid] = incl;
  __syncthreads();
  if (tid == 0) {
    int r = 0;
#pragma unroll
    for (int w2 = 0; w2 < 4; ++w2) { int t = wtot[w2]; wtot[w2] = r; r += t; }
    bsum[blockIdx.x] = r;
  }
  __syncthreads();
  int excl = wtot[wid] + incl - tsum;
#pragma unroll
  for (int k = 0; k < 4; ++k) {
    if (base + k < n) out[base + k] = excl;
    excl += v[k];
  }
}

__global__ __launch_bounds__(256) void k_scan2(int* __restrict__ bsum, int nb, int* __restrict__ total_out)
{
  __shared__ int wtot[4];
  int tid = threadIdx.x, lane = tid & 63, wid = tid >> 6;
  int base = tid * 4;
  int v[4];
#pragma unroll
  for (int k = 0; k < 4; ++k) v[k] = (base + k < nb) ? bsum[base + k] : 0;
  int tsum = v[0] + v[1] + v[2] + v[3];
  int incl = tsum;
#pragma unroll
  for (int off = 1; off < 64; off <<= 1) {
    int up = __shfl_up(incl, off);
    if (lane >= off) incl += up;
  }
  if (lane == 63) wtot[wid] = incl;
  __syncthreads();
  if (tid == 0) {
    int r = 0;
#pragma unroll
    for (int w2 = 0; w2 < 4; ++w2) { int t = wtot[w2]; wtot[w2] = r; r += t; }
    *total_out = r;
  }
  __syncthreads();
  int excl = wtot[wid] + incl - tsum;
#pragma unroll
  for (int k = 0; k < 4; ++k) {
    if (base + k < nb) bsum[base + k] = excl;
    excl += v[k];
  }
}

__global__ __launch_bounds__(256) void k_scan3(
    int* __restrict__ ptr, int* __restrict__ cur, const int* __restrict__ bsum, int n)
{
  for (int i = blockIdx.x * 256 + threadIdx.x; i < n; i += gridDim.x * 256) {
    int v = ptr[i] + bsum[i >> 10];
    ptr[i] = v; cur[i] = v;
  }
}

__global__ __launch_bounds__(256) void k_scatter(
    const int* __restrict__ dst, int* __restrict__ cur, int* __restrict__ perm, int n)
{
  for (int i = blockIdx.x * 256 + threadIdx.x; i < n; i += gridDim.x * 256) {
    int d = dst[i];
    int p = atomicAdd(&cur[d], 1);
    perm[p] = i;
  }
}

// ---- weight prep ----
__global__ __launch_bounds__(256) void k_wt(
    const float* __restrict__ W, unsigned short* __restrict__ Wt, int K, int NO)
{
  int idx = blockIdx.x * 256 + threadIdx.x;
  if (idx >= K * NO) return;
  int k = idx / NO, j = idx - k * NO;
  Wt[(size_t)j * K + k] = f2bf(W[idx]);
}

extern "C" void kernel_launch(void* const* d_in, const int* in_sizes, int n_in,
                              void* d_out, int out_size, void* d_ws, size_t ws_size,
                              hipStream_t stream)
{
  const float* x0    = (const float*)d_in[0];
  const float* e0    = (const float*)d_in[1];
  const float* a0    = (const float*)d_in[2];
  const float* W_ne  = (const float*)d_in[3];
  const float* b_ne  = (const float*)d_in[4];
  const float* g_e   = (const float*)d_in[5];
  const float* be_e  = (const float*)d_in[6];
  const float* W_ea  = (const float*)d_in[7];
  const float* b_ea  = (const float*)d_in[8];
  const float* g_a   = (const float*)d_in[9];
  const float* be_a  = (const float*)d_in[10];
  const float* W_emp = (const float*)d_in[11];
  const float* b_emp = (const float*)d_in[12];
  const float* g_emp = (const float*)d_in[13];
  const float* be_emp= (const float*)d_in[14];
  const float* W_nmp = (const float*)d_in[15];
  const float* b_nmp = (const float*)d_in[16];
  const float* g_nmp = (const float*)d_in[17];
  const float* be_nmp= (const float*)d_in[18];
  const int* node_batch  = (const int*)d_in[19];
  const int* edge_index  = (const int*)d_in[20];
  const int* edge_batch  = (const int*)d_in[21];
  const int* tb_index    = (const int*)d_in[22];
  const int* angle_batch = (const int*)d_in[23];

  const int N = in_sizes[0] / 128;
  const int E = in_sizes[1] / 64;
  const int A = in_sizes[2] / 64;

  // ---- workspace layout (bytes, 256-aligned) ----
  char* wsp = (char*)d_ws;
  auto alloc = [&](size_t bytes) { char* p = wsp; wsp += (bytes + 255) & ~(size_t)255; return p; };
  unsigned short* eAB  = (unsigned short*)alloc((size_t)E * 64 * 2);   // e intermediate (bf16)
  unsigned short* aAB  = (unsigned short*)alloc((size_t)A * 64 * 2);   // a intermediate (bf16)
  unsigned short* msg  = (unsigned short*)alloc((size_t)A * 64 * 2);   // hosts P, pe, msg_e, msg_n
  unsigned short* pn   = (unsigned short*)alloc((size_t)E * 128 * 2);  // nmp x-partial (swizzled)
  unsigned short* PAE  = (unsigned short*)alloc((size_t)E * 256 * 2);  // angle+emp partials (swizzled)
  int* ptr_n  = (int*)alloc((size_t)(N + 1) * 4);
  int* cur_n  = (int*)alloc((size_t)N * 4);
  int* perm_n = (int*)alloc((size_t)E * 4);
  int* ptr_e  = (int*)alloc((size_t)(E + 1) * 4);
  int* cur_e  = (int*)alloc((size_t)E * 4);
  int* perm_e = (int*)alloc((size_t)A * 4);
  int* bsum   = (int*)alloc(4096 * 4);
  float* stats = (float*)alloc(5 * NG * 4);   // contiguous: s1,s2,cnt_n,cnt_e,cnt_a
  float* s1    = stats;
  float* s2    = stats + NG;
  float* cnt_n = stats + 2 * NG;
  float* cnt_e = stats + 3 * NG;
  float* cnt_a = stats + 4 * NG;
  float* afE_idA = (float*)alloc(1024 * 4); float* afE_idB = (float*)alloc(1024 * 4);
  float* afA_idA = (float*)alloc(1024 * 4); float* afA_idB = (float*)alloc(1024 * 4);
  float* afE1A   = (float*)alloc(1024 * 4); float* afE1B   = (float*)alloc(1024 * 4);
  float* afE2A   = (float*)alloc(1024 * 4); float* afE2B   = (float*)alloc(1024 * 4);
  float* afA1A   = (float*)alloc(1024 * 4); float* afA1B   = (float*)alloc(1024 * 4);
  float* afXA    = (float*)alloc(2048 * 4); float* afXB    = (float*)alloc(2048 * 4);
  unsigned short* wt_ne  = (unsigned short*)alloc((size_t)2 * 320 * 64 * 2);
  unsigned short* wt_ea  = (unsigned short*)alloc((size_t)2 * 192 * 64 * 2);
  unsigned short* wt_emp = (unsigned short*)alloc((size_t)2 * 192 * 64 * 2);
  unsigned short* wt_nmp = (unsigned short*)alloc((size_t)2 * 320 * 128 * 2);

  unsigned short* P = msg;   // P (N*384 bf16) lives in msg; dead before pe/msg written
  float* x_out = (float*)d_out;

  // ---- one-time prep ----
  for (int i = 0; i < 2; ++i) {
    k_wt<<<(320*64 + 255)/256, 256, 0, stream>>>(W_ne  + (size_t)i*320*64,  wt_ne  + (size_t)i*320*64,  320, 64);
    k_wt<<<(192*64 + 255)/256, 256, 0, stream>>>(W_ea  + (size_t)i*192*64,  wt_ea  + (size_t)i*192*64,  192, 64);
    k_wt<<<(192*64 + 255)/256, 256, 0, stream>>>(W_emp + (size_t)i*192*64,  wt_emp + (size_t)i*192*64,  192, 64);
    k_wt<<<(320*128 + 255)/256, 256, 0, stream>>>(W_nmp + (size_t)i*320*128, wt_nmp + (size_t)i*320*128, 320, 128);
  }
  hipMemsetAsync(stats, 0, 5 * NG * 4, stream);
  k_count<<<512, 256, 0, stream>>>(node_batch, N, cnt_n);
  k_count<<<512, 256, 0, stream>>>(edge_batch, E, cnt_e);
  k_count<<<512, 256, 0, stream>>>(angle_batch, A, cnt_a);
  k_idaff<<<4, 256, 0, stream>>>(afE_idA, afE_idB, 1024);
  k_idaff<<<4, 256, 0, stream>>>(afA_idA, afA_idB, 1024);

  // CSR over nodes (dst of edge_index) and edges (dst of threebody)
  hipMemsetAsync(cur_n, 0, (size_t)N * 4, stream);
  hipMemsetAsync(cur_e, 0, (size_t)E * 4, stream);
  k_hist<<<1024, 256, 0, stream>>>(edge_index + E, E, cur_n);
  k_hist<<<1024, 256, 0, stream>>>(tb_index + A, A, cur_e);
  int nbN = (N + 1023) / 1024, nbE = (E + 1023) / 1024;
  k_scan1<<<nbN, 256, 0, stream>>>(cur_n, ptr_n, bsum, N);
  k_scan2<<<1, 256, 0, stream>>>(bsum, nbN, ptr_n + N);
  k_scan3<<<1024, 256, 0, stream>>>(ptr_n, cur_n, bsum, N);
  k_scatter<<<1024, 256, 0, stream>>>(edge_index + E, cur_n, perm_n, E);
  k_scan1<<<nbE, 256, 0, stream>>>(cur_e, ptr_e, bsum, E);
  k_scan2<<<1, 256, 0, stream>>>(bsum, nbE, ptr_e + E);
  k_scan3<<<1024, 256, 0, stream>>>(ptr_e, cur_e, bsum, E);
  k_scatter<<<1024, 256, 0, stream>>>(tb_index + A, cur_e, perm_e, A);

  const float* x_cur = x0;
  int blkE = (E / 16 + 3) / 4;
  int blkA = (A / 16 + 3) / 4;
  int blkN = (N / 16 + 3) / 4;

  for (int i = 0; i < 2; ++i) {
    const float* fEinA = (i == 0) ? afE_idA : afE2A;
    const float* fEinB = (i == 0) ? afE_idB : afE2B;
    const float* fAinA = (i == 0) ? afA_idA : afA1A;
    const float* fAinB = (i == 0) ? afA_idB : afA1B;

    // 0. dense x-partials
    k_dense_x<<<blkN, 256, 0, stream>>>(x_cur, wt_ne + (size_t)i*320*64,
                                        wt_nmp + (size_t)i*320*128, P, N);

    // 1. edge stage (co-gathers stage-4 x-partials) -> affE1
    hipMemsetAsync(s1, 0, 2 * NG * 4, stream);
    if (i == 0)
      k_edge<true><<<blkE, 256, 0, stream>>>(P, (const void*)e0, eAB, edge_index, edge_batch,
                                             wt_ne + (size_t)i*320*64, b_ne + i*64,
                                             fEinA, fEinB, s1, s2, pn, E);
    else
      k_edge<false><<<blkE, 256, 0, stream>>>(P, (const void*)eAB, eAB, edge_index, edge_batch,
                                              wt_ne + (size_t)i*320*64, b_ne + i*64,
                                              fEinA, fEinB, s1, s2, pn, E);
    k_mkaff<<<4, 256, 0, stream>>>(s1, s2, cnt_e, 64, g_e + i*64, be_e + i*64, afE1A, afE1B);

    // 1.5 dense angle+emp partials over edges -> PAE
    k_prep_e<<<blkE, 256, 0, stream>>>(eAB, edge_batch, afE1A, afE1B,
                                       wt_ea + (size_t)i*192*64, wt_emp + (size_t)i*192*64,
                                       PAE, E);

    // 2. angle stage (adds-only gathers) -> affA1, pe -> msg
    hipMemsetAsync(s1, 0, 2 * NG * 4, stream);
    if (i == 0)
      k_angle<true><<<blkA, 256, 0, stream>>>(PAE, (const void*)a0, aAB, tb_index, angle_batch,
                                              wt_ea + (size_t)i*192*64, b_ea + i*64,
                                              fAinA, fAinB, s1, s2, msg, A);
    else
      k_angle<false><<<blkA, 256, 0, stream>>>(PAE, (const void*)aAB, aAB, tb_index, angle_batch,
                                               wt_ea + (size_t)i*192*64, b_ea + i*64,
                                               fAinA, fAinB, s1, s2, msg, A);
    k_mkaff<<<4, 256, 0, stream>>>(s1, s2, cnt_a, 64, g_a + i*64, be_a + i*64, afA1A, afA1B);

    // 3. emp finish (stream) -> msg; CSR reduce -> affE2
    k_fin_emp<<<blkA, 256, 0, stream>>>(aAB, angle_batch, wt_emp + (size_t)i*192*64,
                                        b_emp + i*64, afA1A, afA1B, msg, A);
    hipMemsetAsync(s1, 0, 2 * NG * 4, stream);
    k_red_e<<<2048, 256, 0, stream>>>(msg, eAB, eAB, ptr_e, perm_e, edge_batch,
                                      afE1A, afE1B, s1, s2, E);
    k_mkaff<<<4, 256, 0, stream>>>(s1, s2, cnt_e, 64, g_emp + i*64, be_emp + i*64, afE2A, afE2B);

    // 4. nmp finish (stream) -> msg; CSR reduce; apply
    k_fin_nmp<<<blkE, 256, 0, stream>>>(eAB, edge_batch, wt_nmp + (size_t)i*320*128,
                                        b_nmp + i*128, afE2A, afE2B, pn, msg, E);
    hipMemsetAsync(s1, 0, 2 * NG * 4, stream);
    k_red_n<<<2048, 256, 0, stream>>>(msg, x_cur, x_out, ptr_n, perm_n, node_batch,
                                      s1, s2, N);
    k_mkaff<<<8, 256, 0, stream>>>(s1, s2, cnt_n, 128, g_nmp + i*128, be_nmp + i*128, afXA, afXB);
    k_apply<<<2048, 256, 0, stream>>>(x_out, node_batch, afXA, afXB, N);

    x_cur = x_out;
  }
}

// Round 10
// 1625.556 us; speedup vs baseline: 1.4318x; 1.0340x over previous
//
#include <hip/hip_runtime.h>

typedef __attribute__((ext_vector_type(8))) short bf16x8_t;
typedef __attribute__((ext_vector_type(4))) short bf16x4_t;
typedef __attribute__((ext_vector_type(4))) float f32x4_t;

constexpr int NG = 16;
constexpr float EPS = 1e-5f;

__device__ inline unsigned short f2bf(float f) {
  unsigned u = __builtin_bit_cast(unsigned, f);
  u += 0x7FFFu + ((u >> 16) & 1u);
  return (unsigned short)(u >> 16);
}
__device__ inline float bf2f(unsigned short u) {
  unsigned x = ((unsigned)u) << 16;
  return __builtin_bit_cast(float, x);
}

// load 8 contiguous elements as f32 from fp32 or bf16 storage
template<bool F32>
__device__ inline void ldrow8(const void* base, size_t off, float v[8]) {
  if constexpr (F32) {
    const float* p = (const float*)base + off;
    float4 f0 = *(const float4*)p, f1 = *(const float4*)(p + 4);
    v[0]=f0.x; v[1]=f0.y; v[2]=f0.z; v[3]=f0.w;
    v[4]=f1.x; v[5]=f1.y; v[6]=f1.z; v[7]=f1.w;
  } else {
    bf16x8_t t = *(const bf16x8_t*)((const unsigned short*)base + off);
#pragma unroll
    for (int k = 0; k < 8; ++k) v[k] = bf2f((unsigned short)t[k]);
  }
}
template<bool F32>
__device__ inline float ldel(const void* base, size_t off) {
  if constexpr (F32) return ((const float*)base)[off];
  return bf2f(((const unsigned short*)base)[off]);
}

// =====================================================================
// Dense partial GEMM over nodes (coalesced):
//   P[n] = x[n] @ [Wne_s | Wne_d | Wnmp_s | Wnmp_d]  (N x 384 bf16, swizzled)
// =====================================================================
__global__ __launch_bounds__(256) void k_dense_x(
    const float* __restrict__ x,
    const unsigned short* __restrict__ WtNE,   // [64][320]
    const unsigned short* __restrict__ WtNM,   // [128][320]
    unsigned short* __restrict__ P, int nN)
{
  int gw = (int)((blockIdx.x * 256u + threadIdx.x) >> 6);
  int ntile = nN >> 4;
  if (gw >= ntile) return;
  int lane = threadIdx.x & 63;
  int colb = lane & 15;
  int ko = (lane >> 4) << 3;
  int rowb = (lane >> 4) << 2;
  int row = (gw << 4) + colb;
  const float* xr = x + (size_t)row * 128;
  f32x4_t a1[4] = {}, a2[4] = {}, a3[8] = {}, a4[8] = {};
#pragma unroll
  for (int c = 0; c < 4; ++c) {
    float4 f0 = *(const float4*)(xr + c * 32 + ko);
    float4 f1 = *(const float4*)(xr + c * 32 + ko + 4);
    float vv[8] = {f0.x,f0.y,f0.z,f0.w,f1.x,f1.y,f1.z,f1.w};
    bf16x8_t a;
#pragma unroll
    for (int k = 0; k < 8; ++k) a[k] = (short)f2bf(vv[k]);
#pragma unroll
    for (int nb = 0; nb < 4; ++nb) {
      bf16x8_t b1 = *(const bf16x8_t*)(WtNE + (size_t)(nb * 16 + colb) * 320 + c * 32 + ko);
      a1[nb] = __builtin_amdgcn_mfma_f32_16x16x32_bf16(a, b1, a1[nb], 0, 0, 0);
      bf16x8_t b2 = *(const bf16x8_t*)(WtNE + (size_t)(nb * 16 + colb) * 320 + (c + 4) * 32 + ko);
      a2[nb] = __builtin_amdgcn_mfma_f32_16x16x32_bf16(a, b2, a2[nb], 0, 0, 0);
    }
#pragma unroll
    for (int nb = 0; nb < 8; ++nb) {
      bf16x8_t b3 = *(const bf16x8_t*)(WtNM + (size_t)(nb * 16 + colb) * 320 + c * 32 + ko);
      a3[nb] = __builtin_amdgcn_mfma_f32_16x16x32_bf16(a, b3, a3[nb], 0, 0, 0);
      bf16x8_t b4 = *(const bf16x8_t*)(WtNM + (size_t)(nb * 16 + colb) * 320 + (c + 4) * 32 + ko);
      a4[nb] = __builtin_amdgcn_mfma_f32_16x16x32_bf16(a, b4, a4[nb], 0, 0, 0);
    }
  }
#pragma unroll
  for (int r = 0; r < 4; ++r) {
    size_t ro = (size_t)((gw << 4) + rowb + r) * 384;
    bf16x4_t t1, t2;
#pragma unroll
    for (int nb = 0; nb < 4; ++nb) { t1[nb] = (short)f2bf(a1[nb][r]); t2[nb] = (short)f2bf(a2[nb][r]); }
    *(bf16x4_t*)(P + ro + colb * 4) = t1;
    *(bf16x4_t*)(P + ro + 64 + colb * 4) = t2;
    bf16x8_t t3, t4;
#pragma unroll
    for (int nb = 0; nb < 8; ++nb) { t3[nb] = (short)f2bf(a3[nb][r]); t4[nb] = (short)f2bf(a4[nb][r]); }
    *(bf16x8_t*)(P + ro + 128 + colb * 8) = t3;
    *(bf16x8_t*)(P + ro + 256 + colb * 8) = t4;
  }
}

// =====================================================================
// Dense angle+emp partials over edges (coalesced, one eAB read):
//   ê = affE1(e);  PA1=ê@Wea_s, PA2=ê@Wea_d, PE3=ê@Wemp_s, PE4=ê@Wemp_d
// PAE row (256): s-half at colb*8: [PA1|PE3]; d-half at 128+colb*8: [PA2|PE4].
// =====================================================================
__global__ __launch_bounds__(256) void k_prep_e(
    const unsigned short* __restrict__ eA, const int* __restrict__ ebatch,
    const float* __restrict__ afA, const float* __restrict__ afB,
    const unsigned short* __restrict__ WtA,    // wt_ea  [64][192]
    const unsigned short* __restrict__ WtP,    // wt_emp [64][192]
    unsigned short* __restrict__ PAE, int nE)
{
  __shared__ float lA[1024], lB[1024];
  for (int i = threadIdx.x; i < 1024; i += 256) { lA[i] = afA[i]; lB[i] = afB[i]; }
  __syncthreads();
  int gw = (int)((blockIdx.x * 256u + threadIdx.x) >> 6);
  int ntile = nE >> 4;
  if (gw >= ntile) return;
  int lane = threadIdx.x & 63;
  int colb = lane & 15;
  int ko = (lane >> 4) << 3;
  int rowb = (lane >> 4) << 2;
  int row = (gw << 4) + colb;
  int ge = ebatch[row];
  f32x4_t pa1[4] = {}, pa2[4] = {}, pe3[4] = {}, pe4[4] = {};
#pragma unroll
  for (int c2 = 0; c2 < 2; ++c2) {
    int fb = c2 * 32 + ko;
    bf16x8_t t = *(const bf16x8_t*)(eA + (size_t)row * 64 + fb);
    bf16x8_t an;
#pragma unroll
    for (int k = 0; k < 8; ++k)
      an[k] = (short)f2bf(bf2f((unsigned short)t[k]) * lA[ge*64 + fb + k] + lB[ge*64 + fb + k]);
#pragma unroll
    for (int nb = 0; nb < 4; ++nb) {
      size_t wb = (size_t)(nb * 16 + colb) * 192;
      bf16x8_t b;
      b = *(const bf16x8_t*)(WtA + wb + c2 * 32 + ko);
      pa1[nb] = __builtin_amdgcn_mfma_f32_16x16x32_bf16(an, b, pa1[nb], 0, 0, 0);
      b = *(const bf16x8_t*)(WtA + wb + 64 + c2 * 32 + ko);
      pa2[nb] = __builtin_amdgcn_mfma_f32_16x16x32_bf16(an, b, pa2[nb], 0, 0, 0);
      b = *(const bf16x8_t*)(WtP + wb + c2 * 32 + ko);
      pe3[nb] = __builtin_amdgcn_mfma_f32_16x16x32_bf16(an, b, pe3[nb], 0, 0, 0);
      b = *(const bf16x8_t*)(WtP + wb + 64 + c2 * 32 + ko);
      pe4[nb] = __builtin_amdgcn_mfma_f32_16x16x32_bf16(an, b, pe4[nb], 0, 0, 0);
    }
  }
#pragma unroll
  for (int r = 0; r < 4; ++r) {
    size_t ro = (size_t)((gw << 4) + rowb + r) * 256;
    bf16x8_t sH, dH;
#pragma unroll
    for (int nb = 0; nb < 4; ++nb) {
      sH[nb] = (short)f2bf(pa1[nb][r]); sH[4 + nb] = (short)f2bf(pe3[nb][r]);
      dH[nb] = (short)f2bf(pa2[nb][r]); dH[4 + nb] = (short)f2bf(pe4[nb][r]);
    }
    *(bf16x8_t*)(PAE + ro + colb * 8) = sH;
    *(bf16x8_t*)(PAE + ro + 128 + colb * 8) = dH;
  }
}

// =====================================================================
// EDGE stage (light): e_out(bf16) = affEin(e_in) + P_T1[s]+P_T2[d]
//                     + affEin(e_in)@Wne_e + b  (+stats)
// (T3/T4 gathers moved to k_fin_nmp — pn round trip deleted.)
// =====================================================================
template<bool EF32>
__global__ __launch_bounds__(256) void k_edge(
    const unsigned short* __restrict__ P, const void* e_in, unsigned short* e_out,
    const int* __restrict__ ei, const int* __restrict__ ebatch,
    const unsigned short* __restrict__ Wt,    // wt_ne [64][320]
    const float* __restrict__ bias,
    const float* __restrict__ afA, const float* __restrict__ afB,
    float* __restrict__ gs1, float* __restrict__ gs2, int nE)
{
  __shared__ float lA[1024], lB[1024];
  __shared__ float ls1[NG], ls2[NG];
  for (int i = threadIdx.x; i < 1024; i += 256) { lA[i] = afA[i]; lB[i] = afB[i]; }
  if (threadIdx.x < NG) { ls1[threadIdx.x] = 0.f; ls2[threadIdx.x] = 0.f; }
  __syncthreads();
  int gw = (int)((blockIdx.x * 256u + threadIdx.x) >> 6);
  int ntile = nE >> 4;
  bool act = gw < ntile;
  int lane = threadIdx.x & 63;
  int colb = lane & 15;
  int ko = (lane >> 4) << 3;
  int rowb = (lane >> 4) << 2;
  float sr[4] = {0.f,0.f,0.f,0.f}, ssr[4] = {0.f,0.f,0.f,0.f};
  if (act) {
    int sI[4], dI[4];
#pragma unroll
    for (int r = 0; r < 4; ++r) {
      int e_r = (gw << 4) + rowb + r;
      sI[r] = ei[e_r]; dI[r] = ei[nE + e_r];
    }
    bf16x4_t g1[4], g2[4];
#pragma unroll
    for (int r = 0; r < 4; ++r) {
      g1[r] = *(const bf16x4_t*)(P + (size_t)sI[r] * 384 + colb * 4);
      g2[r] = *(const bf16x4_t*)(P + (size_t)dI[r] * 384 + 64 + colb * 4);
    }
    int row = (gw << 4) + colb;
    int ge = ebatch[row];
    f32x4_t acc[4] = {};
#pragma unroll
    for (int c2 = 0; c2 < 2; ++c2) {
      int fb = c2 * 32 + ko;
      float vv[8];
      ldrow8<EF32>(e_in, (size_t)row * 64 + fb, vv);
      bf16x8_t a;
#pragma unroll
      for (int k = 0; k < 8; ++k) a[k] = (short)f2bf(vv[k] * lA[ge*64 + fb + k] + lB[ge*64 + fb + k]);
#pragma unroll
      for (int nb = 0; nb < 4; ++nb) {
        bf16x8_t b = *(const bf16x8_t*)(Wt + (size_t)(nb * 16 + colb) * 320 + (8 + c2) * 32 + ko);
        acc[nb] = __builtin_amdgcn_mfma_f32_16x16x32_bf16(a, b, acc[nb], 0, 0, 0);
      }
    }
#pragma unroll
    for (int r = 0; r < 4; ++r) {
      int e_ = (gw << 4) + rowb + r;
      int gr = ebatch[e_];
#pragma unroll
      for (int nb = 0; nb < 4; ++nb) {
        int col = nb * 16 + colb;
        size_t off = (size_t)e_ * 64 + col;
        float ev = ldel<EF32>(e_in, off);
        float vv = ev * lA[gr*64 + col] + lB[gr*64 + col] + bias[col]
                 + acc[nb][r] + bf2f((unsigned short)g1[r][nb]) + bf2f((unsigned short)g2[r][nb]);
        e_out[off] = f2bf(vv);
        sr[r] += vv; ssr[r] += vv * vv;
      }
    }
  }
#pragma unroll
  for (int m = 1; m <= 8; m <<= 1)
#pragma unroll
    for (int r = 0; r < 4; ++r) { sr[r] += __shfl_xor(sr[r], m); ssr[r] += __shfl_xor(ssr[r], m); }
  if (act && colb == 0) {
#pragma unroll
    for (int r = 0; r < 4; ++r) {
      int g = ebatch[(gw << 4) + rowb + r];
      atomicAdd(&ls1[g], sr[r]); atomicAdd(&ls2[g], ssr[r]);
    }
  }
  __syncthreads();
  if (threadIdx.x < NG) {
    atomicAdd(&gs1[threadIdx.x], ls1[threadIdx.x]);
    atomicAdd(&gs2[threadIdx.x], ls2[threadIdx.x]);
  }
}

// =====================================================================
// ANGLE stage: adds-only gathers from PAE.
//   a_out(bf16) = affAin(a_in) + PA1[s]+PA2[d] + affAin(a_in)@Wea_a + b (+stats)
//   pe = PE3[s] + PE4[d]  -> msg (swizzled)
// =====================================================================
template<bool AF32>
__global__ __launch_bounds__(256) void k_angle(
    const unsigned short* __restrict__ PAE,
    const void* a_in, unsigned short* a_out,
    const int* __restrict__ ti, const int* __restrict__ abatch,
    const unsigned short* __restrict__ Wt,    // wt_ea [64][192]
    const float* __restrict__ bias,
    const float* __restrict__ afAA, const float* __restrict__ afAB,
    float* __restrict__ gs1, float* __restrict__ gs2,
    unsigned short* __restrict__ pe, int nA)
{
  __shared__ float lAA[1024], lAB[1024];
  __shared__ float ls1[NG], ls2[NG];
  for (int i = threadIdx.x; i < 1024; i += 256) { lAA[i] = afAA[i]; lAB[i] = afAB[i]; }
  if (threadIdx.x < NG) { ls1[threadIdx.x] = 0.f; ls2[threadIdx.x] = 0.f; }
  __syncthreads();
  int gw = (int)((blockIdx.x * 256u + threadIdx.x) >> 6);
  int ntile = nA >> 4;
  bool act = gw < ntile;
  int lane = threadIdx.x & 63;
  int colb = lane & 15;
  int ko = (lane >> 4) << 3;
  int rowb = (lane >> 4) << 2;
  float sr[4] = {0.f,0.f,0.f,0.f}, ssr[4] = {0.f,0.f,0.f,0.f};
  if (act) {
    int sI[4], dI[4];
#pragma unroll
    for (int r = 0; r < 4; ++r) {
      int a_r = (gw << 4) + rowb + r;
      sI[r] = ti[a_r]; dI[r] = ti[nA + a_r];
    }
    bf16x8_t gS[4], gD[4];
#pragma unroll
    for (int r = 0; r < 4; ++r) {
      gS[r] = *(const bf16x8_t*)(PAE + (size_t)sI[r] * 256 + colb * 8);
      gD[r] = *(const bf16x8_t*)(PAE + (size_t)dI[r] * 256 + 128 + colb * 8);
    }
    int row = (gw << 4) + colb;
    int ga = abatch[row];
    f32x4_t acc[4] = {};
#pragma unroll
    for (int c2 = 0; c2 < 2; ++c2) {
      int fb = c2 * 32 + ko;
      float vv[8];
      ldrow8<AF32>(a_in, (size_t)row * 64 + fb, vv);
      bf16x8_t a;
#pragma unroll
      for (int k = 0; k < 8; ++k) a[k] = (short)f2bf(vv[k] * lAA[ga*64 + fb + k] + lAB[ga*64 + fb + k]);
#pragma unroll
      for (int nb = 0; nb < 4; ++nb) {
        bf16x8_t b = *(const bf16x8_t*)(Wt + (size_t)(nb * 16 + colb) * 192 + 128 + c2 * 32 + ko);
        acc[nb] = __builtin_amdgcn_mfma_f32_16x16x32_bf16(a, b, acc[nb], 0, 0, 0);
      }
    }
#pragma unroll
    for (int r = 0; r < 4; ++r) {
      int a_ = (gw << 4) + rowb + r;
      int gr = abatch[a_];
#pragma unroll
      for (int nb = 0; nb < 4; ++nb) {
        int col = nb * 16 + colb;
        size_t off = (size_t)a_ * 64 + col;
        float av = ldel<AF32>(a_in, off);
        float vv = av * lAA[gr*64 + col] + lAB[gr*64 + col] + bias[col] + acc[nb][r]
                 + bf2f((unsigned short)gS[r][nb]) + bf2f((unsigned short)gD[r][nb]);
        a_out[off] = f2bf(vv);
        sr[r] += vv; ssr[r] += vv * vv;
      }
      bf16x4_t pv;
#pragma unroll
      for (int nb = 0; nb < 4; ++nb)
        pv[nb] = (short)f2bf(bf2f((unsigned short)gS[r][4 + nb]) + bf2f((unsigned short)gD[r][4 + nb]));
      *(bf16x4_t*)(pe + (size_t)a_ * 64 + colb * 4) = pv;
    }
  }
#pragma unroll
  for (int m = 1; m <= 8; m <<= 1)
#pragma unroll
    for (int r = 0; r < 4; ++r) { sr[r] += __shfl_xor(sr[r], m); ssr[r] += __shfl_xor(ssr[r], m); }
  if (act && colb == 0) {
#pragma unroll
    for (int r = 0; r < 4; ++r) {
      int g = abatch[(gw << 4) + rowb + r];
      atomicAdd(&ls1[g], sr[r]); atomicAdd(&ls2[g], ssr[r]);
    }
  }
  __syncthreads();
  if (threadIdx.x < NG) {
    atomicAdd(&gs1[threadIdx.x], ls1[threadIdx.x]);
    atomicAdd(&gs2[threadIdx.x], ls2[threadIdx.x]);
  }
}

// =====================================================================
// emp finish (pure stream): msg = relu(pe + affA1(a1)@Wemp_a + b)
// =====================================================================
__global__ __launch_bounds__(256) void k_fin_emp(
    const unsigned short* __restrict__ a_, const int* __restrict__ abatch,
    const unsigned short* __restrict__ Wt,    // wt_emp [64][192]
    const float* __restrict__ bias,
    const float* __restrict__ afAA, const float* __restrict__ afAB,
    unsigned short* __restrict__ msg, int nA)
{
  __shared__ float lAA[1024], lAB[1024];
  for (int i = threadIdx.x; i < 1024; i += 256) { lAA[i] = afAA[i]; lAB[i] = afAB[i]; }
  __syncthreads();
  int gw = (int)((blockIdx.x * 256u + threadIdx.x) >> 6);
  int ntile = nA >> 4;
  if (gw >= ntile) return;
  int lane = threadIdx.x & 63;
  int colb = lane & 15;
  int ko = (lane >> 4) << 3;
  int rowb = (lane >> 4) << 2;
  int row = (gw << 4) + colb;
  int ga = abatch[row];
  f32x4_t acc[4] = {};
#pragma unroll
  for (int c2 = 0; c2 < 2; ++c2) {
    int fb = c2 * 32 + ko;
    bf16x8_t t = *(const bf16x8_t*)(a_ + (size_t)row * 64 + fb);
    bf16x8_t a;
#pragma unroll
    for (int k = 0; k < 8; ++k)
      a[k] = (short)f2bf(bf2f((unsigned short)t[k]) * lAA[ga*64 + fb + k] + lAB[ga*64 + fb + k]);
#pragma unroll
    for (int nb = 0; nb < 4; ++nb) {
      bf16x8_t b = *(const bf16x8_t*)(Wt + (size_t)(nb * 16 + colb) * 192 + 128 + c2 * 32 + ko);
      acc[nb] = __builtin_amdgcn_mfma_f32_16x16x32_bf16(a, b, acc[nb], 0, 0, 0);
    }
  }
  bf16x4_t p4[4];
#pragma unroll
  for (int r = 0; r < 4; ++r)
    p4[r] = *(const bf16x4_t*)(msg + (size_t)((gw << 4) + rowb + r) * 64 + colb * 4);
#pragma unroll
  for (int r = 0; r < 4; ++r) {
    int a_idx = (gw << 4) + rowb + r;
#pragma unroll
    for (int nb = 0; nb < 4; ++nb) {
      int col = nb * 16 + colb;
      float v = fmaxf(acc[nb][r] + bf2f((unsigned short)p4[r][nb]) + bias[col], 0.f);
      msg[(size_t)a_idx * 64 + col] = f2bf(v);
    }
  }
}

// =====================================================================
// nmp finish (gathers T3/T4 of P directly — pn round trip deleted):
//   msg = relu(P_T3[s] + P_T4[d] + affE2(e2)@Wnmp_e + b)
// =====================================================================
__global__ __launch_bounds__(256) void k_fin_nmp(
    const unsigned short* __restrict__ P,
    const unsigned short* __restrict__ e, const int* __restrict__ ei,
    const int* __restrict__ ebatch,
    const unsigned short* __restrict__ Wt,    // wt_nmp [128][320]
    const float* __restrict__ bias,
    const float* __restrict__ afEA, const float* __restrict__ afEB,
    unsigned short* __restrict__ msg, int nE)
{
  __shared__ float lEA[1024], lEB[1024];
  for (int i = threadIdx.x; i < 1024; i += 256) { lEA[i] = afEA[i]; lEB[i] = afEB[i]; }
  __syncthreads();
  int gw = (int)((blockIdx.x * 256u + threadIdx.x) >> 6);
  int ntile = nE >> 4;
  if (gw >= ntile) return;
  int lane = threadIdx.x & 63;
  int colb = lane & 15;
  int ko = (lane >> 4) << 3;
  int rowb = (lane >> 4) << 2;
  // issue gathers first (8 independent 16B loads)
  int sI[4], dI[4];
#pragma unroll
  for (int r = 0; r < 4; ++r) {
    int e_r = (gw << 4) + rowb + r;
    sI[r] = ei[e_r]; dI[r] = ei[nE + e_r];
  }
  bf16x8_t g3[4], g4[4];
#pragma unroll
  for (int r = 0; r < 4; ++r) {
    g3[r] = *(const bf16x8_t*)(P + (size_t)sI[r] * 384 + 128 + colb * 8);
    g4[r] = *(const bf16x8_t*)(P + (size_t)dI[r] * 384 + 256 + colb * 8);
  }
  int row = (gw << 4) + colb;
  int ge = ebatch[row];
  f32x4_t acc[8] = {};
#pragma unroll
  for (int c2 = 0; c2 < 2; ++c2) {
    int fb = c2 * 32 + ko;
    bf16x8_t t = *(const bf16x8_t*)(e + (size_t)row * 64 + fb);
    bf16x8_t a;
#pragma unroll
    for (int k = 0; k < 8; ++k)
      a[k] = (short)f2bf(bf2f((unsigned short)t[k]) * lEA[ge*64 + fb + k] + lEB[ge*64 + fb + k]);
#pragma unroll
    for (int nb = 0; nb < 8; ++nb) {
      bf16x8_t b = *(const bf16x8_t*)(Wt + (size_t)(nb * 16 + colb) * 320 + (8 + c2) * 32 + ko);
      acc[nb] = __builtin_amdgcn_mfma_f32_16x16x32_bf16(a, b, acc[nb], 0, 0, 0);
    }
  }
  // acc layout: row = rowb+r (C-frag), col = nb*16+colb; gathered partials are
  // per-row (r) in swizzled order [colb*8+nb] — matches g3[r][nb].
#pragma unroll
  for (int r = 0; r < 4; ++r) {
    int e_ = (gw << 4) + rowb + r;
#pragma unroll
    for (int nb = 0; nb < 8; ++nb) {
      int col = nb * 16 + colb;
      float v = fmaxf(acc[nb][r] + bf2f((unsigned short)g3[r][nb]) + bf2f((unsigned short)g4[r][nb])
                      + bias[col], 0.f);
      msg[(size_t)e_ * 128 + col] = f2bf(v);
    }
  }
}

// =====================================================================
// CSR gather-reduce over edges: e2(bf16) = affE1(e1) + sum(msg rows); fused stats.
// =====================================================================
__global__ __launch_bounds__(256) void k_red_e(
    const unsigned short* __restrict__ msg, const unsigned short* e_in, unsigned short* e_out,
    const int* __restrict__ ptr, const int* __restrict__ perm,
    const int* __restrict__ ebatch,
    const float* __restrict__ afA, const float* __restrict__ afB,
    float* __restrict__ gs1, float* __restrict__ gs2, int nE)
{
  __shared__ float lA[1024], lB[1024], ls1[NG], ls2[NG];
  for (int i = threadIdx.x; i < 1024; i += 256) { lA[i] = afA[i]; lB[i] = afB[i]; }
  if (threadIdx.x < NG) { ls1[threadIdx.x] = 0.f; ls2[threadIdx.x] = 0.f; }
  __syncthreads();
  int lane = threadIdx.x & 63;
  int wv = (int)((blockIdx.x * 256u + threadIdx.x) >> 6);
  int nw = (int)((gridDim.x * 256u) >> 6);
  for (int eidx = wv; eidx < nE; eidx += nw) {
    int p0 = ptr[eidx], p1 = ptr[eidx + 1];
    float sum = 0.f;
    for (int j = p0; j < p1; ++j) {
      int aidx = perm[j];
      sum += bf2f(msg[(size_t)aidx * 64 + lane]);
    }
    int g = ebatch[eidx];
    size_t off = (size_t)eidx * 64 + lane;
    float v = bf2f(e_in[off]) * lA[g*64 + lane] + lB[g*64 + lane] + sum;
    e_out[off] = f2bf(v);
    float s = v, ss = v * v;
#pragma unroll
    for (int m = 1; m < 64; m <<= 1) { s += __shfl_xor(s, m); ss += __shfl_xor(ss, m); }
    if (lane == 0) { atomicAdd(&ls1[g], s); atomicAdd(&ls2[g], ss); }
  }
  __syncthreads();
  if (threadIdx.x < NG) {
    atomicAdd(&gs1[threadIdx.x], ls1[threadIdx.x]);
    atomicAdd(&gs2[threadIdx.x], ls2[threadIdx.x]);
  }
}

// =====================================================================
// CSR gather-reduce over nodes: h = x + sum(msg rows); fused stats. (x fp32)
// =====================================================================
__global__ __launch_bounds__(256) void k_red_n(
    const unsigned short* __restrict__ msg, const float* x_in, float* out,
    const int* __restrict__ ptr, const int* __restrict__ perm,
    const int* __restrict__ nbatch,
    float* __restrict__ gs1, float* __restrict__ gs2, int nN)
{
  __shared__ float ls1[NG], ls2[NG];
  if (threadIdx.x < NG) { ls1[threadIdx.x] = 0.f; ls2[threadIdx.x] = 0.f; }
  __syncthreads();
  int lane = threadIdx.x & 63;
  int wv = (int)((blockIdx.x * 256u + threadIdx.x) >> 6);
  int nw = (int)((gridDim.x * 256u) >> 6);
  for (int n = wv; n < nN; n += nw) {
    int p0 = ptr[n], p1 = ptr[n + 1];
    float s0 = 0.f, s1v = 0.f;
    for (int j = p0; j < p1; ++j) {
      int e = perm[j];
      unsigned u = *(const unsigned*)(msg + (size_t)e * 128 + lane * 2);
      s0 += bf2f((unsigned short)(u & 0xffffu));
      s1v += bf2f((unsigned short)(u >> 16));
    }
    size_t off = (size_t)n * 128 + lane * 2;
    float h0 = x_in[off] + s0, h1 = x_in[off + 1] + s1v;
    out[off] = h0; out[off + 1] = h1;
    float s = h0 + h1, ss = h0 * h0 + h1 * h1;
#pragma unroll
    for (int m = 1; m < 64; m <<= 1) { s += __shfl_xor(s, m); ss += __shfl_xor(ss, m); }
    if (lane == 0) { int g = nbatch[n]; atomicAdd(&ls1[g], s); atomicAdd(&ls2[g], ss); }
  }
  __syncthreads();
  if (threadIdx.x < NG) {
    atomicAdd(&gs1[threadIdx.x], ls1[threadIdx.x]);
    atomicAdd(&gs2[threadIdx.x], ls2[threadIdx.x]);
  }
}

// ---- affine table construction ----
__global__ __launch_bounds__(256) void k_mkaff(
    const float* __restrict__ s1, const float* __restrict__ s2,
    const float* __restrict__ cnt, int F,
    const float* __restrict__ w, const float* __restrict__ b,
    float* __restrict__ A, float* __restrict__ B)
{
  int idx = blockIdx.x * 256 + threadIdx.x;
  if (idx >= NG * F) return;
  int g = idx / F, f = idx - g * F;
  float norm = fmaxf(cnt[g], 1.f) * (float)F;
  float m = s1[g] / norm;
  float var = s2[g] / norm - m * m;
  float inv = rsqrtf(var + EPS);
  float a = inv * w[f];
  A[idx] = a;
  B[idx] = b[f] - m * a;
}

__global__ __launch_bounds__(256) void k_idaff(float* __restrict__ A, float* __restrict__ B, int n)
{
  int idx = blockIdx.x * 256 + threadIdx.x;
  if (idx < n) { A[idx] = 1.f; B[idx] = 0.f; }
}

// ---- apply norm to x (in-place, fp32) ----
__global__ __launch_bounds__(256) void k_apply(
    float* h, const int* __restrict__ batch,
    const float* __restrict__ A, const float* __restrict__ B, int nN)
{
  int total = nN * 16;
  int stride = gridDim.x * 256;
  for (int idx = blockIdx.x * 256 + threadIdx.x; idx < total; idx += stride) {
    int row = idx >> 4, q = (idx & 15) * 8;
    int g = batch[row];
    float* hp = h + (size_t)row * 128 + q;
    float4 f0 = *(const float4*)hp;
    float4 f1 = *(const float4*)(hp + 4);
    float vv[8] = {f0.x,f0.y,f0.z,f0.w,f1.x,f1.y,f1.z,f1.w};
#pragma unroll
    for (int k = 0; k < 8; ++k) vv[k] = vv[k] * A[(g << 7) + q + k] + B[(g << 7) + q + k];
    float4 g0 = {vv[0],vv[1],vv[2],vv[3]}, g1 = {vv[4],vv[5],vv[6],vv[7]};
    *(float4*)hp = g0;
    *(float4*)(hp + 4) = g1;
  }
}

__global__ __launch_bounds__(256) void k_count(
    const int* __restrict__ batch, int n, float* __restrict__ cnt)
{
  __shared__ float lc[NG];
  if (threadIdx.x < NG) lc[threadIdx.x] = 0.f;
  __syncthreads();
  for (int i = blockIdx.x * 256 + threadIdx.x; i < n; i += gridDim.x * 256)
    atomicAdd(&lc[batch[i]], 1.f);
  __syncthreads();
  if (threadIdx.x < NG) atomicAdd(&cnt[threadIdx.x], lc[threadIdx.x]);
}

// ---- CSR build ----
__global__ __launch_bounds__(256) void k_hist(
    const int* __restrict__ dst, int n, int* __restrict__ cnt)
{
  for (int i = blockIdx.x * 256 + threadIdx.x; i < n; i += gridDim.x * 256)
    atomicAdd(&cnt[dst[i]], 1);
}

__global__ __launch_bounds__(256) void k_scan1(
    const int* __restrict__ in, int* __restrict__ out, int* __restrict__ bsum, int n)
{
  __shared__ int wtot[4];
  int tid = threadIdx.x, lane = tid & 63, wid = tid >> 6;
  int base = blockIdx.x * 1024 + tid * 4;
  int v[4];
#pragma unroll
  for (int k = 0; k < 4; ++k) v[k] = (base + k < n) ? in[base + k] : 0;
  int tsum = v[0] + v[1] + v[2] + v[3];
  int incl = tsum;
#pragma unroll
  for (int off = 1; off < 64; off <<= 1) {
    int up = __shfl_up(incl, off);
    if (lane >= off) incl += up;
  }
  if (lane == 63) wtot[wid] = incl;
  __syncthreads();
  if (tid == 0) {
    int r = 0;
#pragma unroll
    for (int w2 = 0; w2 < 4; ++w2) { int t = wtot[w2]; wtot[w2] = r; r += t; }
    bsum[blockIdx.x] = r;
  }
  __syncthreads();
  int excl = wtot[wid] + incl - tsum;
#pragma unroll
  for (int k = 0; k < 4; ++k) {
    if (base + k < n) out[base + k] = excl;
    excl += v[k];
  }
}

__global__ __launch_bounds__(256) void k_scan2(int* __restrict__ bsum, int nb, int* __restrict__ total_out)
{
  __shared__ int wtot[4];
  int tid = threadIdx.x, lane = tid & 63, wid = tid >> 6;
  int base = tid * 4;
  int v[4];
#pragma unroll
  for (int k = 0; k < 4; ++k) v[k] = (base + k < nb) ? bsum[base + k] : 0;
  int tsum = v[0] + v[1] + v[2] + v[3];
  int incl = tsum;
#pragma unroll
  for (int off = 1; off < 64; off <<= 1) {
    int up = __shfl_up(incl, off);
    if (lane >= off) incl += up;
  }
  if (lane == 63) wtot[wid] = incl;
  __syncthreads();
  if (tid == 0) {
    int r = 0;
#pragma unroll
    for (int w2 = 0; w2 < 4; ++w2) { int t = wtot[w2]; wtot[w2] = r; r += t; }
    *total_out = r;
  }
  __syncthreads();
  int excl = wtot[wid] + incl - tsum;
#pragma unroll
  for (int k = 0; k < 4; ++k) {
    if (base + k < nb) bsum[base + k] = excl;
    excl += v[k];
  }
}

__global__ __launch_bounds__(256) void k_scan3(
    int* __restrict__ ptr, int* __restrict__ cur, const int* __restrict__ bsum, int n)
{
  for (int i = blockIdx.x * 256 + threadIdx.x; i < n; i += gridDim.x * 256) {
    int v = ptr[i] + bsum[i >> 10];
    ptr[i] = v; cur[i] = v;
  }
}

__global__ __launch_bounds__(256) void k_scatter(
    const int* __restrict__ dst, int* __restrict__ cur, int* __restrict__ perm, int n)
{
  for (int i = blockIdx.x * 256 + threadIdx.x; i < n; i += gridDim.x * 256) {
    int d = dst[i];
    int p = atomicAdd(&cur[d], 1);
    perm[p] = i;
  }
}

// ---- weight prep ----
__global__ __launch_bounds__(256) void k_wt(
    const float* __restrict__ W, unsigned short* __restrict__ Wt, int K, int NO)
{
  int idx = blockIdx.x * 256 + threadIdx.x;
  if (idx >= K * NO) return;
  int k = idx / NO, j = idx - k * NO;
  Wt[(size_t)j * K + k] = f2bf(W[idx]);
}

extern "C" void kernel_launch(void* const* d_in, const int* in_sizes, int n_in,
                              void* d_out, int out_size, void* d_ws, size_t ws_size,
                              hipStream_t stream)
{
  const float* x0    = (const float*)d_in[0];
  const float* e0    = (const float*)d_in[1];
  const float* a0    = (const float*)d_in[2];
  const float* W_ne  = (const float*)d_in[3];
  const float* b_ne  = (const float*)d_in[4];
  const float* g_e   = (const float*)d_in[5];
  const float* be_e  = (const float*)d_in[6];
  const float* W_ea  = (const float*)d_in[7];
  const float* b_ea  = (const float*)d_in[8];
  const float* g_a   = (const float*)d_in[9];
  const float* be_a  = (const float*)d_in[10];
  const float* W_emp = (const float*)d_in[11];
  const float* b_emp = (const float*)d_in[12];
  const float* g_emp = (const float*)d_in[13];
  const float* be_emp= (const float*)d_in[14];
  const float* W_nmp = (const float*)d_in[15];
  const float* b_nmp = (const float*)d_in[16];
  const float* g_nmp = (const float*)d_in[17];
  const float* be_nmp= (const float*)d_in[18];
  const int* node_batch  = (const int*)d_in[19];
  const int* edge_index  = (const int*)d_in[20];
  const int* edge_batch  = (const int*)d_in[21];
  const int* tb_index    = (const int*)d_in[22];
  const int* angle_batch = (const int*)d_in[23];

  const int N = in_sizes[0] / 128;
  const int E = in_sizes[1] / 64;
  const int A = in_sizes[2] / 64;

  // ---- workspace layout (bytes, 256-aligned) ----
  char* wsp = (char*)d_ws;
  auto alloc = [&](size_t bytes) { char* p = wsp; wsp += (bytes + 255) & ~(size_t)255; return p; };
  unsigned short* eAB  = (unsigned short*)alloc((size_t)E * 64 * 2);   // e intermediate (bf16)
  unsigned short* aAB  = (unsigned short*)alloc((size_t)A * 64 * 2);   // a intermediate (bf16)
  unsigned short* msg  = (unsigned short*)alloc((size_t)A * 64 * 2);   // pe / msg_e / msg_n
  unsigned short* P    = (unsigned short*)alloc((size_t)N * 384 * 2);  // x partials (standalone — lives to stage 4)
  unsigned short* PAE  = (unsigned short*)alloc((size_t)E * 256 * 2);  // angle+emp partials (swizzled)
  int* ptr_n  = (int*)alloc((size_t)(N + 1) * 4);
  int* cur_n  = (int*)alloc((size_t)N * 4);
  int* perm_n = (int*)alloc((size_t)E * 4);
  int* ptr_e  = (int*)alloc((size_t)(E + 1) * 4);
  int* cur_e  = (int*)alloc((size_t)E * 4);
  int* perm_e = (int*)alloc((size_t)A * 4);
  int* bsum   = (int*)alloc(4096 * 4);
  float* stats = (float*)alloc(5 * NG * 4);   // contiguous: s1,s2,cnt_n,cnt_e,cnt_a
  float* s1    = stats;
  float* s2    = stats + NG;
  float* cnt_n = stats + 2 * NG;
  float* cnt_e = stats + 3 * NG;
  float* cnt_a = stats + 4 * NG;
  float* afE_idA = (float*)alloc(1024 * 4); float* afE_idB = (float*)alloc(1024 * 4);
  float* afA_idA = (float*)alloc(1024 * 4); float* afA_idB = (float*)alloc(1024 * 4);
  float* afE1A   = (float*)alloc(1024 * 4); float* afE1B   = (float*)alloc(1024 * 4);
  float* afE2A   = (float*)alloc(1024 * 4); float* afE2B   = (float*)alloc(1024 * 4);
  float* afA1A   = (float*)alloc(1024 * 4); float* afA1B   = (float*)alloc(1024 * 4);
  float* afXA    = (float*)alloc(2048 * 4); float* afXB    = (float*)alloc(2048 * 4);
  unsigned short* wt_ne  = (unsigned short*)alloc((size_t)2 * 320 * 64 * 2);
  unsigned short* wt_ea  = (unsigned short*)alloc((size_t)2 * 192 * 64 * 2);
  unsigned short* wt_emp = (unsigned short*)alloc((size_t)2 * 192 * 64 * 2);
  unsigned short* wt_nmp = (unsigned short*)alloc((size_t)2 * 320 * 128 * 2);

  float* x_out = (float*)d_out;

  // ---- one-time prep ----
  for (int i = 0; i < 2; ++i) {
    k_wt<<<(320*64 + 255)/256, 256, 0, stream>>>(W_ne  + (size_t)i*320*64,  wt_ne  + (size_t)i*320*64,  320, 64);
    k_wt<<<(192*64 + 255)/256, 256, 0, stream>>>(W_ea  + (size_t)i*192*64,  wt_ea  + (size_t)i*192*64,  192, 64);
    k_wt<<<(192*64 + 255)/256, 256, 0, stream>>>(W_emp + (size_t)i*192*64,  wt_emp + (size_t)i*192*64,  192, 64);
    k_wt<<<(320*128 + 255)/256, 256, 0, stream>>>(W_nmp + (size_t)i*320*128, wt_nmp + (size_t)i*320*128, 320, 128);
  }
  hipMemsetAsync(stats, 0, 5 * NG * 4, stream);
  k_count<<<512, 256, 0, stream>>>(node_batch, N, cnt_n);
  k_count<<<512, 256, 0, stream>>>(edge_batch, E, cnt_e);
  k_count<<<512, 256, 0, stream>>>(angle_batch, A, cnt_a);
  k_idaff<<<4, 256, 0, stream>>>(afE_idA, afE_idB, 1024);
  k_idaff<<<4, 256, 0, stream>>>(afA_idA, afA_idB, 1024);

  // CSR over nodes (dst of edge_index) and edges (dst of threebody)
  hipMemsetAsync(cur_n, 0, (size_t)N * 4, stream);
  hipMemsetAsync(cur_e, 0, (size_t)E * 4, stream);
  k_hist<<<1024, 256, 0, stream>>>(edge_index + E, E, cur_n);
  k_hist<<<1024, 256, 0, stream>>>(tb_index + A, A, cur_e);
  int nbN = (N + 1023) / 1024, nbE = (E + 1023) / 1024;
  k_scan1<<<nbN, 256, 0, stream>>>(cur_n, ptr_n, bsum, N);
  k_scan2<<<1, 256, 0, stream>>>(bsum, nbN, ptr_n + N);
  k_scan3<<<1024, 256, 0, stream>>>(ptr_n, cur_n, bsum, N);
  k_scatter<<<1024, 256, 0, stream>>>(edge_index + E, cur_n, perm_n, E);
  k_scan1<<<nbE, 256, 0, stream>>>(cur_e, ptr_e, bsum, E);
  k_scan2<<<1, 256, 0, stream>>>(bsum, nbE, ptr_e + E);
  k_scan3<<<1024, 256, 0, stream>>>(ptr_e, cur_e, bsum, E);
  k_scatter<<<1024, 256, 0, stream>>>(tb_index + A, cur_e, perm_e, A);

  const float* x_cur = x0;
  int blkE = (E / 16 + 3) / 4;
  int blkA = (A / 16 + 3) / 4;
  int blkN = (N / 16 + 3) / 4;

  for (int i = 0; i < 2; ++i) {
    const float* fEinA = (i == 0) ? afE_idA : afE2A;
    const float* fEinB = (i == 0) ? afE_idB : afE2B;
    const float* fAinA = (i == 0) ? afA_idA : afA1A;
    const float* fAinB = (i == 0) ? afA_idB : afA1B;

    // 0. dense x-partials (P persists through stage 4)
    k_dense_x<<<blkN, 256, 0, stream>>>(x_cur, wt_ne + (size_t)i*320*64,
                                        wt_nmp + (size_t)i*320*128, P, N);

    // 1. edge stage (T1/T2 gathers only) -> affE1
    hipMemsetAsync(s1, 0, 2 * NG * 4, stream);
    if (i == 0)
      k_edge<true><<<blkE, 256, 0, stream>>>(P, (const void*)e0, eAB, edge_index, edge_batch,
                                             wt_ne + (size_t)i*320*64, b_ne + i*64,
                                             fEinA, fEinB, s1, s2, E);
    else
      k_edge<false><<<blkE, 256, 0, stream>>>(P, (const void*)eAB, eAB, edge_index, edge_batch,
                                              wt_ne + (size_t)i*320*64, b_ne + i*64,
                                              fEinA, fEinB, s1, s2, E);
    k_mkaff<<<4, 256, 0, stream>>>(s1, s2, cnt_e, 64, g_e + i*64, be_e + i*64, afE1A, afE1B);

    // 1.5 dense angle+emp partials over edges -> PAE
    k_prep_e<<<blkE, 256, 0, stream>>>(eAB, edge_batch, afE1A, afE1B,
                                       wt_ea + (size_t)i*192*64, wt_emp + (size_t)i*192*64,
                                       PAE, E);

    // 2. angle stage (adds-only gathers) -> affA1, pe -> msg
    hipMemsetAsync(s1, 0, 2 * NG * 4, stream);
    if (i == 0)
      k_angle<true><<<blkA, 256, 0, stream>>>(PAE, (const void*)a0, aAB, tb_index, angle_batch,
                                              wt_ea + (size_t)i*192*64, b_ea + i*64,
                                              fAinA, fAinB, s1, s2, msg, A);
    else
      k_angle<false><<<blkA, 256, 0, stream>>>(PAE, (const void*)aAB, aAB, tb_index, angle_batch,
                                               wt_ea + (size_t)i*192*64, b_ea + i*64,
                                               fAinA, fAinB, s1, s2, msg, A);
    k_mkaff<<<4, 256, 0, stream>>>(s1, s2, cnt_a, 64, g_a + i*64, be_a + i*64, afA1A, afA1B);

    // 3. emp finish (stream) -> msg; CSR reduce -> affE2
    k_fin_emp<<<blkA, 256, 0, stream>>>(aAB, angle_batch, wt_emp + (size_t)i*192*64,
                                        b_emp + i*64, afA1A, afA1B, msg, A);
    hipMemsetAsync(s1, 0, 2 * NG * 4, stream);
    k_red_e<<<2048, 256, 0, stream>>>(msg, eAB, eAB, ptr_e, perm_e, edge_batch,
                                      afE1A, afE1B, s1, s2, E);
    k_mkaff<<<4, 256, 0, stream>>>(s1, s2, cnt_e, 64, g_emp + i*64, be_emp + i*64, afE2A, afE2B);

    // 4. nmp finish (gathers P T3/T4 directly) -> msg; CSR reduce; apply
    k_fin_nmp<<<blkE, 256, 0, stream>>>(P, eAB, edge_index, edge_batch,
                                        wt_nmp + (size_t)i*320*128, b_nmp + i*128,
                                        afE2A, afE2B, msg, E);
    hipMemsetAsync(s1, 0, 2 * NG * 4, stream);
    k_red_n<<<2048, 256, 0, stream>>>(msg, x_cur, x_out, ptr_n, perm_n, node_batch,
                                      s1, s2, N);
    k_mkaff<<<8, 256, 0, stream>>>(s1, s2, cnt_n, 128, g_nmp + i*128, be_nmp + i*128, afXA, afXB);
    k_apply<<<2048, 256, 0, stream>>>(x_out, node_batch, afXA, afXB, N);

    x_cur = x_out;
  }
}

// Round 11
// 1615.052 us; speedup vs baseline: 1.4411x; 1.0065x over previous
//
#include <hip/hip_runtime.h>

typedef __attribute__((ext_vector_type(8))) short bf16x8_t;
typedef __attribute__((ext_vector_type(4))) short bf16x4_t;
typedef __attribute__((ext_vector_type(4))) float f32x4_t;

constexpr int NG = 16;
constexpr float EPS = 1e-5f;

__device__ inline unsigned short f2bf(float f) {
  unsigned u = __builtin_bit_cast(unsigned, f);
  u += 0x7FFFu + ((u >> 16) & 1u);
  return (unsigned short)(u >> 16);
}
__device__ inline float bf2f(unsigned short u) {
  unsigned x = ((unsigned)u) << 16;
  return __builtin_bit_cast(float, x);
}

// load 8 contiguous elements as f32 from fp32 or bf16 storage
template<bool F32>
__device__ inline void ldrow8(const void* base, size_t off, float v[8]) {
  if constexpr (F32) {
    const float* p = (const float*)base + off;
    float4 f0 = *(const float4*)p, f1 = *(const float4*)(p + 4);
    v[0]=f0.x; v[1]=f0.y; v[2]=f0.z; v[3]=f0.w;
    v[4]=f1.x; v[5]=f1.y; v[6]=f1.z; v[7]=f1.w;
  } else {
    bf16x8_t t = *(const bf16x8_t*)((const unsigned short*)base + off);
#pragma unroll
    for (int k = 0; k < 8; ++k) v[k] = bf2f((unsigned short)t[k]);
  }
}

// =====================================================================
// Dense partial GEMM over nodes (coalesced):
//   P[n] = x[n] @ [Wne_s | Wne_d | Wnmp_s | Wnmp_d]  (N x 384 bf16, swizzled)
// =====================================================================
__global__ __launch_bounds__(256) void k_dense_x(
    const float* __restrict__ x,
    const unsigned short* __restrict__ WtNE,   // [64][320]
    const unsigned short* __restrict__ WtNM,   // [128][320]
    unsigned short* __restrict__ P, int nN)
{
  int gw = (int)((blockIdx.x * 256u + threadIdx.x) >> 6);
  int ntile = nN >> 4;
  if (gw >= ntile) return;
  int lane = threadIdx.x & 63;
  int colb = lane & 15;
  int ko = (lane >> 4) << 3;
  int rowb = (lane >> 4) << 2;
  int row = (gw << 4) + colb;
  const float* xr = x + (size_t)row * 128;
  f32x4_t a1[4] = {}, a2[4] = {}, a3[8] = {}, a4[8] = {};
#pragma unroll
  for (int c = 0; c < 4; ++c) {
    float4 f0 = *(const float4*)(xr + c * 32 + ko);
    float4 f1 = *(const float4*)(xr + c * 32 + ko + 4);
    float vv[8] = {f0.x,f0.y,f0.z,f0.w,f1.x,f1.y,f1.z,f1.w};
    bf16x8_t a;
#pragma unroll
    for (int k = 0; k < 8; ++k) a[k] = (short)f2bf(vv[k]);
#pragma unroll
    for (int nb = 0; nb < 4; ++nb) {
      bf16x8_t b1 = *(const bf16x8_t*)(WtNE + (size_t)(nb * 16 + colb) * 320 + c * 32 + ko);
      a1[nb] = __builtin_amdgcn_mfma_f32_16x16x32_bf16(a, b1, a1[nb], 0, 0, 0);
      bf16x8_t b2 = *(const bf16x8_t*)(WtNE + (size_t)(nb * 16 + colb) * 320 + (c + 4) * 32 + ko);
      a2[nb] = __builtin_amdgcn_mfma_f32_16x16x32_bf16(a, b2, a2[nb], 0, 0, 0);
    }
#pragma unroll
    for (int nb = 0; nb < 8; ++nb) {
      bf16x8_t b3 = *(const bf16x8_t*)(WtNM + (size_t)(nb * 16 + colb) * 320 + c * 32 + ko);
      a3[nb] = __builtin_amdgcn_mfma_f32_16x16x32_bf16(a, b3, a3[nb], 0, 0, 0);
      bf16x8_t b4 = *(const bf16x8_t*)(WtNM + (size_t)(nb * 16 + colb) * 320 + (c + 4) * 32 + ko);
      a4[nb] = __builtin_amdgcn_mfma_f32_16x16x32_bf16(a, b4, a4[nb], 0, 0, 0);
    }
  }
#pragma unroll
  for (int r = 0; r < 4; ++r) {
    size_t ro = (size_t)((gw << 4) + rowb + r) * 384;
    bf16x4_t t1, t2;
#pragma unroll
    for (int nb = 0; nb < 4; ++nb) { t1[nb] = (short)f2bf(a1[nb][r]); t2[nb] = (short)f2bf(a2[nb][r]); }
    *(bf16x4_t*)(P + ro + colb * 4) = t1;
    *(bf16x4_t*)(P + ro + 64 + colb * 4) = t2;
    bf16x8_t t3, t4;
#pragma unroll
    for (int nb = 0; nb < 8; ++nb) { t3[nb] = (short)f2bf(a3[nb][r]); t4[nb] = (short)f2bf(a4[nb][r]); }
    *(bf16x8_t*)(P + ro + 128 + colb * 8) = t3;
    *(bf16x8_t*)(P + ro + 256 + colb * 8) = t4;
  }
}

// =====================================================================
// Dense angle+emp partials over edges (coalesced, one eAB read):
//   ê = affE1(e);  PA1=ê@Wea_s, PA2=ê@Wea_d, PE3=ê@Wemp_s, PE4=ê@Wemp_d
// PAE row (256): s-half at colb*8: [PA1|PE3]; d-half at 128+colb*8: [PA2|PE4].
// =====================================================================
__global__ __launch_bounds__(256) void k_prep_e(
    const unsigned short* __restrict__ eA, const int* __restrict__ ebatch,
    const float* __restrict__ afA, const float* __restrict__ afB,
    const unsigned short* __restrict__ WtA,    // wt_ea  [64][192]
    const unsigned short* __restrict__ WtP,    // wt_emp [64][192]
    unsigned short* __restrict__ PAE, int nE)
{
  __shared__ float lA[1024], lB[1024];
  for (int i = threadIdx.x; i < 1024; i += 256) { lA[i] = afA[i]; lB[i] = afB[i]; }
  __syncthreads();
  int gw = (int)((blockIdx.x * 256u + threadIdx.x) >> 6);
  int ntile = nE >> 4;
  if (gw >= ntile) return;
  int lane = threadIdx.x & 63;
  int colb = lane & 15;
  int ko = (lane >> 4) << 3;
  int rowb = (lane >> 4) << 2;
  int row = (gw << 4) + colb;
  int ge = ebatch[row];
  f32x4_t pa1[4] = {}, pa2[4] = {}, pe3[4] = {}, pe4[4] = {};
#pragma unroll
  for (int c2 = 0; c2 < 2; ++c2) {
    int fb = c2 * 32 + ko;
    bf16x8_t t = *(const bf16x8_t*)(eA + (size_t)row * 64 + fb);
    bf16x8_t an;
#pragma unroll
    for (int k = 0; k < 8; ++k)
      an[k] = (short)f2bf(bf2f((unsigned short)t[k]) * lA[ge*64 + fb + k] + lB[ge*64 + fb + k]);
#pragma unroll
    for (int nb = 0; nb < 4; ++nb) {
      size_t wb = (size_t)(nb * 16 + colb) * 192;
      bf16x8_t b;
      b = *(const bf16x8_t*)(WtA + wb + c2 * 32 + ko);
      pa1[nb] = __builtin_amdgcn_mfma_f32_16x16x32_bf16(an, b, pa1[nb], 0, 0, 0);
      b = *(const bf16x8_t*)(WtA + wb + 64 + c2 * 32 + ko);
      pa2[nb] = __builtin_amdgcn_mfma_f32_16x16x32_bf16(an, b, pa2[nb], 0, 0, 0);
      b = *(const bf16x8_t*)(WtP + wb + c2 * 32 + ko);
      pe3[nb] = __builtin_amdgcn_mfma_f32_16x16x32_bf16(an, b, pe3[nb], 0, 0, 0);
      b = *(const bf16x8_t*)(WtP + wb + 64 + c2 * 32 + ko);
      pe4[nb] = __builtin_amdgcn_mfma_f32_16x16x32_bf16(an, b, pe4[nb], 0, 0, 0);
    }
  }
#pragma unroll
  for (int r = 0; r < 4; ++r) {
    size_t ro = (size_t)((gw << 4) + rowb + r) * 256;
    bf16x8_t sH, dH;
#pragma unroll
    for (int nb = 0; nb < 4; ++nb) {
      sH[nb] = (short)f2bf(pa1[nb][r]); sH[4 + nb] = (short)f2bf(pe3[nb][r]);
      dH[nb] = (short)f2bf(pa2[nb][r]); dH[4 + nb] = (short)f2bf(pe4[nb][r]);
    }
    *(bf16x8_t*)(PAE + ro + colb * 8) = sH;
    *(bf16x8_t*)(PAE + ro + 128 + colb * 8) = dH;
  }
}

// =====================================================================
// EDGE stage: e_out(bf16) = ê + P_T1[s]+P_T2[d] + ê@Wne_e + b  (+stats)
// ê = affEin(e_in). Normalized tile staged in per-wave LDS — the epilogue
// reads its C-layout residual from LDS instead of 16 scalar global loads.
// =====================================================================
template<bool EF32>
__global__ __launch_bounds__(256) void k_edge(
    const unsigned short* __restrict__ P, const void* e_in, unsigned short* e_out,
    const int* __restrict__ ei, const int* __restrict__ ebatch,
    const unsigned short* __restrict__ Wt,    // wt_ne [64][320]
    const float* __restrict__ bias,
    const float* __restrict__ afA, const float* __restrict__ afB,
    float* __restrict__ gs1, float* __restrict__ gs2, int nE)
{
  __shared__ float lA[1024], lB[1024];
  __shared__ float ls1[NG], ls2[NG];
  __shared__ __align__(16) unsigned short tl[4][16][72];  // per-wave normalized tile
  for (int i = threadIdx.x; i < 1024; i += 256) { lA[i] = afA[i]; lB[i] = afB[i]; }
  if (threadIdx.x < NG) { ls1[threadIdx.x] = 0.f; ls2[threadIdx.x] = 0.f; }
  __syncthreads();
  int gw = (int)((blockIdx.x * 256u + threadIdx.x) >> 6);
  int ntile = nE >> 4;
  bool act = gw < ntile;
  int lane = threadIdx.x & 63;
  int wid = threadIdx.x >> 6;
  int colb = lane & 15;
  int ko = (lane >> 4) << 3;
  int rowb = (lane >> 4) << 2;
  float sr[4] = {0.f,0.f,0.f,0.f}, ssr[4] = {0.f,0.f,0.f,0.f};
  if (act) {
    int sI[4], dI[4];
#pragma unroll
    for (int r = 0; r < 4; ++r) {
      int e_r = (gw << 4) + rowb + r;
      sI[r] = ei[e_r]; dI[r] = ei[nE + e_r];
    }
    bf16x4_t g1[4], g2[4];
#pragma unroll
    for (int r = 0; r < 4; ++r) {
      g1[r] = *(const bf16x4_t*)(P + (size_t)sI[r] * 384 + colb * 4);
      g2[r] = *(const bf16x4_t*)(P + (size_t)dI[r] * 384 + 64 + colb * 4);
    }
    int row = (gw << 4) + colb;
    int ge = ebatch[row];
    f32x4_t acc[4] = {};
#pragma unroll
    for (int c2 = 0; c2 < 2; ++c2) {
      int fb = c2 * 32 + ko;
      float vv[8];
      ldrow8<EF32>(e_in, (size_t)row * 64 + fb, vv);
      bf16x8_t a;
#pragma unroll
      for (int k = 0; k < 8; ++k) a[k] = (short)f2bf(vv[k] * lA[ge*64 + fb + k] + lB[ge*64 + fb + k]);
      *(bf16x8_t*)&tl[wid][colb][fb] = a;   // stage normalized tile (wave-private)
#pragma unroll
      for (int nb = 0; nb < 4; ++nb) {
        bf16x8_t b = *(const bf16x8_t*)(Wt + (size_t)(nb * 16 + colb) * 320 + (8 + c2) * 32 + ko);
        acc[nb] = __builtin_amdgcn_mfma_f32_16x16x32_bf16(a, b, acc[nb], 0, 0, 0);
      }
    }
#pragma unroll
    for (int r = 0; r < 4; ++r) {
      int e_ = (gw << 4) + rowb + r;
#pragma unroll
      for (int nb = 0; nb < 4; ++nb) {
        int col = nb * 16 + colb;
        size_t off = (size_t)e_ * 64 + col;
        float nv = bf2f(tl[wid][rowb + r][col]);
        float vv = nv + bias[col]
                 + acc[nb][r] + bf2f((unsigned short)g1[r][nb]) + bf2f((unsigned short)g2[r][nb]);
        e_out[off] = f2bf(vv);
        sr[r] += vv; ssr[r] += vv * vv;
      }
    }
  }
#pragma unroll
  for (int m = 1; m <= 8; m <<= 1)
#pragma unroll
    for (int r = 0; r < 4; ++r) { sr[r] += __shfl_xor(sr[r], m); ssr[r] += __shfl_xor(ssr[r], m); }
  if (act && colb == 0) {
#pragma unroll
    for (int r = 0; r < 4; ++r) {
      int g = ebatch[(gw << 4) + rowb + r];
      atomicAdd(&ls1[g], sr[r]); atomicAdd(&ls2[g], ssr[r]);
    }
  }
  __syncthreads();
  if (threadIdx.x < NG) {
    atomicAdd(&gs1[threadIdx.x], ls1[threadIdx.x]);
    atomicAdd(&gs2[threadIdx.x], ls2[threadIdx.x]);
  }
}

// =====================================================================
// ANGLE stage: adds-only gathers from PAE; normalized tile staged in LDS.
//   a_out(bf16) = â + PA1[s]+PA2[d] + â@Wea_a + b (+stats), â = affAin(a_in)
//   pe = PE3[s] + PE4[d]  -> msg (swizzled)
// =====================================================================
template<bool AF32>
__global__ __launch_bounds__(256) void k_angle(
    const unsigned short* __restrict__ PAE,
    const void* a_in, unsigned short* a_out,
    const int* __restrict__ ti, const int* __restrict__ abatch,
    const unsigned short* __restrict__ Wt,    // wt_ea [64][192]
    const float* __restrict__ bias,
    const float* __restrict__ afAA, const float* __restrict__ afAB,
    float* __restrict__ gs1, float* __restrict__ gs2,
    unsigned short* __restrict__ pe, int nA)
{
  __shared__ float lAA[1024], lAB[1024];
  __shared__ float ls1[NG], ls2[NG];
  __shared__ __align__(16) unsigned short tl[4][16][72];
  for (int i = threadIdx.x; i < 1024; i += 256) { lAA[i] = afAA[i]; lAB[i] = afAB[i]; }
  if (threadIdx.x < NG) { ls1[threadIdx.x] = 0.f; ls2[threadIdx.x] = 0.f; }
  __syncthreads();
  int gw = (int)((blockIdx.x * 256u + threadIdx.x) >> 6);
  int ntile = nA >> 4;
  bool act = gw < ntile;
  int lane = threadIdx.x & 63;
  int wid = threadIdx.x >> 6;
  int colb = lane & 15;
  int ko = (lane >> 4) << 3;
  int rowb = (lane >> 4) << 2;
  float sr[4] = {0.f,0.f,0.f,0.f}, ssr[4] = {0.f,0.f,0.f,0.f};
  if (act) {
    int sI[4], dI[4];
#pragma unroll
    for (int r = 0; r < 4; ++r) {
      int a_r = (gw << 4) + rowb + r;
      sI[r] = ti[a_r]; dI[r] = ti[nA + a_r];
    }
    bf16x8_t gS[4], gD[4];
#pragma unroll
    for (int r = 0; r < 4; ++r) {
      gS[r] = *(const bf16x8_t*)(PAE + (size_t)sI[r] * 256 + colb * 8);
      gD[r] = *(const bf16x8_t*)(PAE + (size_t)dI[r] * 256 + 128 + colb * 8);
    }
    int row = (gw << 4) + colb;
    int ga = abatch[row];
    f32x4_t acc[4] = {};
#pragma unroll
    for (int c2 = 0; c2 < 2; ++c2) {
      int fb = c2 * 32 + ko;
      float vv[8];
      ldrow8<AF32>(a_in, (size_t)row * 64 + fb, vv);
      bf16x8_t a;
#pragma unroll
      for (int k = 0; k < 8; ++k) a[k] = (short)f2bf(vv[k] * lAA[ga*64 + fb + k] + lAB[ga*64 + fb + k]);
      *(bf16x8_t*)&tl[wid][colb][fb] = a;
#pragma unroll
      for (int nb = 0; nb < 4; ++nb) {
        bf16x8_t b = *(const bf16x8_t*)(Wt + (size_t)(nb * 16 + colb) * 192 + 128 + c2 * 32 + ko);
        acc[nb] = __builtin_amdgcn_mfma_f32_16x16x32_bf16(a, b, acc[nb], 0, 0, 0);
      }
    }
#pragma unroll
    for (int r = 0; r < 4; ++r) {
      int a_ = (gw << 4) + rowb + r;
#pragma unroll
      for (int nb = 0; nb < 4; ++nb) {
        int col = nb * 16 + colb;
        size_t off = (size_t)a_ * 64 + col;
        float nv = bf2f(tl[wid][rowb + r][col]);
        float vv = nv + bias[col] + acc[nb][r]
                 + bf2f((unsigned short)gS[r][nb]) + bf2f((unsigned short)gD[r][nb]);
        a_out[off] = f2bf(vv);
        sr[r] += vv; ssr[r] += vv * vv;
      }
      bf16x4_t pv;
#pragma unroll
      for (int nb = 0; nb < 4; ++nb)
        pv[nb] = (short)f2bf(bf2f((unsigned short)gS[r][4 + nb]) + bf2f((unsigned short)gD[r][4 + nb]));
      *(bf16x4_t*)(pe + (size_t)a_ * 64 + colb * 4) = pv;
    }
  }
#pragma unroll
  for (int m = 1; m <= 8; m <<= 1)
#pragma unroll
    for (int r = 0; r < 4; ++r) { sr[r] += __shfl_xor(sr[r], m); ssr[r] += __shfl_xor(ssr[r], m); }
  if (act && colb == 0) {
#pragma unroll
    for (int r = 0; r < 4; ++r) {
      int g = abatch[(gw << 4) + rowb + r];
      atomicAdd(&ls1[g], sr[r]); atomicAdd(&ls2[g], ssr[r]);
    }
  }
  __syncthreads();
  if (threadIdx.x < NG) {
    atomicAdd(&gs1[threadIdx.x], ls1[threadIdx.x]);
    atomicAdd(&gs2[threadIdx.x], ls2[threadIdx.x]);
  }
}

// =====================================================================
// emp finish (pure stream): msg = relu(pe + affA1(a1)@Wemp_a + b)
// =====================================================================
__global__ __launch_bounds__(256) void k_fin_emp(
    const unsigned short* __restrict__ a_, const int* __restrict__ abatch,
    const unsigned short* __restrict__ Wt,    // wt_emp [64][192]
    const float* __restrict__ bias,
    const float* __restrict__ afAA, const float* __restrict__ afAB,
    unsigned short* __restrict__ msg, int nA)
{
  __shared__ float lAA[1024], lAB[1024];
  for (int i = threadIdx.x; i < 1024; i += 256) { lAA[i] = afAA[i]; lAB[i] = afAB[i]; }
  __syncthreads();
  int gw = (int)((blockIdx.x * 256u + threadIdx.x) >> 6);
  int ntile = nA >> 4;
  if (gw >= ntile) return;
  int lane = threadIdx.x & 63;
  int colb = lane & 15;
  int ko = (lane >> 4) << 3;
  int rowb = (lane >> 4) << 2;
  int row = (gw << 4) + colb;
  int ga = abatch[row];
  f32x4_t acc[4] = {};
#pragma unroll
  for (int c2 = 0; c2 < 2; ++c2) {
    int fb = c2 * 32 + ko;
    bf16x8_t t = *(const bf16x8_t*)(a_ + (size_t)row * 64 + fb);
    bf16x8_t a;
#pragma unroll
    for (int k = 0; k < 8; ++k)
      a[k] = (short)f2bf(bf2f((unsigned short)t[k]) * lAA[ga*64 + fb + k] + lAB[ga*64 + fb + k]);
#pragma unroll
    for (int nb = 0; nb < 4; ++nb) {
      bf16x8_t b = *(const bf16x8_t*)(Wt + (size_t)(nb * 16 + colb) * 192 + 128 + c2 * 32 + ko);
      acc[nb] = __builtin_amdgcn_mfma_f32_16x16x32_bf16(a, b, acc[nb], 0, 0, 0);
    }
  }
  bf16x4_t p4[4];
#pragma unroll
  for (int r = 0; r < 4; ++r)
    p4[r] = *(const bf16x4_t*)(msg + (size_t)((gw << 4) + rowb + r) * 64 + colb * 4);
#pragma unroll
  for (int r = 0; r < 4; ++r) {
    int a_idx = (gw << 4) + rowb + r;
#pragma unroll
    for (int nb = 0; nb < 4; ++nb) {
      int col = nb * 16 + colb;
      float v = fmaxf(acc[nb][r] + bf2f((unsigned short)p4[r][nb]) + bias[col], 0.f);
      msg[(size_t)a_idx * 64 + col] = f2bf(v);
    }
  }
}

// =====================================================================
// nmp finish (gathers T3/T4 of P directly):
//   msg = relu(P_T3[s] + P_T4[d] + affE2(e2)@Wnmp_e + b)
// =====================================================================
__global__ __launch_bounds__(256) void k_fin_nmp(
    const unsigned short* __restrict__ P,
    const unsigned short* __restrict__ e, const int* __restrict__ ei,
    const int* __restrict__ ebatch,
    const unsigned short* __restrict__ Wt,    // wt_nmp [128][320]
    const float* __restrict__ bias,
    const float* __restrict__ afEA, const float* __restrict__ afEB,
    unsigned short* __restrict__ msg, int nE)
{
  __shared__ float lEA[1024], lEB[1024];
  for (int i = threadIdx.x; i < 1024; i += 256) { lEA[i] = afEA[i]; lEB[i] = afEB[i]; }
  __syncthreads();
  int gw = (int)((blockIdx.x * 256u + threadIdx.x) >> 6);
  int ntile = nE >> 4;
  if (gw >= ntile) return;
  int lane = threadIdx.x & 63;
  int colb = lane & 15;
  int ko = (lane >> 4) << 3;
  int rowb = (lane >> 4) << 2;
  int sI[4], dI[4];
#pragma unroll
  for (int r = 0; r < 4; ++r) {
    int e_r = (gw << 4) + rowb + r;
    sI[r] = ei[e_r]; dI[r] = ei[nE + e_r];
  }
  bf16x8_t g3[4], g4[4];
#pragma unroll
  for (int r = 0; r < 4; ++r) {
    g3[r] = *(const bf16x8_t*)(P + (size_t)sI[r] * 384 + 128 + colb * 8);
    g4[r] = *(const bf16x8_t*)(P + (size_t)dI[r] * 384 + 256 + colb * 8);
  }
  int row = (gw << 4) + colb;
  int ge = ebatch[row];
  f32x4_t acc[8] = {};
#pragma unroll
  for (int c2 = 0; c2 < 2; ++c2) {
    int fb = c2 * 32 + ko;
    bf16x8_t t = *(const bf16x8_t*)(e + (size_t)row * 64 + fb);
    bf16x8_t a;
#pragma unroll
    for (int k = 0; k < 8; ++k)
      a[k] = (short)f2bf(bf2f((unsigned short)t[k]) * lEA[ge*64 + fb + k] + lEB[ge*64 + fb + k]);
#pragma unroll
    for (int nb = 0; nb < 8; ++nb) {
      bf16x8_t b = *(const bf16x8_t*)(Wt + (size_t)(nb * 16 + colb) * 320 + (8 + c2) * 32 + ko);
      acc[nb] = __builtin_amdgcn_mfma_f32_16x16x32_bf16(a, b, acc[nb], 0, 0, 0);
    }
  }
#pragma unroll
  for (int r = 0; r < 4; ++r) {
    int e_ = (gw << 4) + rowb + r;
#pragma unroll
    for (int nb = 0; nb < 8; ++nb) {
      int col = nb * 16 + colb;
      float v = fmaxf(acc[nb][r] + bf2f((unsigned short)g3[r][nb]) + bf2f((unsigned short)g4[r][nb])
                      + bias[col], 0.f);
      msg[(size_t)e_ * 128 + col] = f2bf(v);
    }
  }
}

// =====================================================================
// CSR gather-reduce over edges: e2(bf16) = affE1(e1) + sum(msg rows); fused stats.
// =====================================================================
__global__ __launch_bounds__(256) void k_red_e(
    const unsigned short* __restrict__ msg, const unsigned short* e_in, unsigned short* e_out,
    const int* __restrict__ ptr, const int* __restrict__ perm,
    const int* __restrict__ ebatch,
    const float* __restrict__ afA, const float* __restrict__ afB,
    float* __restrict__ gs1, float* __restrict__ gs2, int nE)
{
  __shared__ float lA[1024], lB[1024], ls1[NG], ls2[NG];
  for (int i = threadIdx.x; i < 1024; i += 256) { lA[i] = afA[i]; lB[i] = afB[i]; }
  if (threadIdx.x < NG) { ls1[threadIdx.x] = 0.f; ls2[threadIdx.x] = 0.f; }
  __syncthreads();
  int lane = threadIdx.x & 63;
  int wv = (int)((blockIdx.x * 256u + threadIdx.x) >> 6);
  int nw = (int)((gridDim.x * 256u) >> 6);
  for (int eidx = wv; eidx < nE; eidx += nw) {
    int p0 = ptr[eidx], p1 = ptr[eidx + 1];
    float sum = 0.f;
    for (int j = p0; j < p1; ++j) {
      int aidx = perm[j];
      sum += bf2f(msg[(size_t)aidx * 64 + lane]);
    }
    int g = ebatch[eidx];
    size_t off = (size_t)eidx * 64 + lane;
    float v = bf2f(e_in[off]) * lA[g*64 + lane] + lB[g*64 + lane] + sum;
    e_out[off] = f2bf(v);
    float s = v, ss = v * v;
#pragma unroll
    for (int m = 1; m < 64; m <<= 1) { s += __shfl_xor(s, m); ss += __shfl_xor(ss, m); }
    if (lane == 0) { atomicAdd(&ls1[g], s); atomicAdd(&ls2[g], ss); }
  }
  __syncthreads();
  if (threadIdx.x < NG) {
    atomicAdd(&gs1[threadIdx.x], ls1[threadIdx.x]);
    atomicAdd(&gs2[threadIdx.x], ls2[threadIdx.x]);
  }
}

// =====================================================================
// CSR gather-reduce over nodes: h = x + sum(msg rows); fused stats. (x fp32)
// =====================================================================
__global__ __launch_bounds__(256) void k_red_n(
    const unsigned short* __restrict__ msg, const float* x_in, float* out,
    const int* __restrict__ ptr, const int* __restrict__ perm,
    const int* __restrict__ nbatch,
    float* __restrict__ gs1, float* __restrict__ gs2, int nN)
{
  __shared__ float ls1[NG], ls2[NG];
  if (threadIdx.x < NG) { ls1[threadIdx.x] = 0.f; ls2[threadIdx.x] = 0.f; }
  __syncthreads();
  int lane = threadIdx.x & 63;
  int wv = (int)((blockIdx.x * 256u + threadIdx.x) >> 6);
  int nw = (int)((gridDim.x * 256u) >> 6);
  for (int n = wv; n < nN; n += nw) {
    int p0 = ptr[n], p1 = ptr[n + 1];
    float s0 = 0.f, s1v = 0.f;
    for (int j = p0; j < p1; ++j) {
      int e = perm[j];
      unsigned u = *(const unsigned*)(msg + (size_t)e * 128 + lane * 2);
      s0 += bf2f((unsigned short)(u & 0xffffu));
      s1v += bf2f((unsigned short)(u >> 16));
    }
    size_t off = (size_t)n * 128 + lane * 2;
    float h0 = x_in[off] + s0, h1 = x_in[off + 1] + s1v;
    out[off] = h0; out[off + 1] = h1;
    float s = h0 + h1, ss = h0 * h0 + h1 * h1;
#pragma unroll
    for (int m = 1; m < 64; m <<= 1) { s += __shfl_xor(s, m); ss += __shfl_xor(ss, m); }
    if (lane == 0) { int g = nbatch[n]; atomicAdd(&ls1[g], s); atomicAdd(&ls2[g], ss); }
  }
  __syncthreads();
  if (threadIdx.x < NG) {
    atomicAdd(&gs1[threadIdx.x], ls1[threadIdx.x]);
    atomicAdd(&gs2[threadIdx.x], ls2[threadIdx.x]);
  }
}

// ---- affine table construction ----
__global__ __launch_bounds__(256) void k_mkaff(
    const float* __restrict__ s1, const float* __restrict__ s2,
    const float* __restrict__ cnt, int F,
    const float* __restrict__ w, const float* __restrict__ b,
    float* __restrict__ A, float* __restrict__ B)
{
  int idx = blockIdx.x * 256 + threadIdx.x;
  if (idx >= NG * F) return;
  int g = idx / F, f = idx - g * F;
  float norm = fmaxf(cnt[g], 1.f) * (float)F;
  float m = s1[g] / norm;
  float var = s2[g] / norm - m * m;
  float inv = rsqrtf(var + EPS);
  float a = inv * w[f];
  A[idx] = a;
  B[idx] = b[f] - m * a;
}

__global__ __launch_bounds__(256) void k_idaff(float* __restrict__ A, float* __restrict__ B, int n)
{
  int idx = blockIdx.x * 256 + threadIdx.x;
  if (idx < n) { A[idx] = 1.f; B[idx] = 0.f; }
}

// ---- apply norm to x (in-place, fp32) ----
__global__ __launch_bounds__(256) void k_apply(
    float* h, const int* __restrict__ batch,
    const float* __restrict__ A, const float* __restrict__ B, int nN)
{
  int total = nN * 16;
  int stride = gridDim.x * 256;
  for (int idx = blockIdx.x * 256 + threadIdx.x; idx < total; idx += stride) {
    int row = idx >> 4, q = (idx & 15) * 8;
    int g = batch[row];
    float* hp = h + (size_t)row * 128 + q;
    float4 f0 = *(const float4*)hp;
    float4 f1 = *(const float4*)(hp + 4);
    float vv[8] = {f0.x,f0.y,f0.z,f0.w,f1.x,f1.y,f1.z,f1.w};
#pragma unroll
    for (int k = 0; k < 8; ++k) vv[k] = vv[k] * A[(g << 7) + q + k] + B[(g << 7) + q + k];
    float4 g0 = {vv[0],vv[1],vv[2],vv[3]}, g1 = {vv[4],vv[5],vv[6],vv[7]};
    *(float4*)hp = g0;
    *(float4*)(hp + 4) = g1;
  }
}

__global__ __launch_bounds__(256) void k_count(
    const int* __restrict__ batch, int n, float* __restrict__ cnt)
{
  __shared__ float lc[NG];
  if (threadIdx.x < NG) lc[threadIdx.x] = 0.f;
  __syncthreads();
  for (int i = blockIdx.x * 256 + threadIdx.x; i < n; i += gridDim.x * 256)
    atomicAdd(&lc[batch[i]], 1.f);
  __syncthreads();
  if (threadIdx.x < NG) atomicAdd(&cnt[threadIdx.x], lc[threadIdx.x]);
}

// ---- CSR build ----
__global__ __launch_bounds__(256) void k_hist(
    const int* __restrict__ dst, int n, int* __restrict__ cnt)
{
  for (int i = blockIdx.x * 256 + threadIdx.x; i < n; i += gridDim.x * 256)
    atomicAdd(&cnt[dst[i]], 1);
}

__global__ __launch_bounds__(256) void k_scan1(
    const int* __restrict__ in, int* __restrict__ out, int* __restrict__ bsum, int n)
{
  __shared__ int wtot[4];
  int tid = threadIdx.x, lane = tid & 63, wid = tid >> 6;
  int base = blockIdx.x * 1024 + tid * 4;
  int v[4];
#pragma unroll
  for (int k = 0; k < 4; ++k) v[k] = (base + k < n) ? in[base + k] : 0;
  int tsum = v[0] + v[1] + v[2] + v[3];
  int incl = tsum;
#pragma unroll
  for (int off = 1; off < 64; off <<= 1) {
    int up = __shfl_up(incl, off);
    if (lane >= off) incl += up;
  }
  if (lane == 63) wtot[wid] = incl;
  __syncthreads();
  if (tid == 0) {
    int r = 0;
#pragma unroll
    for (int w2 = 0; w2 < 4; ++w2) { int t = wtot[w2]; wtot[w2] = r; r += t; }
    bsum[blockIdx.x] = r;
  }
  __syncthreads();
  int excl = wtot[wid] + incl - tsum;
#pragma unroll
  for (int k = 0; k < 4; ++k) {
    if (base + k < n) out[base + k] = excl;
    excl += v[k];
  }
}

__global__ __launch_bounds__(256) void k_scan2(int* __restrict__ bsum, int nb, int* __restrict__ total_out)
{
  __shared__ int wtot[4];
  int tid = threadIdx.x, lane = tid & 63, wid = tid >> 6;
  int base = tid * 4;
  int v[4];
#pragma unroll
  for (int k = 0; k < 4; ++k) v[k] = (base + k < nb) ? bsum[base + k] : 0;
  int tsum = v[0] + v[1] + v[2] + v[3];
  int incl = tsum;
#pragma unroll
  for (int off = 1; off < 64; off <<= 1) {
    int up = __shfl_up(incl, off);
    if (lane >= off) incl += up;
  }
  if (lane == 63) wtot[wid] = incl;
  __syncthreads();
  if (tid == 0) {
    int r = 0;
#pragma unroll
    for (int w2 = 0; w2 < 4; ++w2) { int t = wtot[w2]; wtot[w2] = r; r += t; }
    *total_out = r;
  }
  __syncthreads();
  int excl = wtot[wid] + incl - tsum;
#pragma unroll
  for (int k = 0; k < 4; ++k) {
    if (base + k < nb) bsum[base + k] = excl;
    excl += v[k];
  }
}

__global__ __launch_bounds__(256) void k_scan3(
    int* __restrict__ ptr, int* __restrict__ cur, const int* __restrict__ bsum, int n)
{
  for (int i = blockIdx.x * 256 + threadIdx.x; i < n; i += gridDim.x * 256) {
    int v = ptr[i] + bsum[i >> 10];
    ptr[i] = v; cur[i] = v;
  }
}

__global__ __launch_bounds__(256) void k_scatter(
    const int* __restrict__ dst, int* __restrict__ cur, int* __restrict__ perm, int n)
{
  for (int i = blockIdx.x * 256 + threadIdx.x; i < n; i += gridDim.x * 256) {
    int d = dst[i];
    int p = atomicAdd(&cur[d], 1);
    perm[p] = i;
  }
}

// ---- weight prep ----
__global__ __launch_bounds__(256) void k_wt(
    const float* __restrict__ W, unsigned short* __restrict__ Wt, int K, int NO)
{
  int idx = blockIdx.x * 256 + threadIdx.x;
  if (idx >= K * NO) return;
  int k = idx / NO, j = idx - k * NO;
  Wt[(size_t)j * K + k] = f2bf(W[idx]);
}

extern "C" void kernel_launch(void* const* d_in, const int* in_sizes, int n_in,
                              void* d_out, int out_size, void* d_ws, size_t ws_size,
                              hipStream_t stream)
{
  const float* x0    = (const float*)d_in[0];
  const float* e0    = (const float*)d_in[1];
  const float* a0    = (const float*)d_in[2];
  const float* W_ne  = (const float*)d_in[3];
  const float* b_ne  = (const float*)d_in[4];
  const float* g_e   = (const float*)d_in[5];
  const float* be_e  = (const float*)d_in[6];
  const float* W_ea  = (const float*)d_in[7];
  const float* b_ea  = (const float*)d_in[8];
  const float* g_a   = (const float*)d_in[9];
  const float* be_a  = (const float*)d_in[10];
  const float* W_emp = (const float*)d_in[11];
  const float* b_emp = (const float*)d_in[12];
  const float* g_emp = (const float*)d_in[13];
  const float* be_emp= (const float*)d_in[14];
  const float* W_nmp = (const float*)d_in[15];
  const float* b_nmp = (const float*)d_in[16];
  const float* g_nmp = (const float*)d_in[17];
  const float* be_nmp= (const float*)d_in[18];
  const int* node_batch  = (const int*)d_in[19];
  const int* edge_index  = (const int*)d_in[20];
  const int* edge_batch  = (const int*)d_in[21];
  const int* tb_index    = (const int*)d_in[22];
  const int* angle_batch = (const int*)d_in[23];

  const int N = in_sizes[0] / 128;
  const int E = in_sizes[1] / 64;
  const int A = in_sizes[2] / 64;

  // ---- workspace layout (bytes, 256-aligned) ----
  char* wsp = (char*)d_ws;
  auto alloc = [&](size_t bytes) { char* p = wsp; wsp += (bytes + 255) & ~(size_t)255; return p; };
  unsigned short* eAB  = (unsigned short*)alloc((size_t)E * 64 * 2);   // e intermediate (bf16)
  unsigned short* aAB  = (unsigned short*)alloc((size_t)A * 64 * 2);   // a intermediate (bf16)
  unsigned short* msg  = (unsigned short*)alloc((size_t)A * 64 * 2);   // pe / msg_e / msg_n
  unsigned short* P    = (unsigned short*)alloc((size_t)N * 384 * 2);  // x partials (lives to stage 4)
  unsigned short* PAE  = (unsigned short*)alloc((size_t)E * 256 * 2);  // angle+emp partials (swizzled)
  int* ptr_n  = (int*)alloc((size_t)(N + 1) * 4);
  int* cur_n  = (int*)alloc((size_t)N * 4);
  int* perm_n = (int*)alloc((size_t)E * 4);
  int* ptr_e  = (int*)alloc((size_t)(E + 1) * 4);
  int* cur_e  = (int*)alloc((size_t)E * 4);
  int* perm_e = (int*)alloc((size_t)A * 4);
  int* bsum   = (int*)alloc(4096 * 4);
  float* stats = (float*)alloc(5 * NG * 4);   // contiguous: s1,s2,cnt_n,cnt_e,cnt_a
  float* s1    = stats;
  float* s2    = stats + NG;
  float* cnt_n = stats + 2 * NG;
  float* cnt_e = stats + 3 * NG;
  float* cnt_a = stats + 4 * NG;
  float* afE_idA = (float*)alloc(1024 * 4); float* afE_idB = (float*)alloc(1024 * 4);
  float* afA_idA = (float*)alloc(1024 * 4); float* afA_idB = (float*)alloc(1024 * 4);
  float* afE1A   = (float*)alloc(1024 * 4); float* afE1B   = (float*)alloc(1024 * 4);
  float* afE2A   = (float*)alloc(1024 * 4); float* afE2B   = (float*)alloc(1024 * 4);
  float* afA1A   = (float*)alloc(1024 * 4); float* afA1B   = (float*)alloc(1024 * 4);
  float* afXA    = (float*)alloc(2048 * 4); float* afXB    = (float*)alloc(2048 * 4);
  unsigned short* wt_ne  = (unsigned short*)alloc((size_t)2 * 320 * 64 * 2);
  unsigned short* wt_ea  = (unsigned short*)alloc((size_t)2 * 192 * 64 * 2);
  unsigned short* wt_emp = (unsigned short*)alloc((size_t)2 * 192 * 64 * 2);
  unsigned short* wt_nmp = (unsigned short*)alloc((size_t)2 * 320 * 128 * 2);

  float* x_out = (float*)d_out;

  // ---- one-time prep ----
  for (int i = 0; i < 2; ++i) {
    k_wt<<<(320*64 + 255)/256, 256, 0, stream>>>(W_ne  + (size_t)i*320*64,  wt_ne  + (size_t)i*320*64,  320, 64);
    k_wt<<<(192*64 + 255)/256, 256, 0, stream>>>(W_ea  + (size_t)i*192*64,  wt_ea  + (size_t)i*192*64,  192, 64);
    k_wt<<<(192*64 + 255)/256, 256, 0, stream>>>(W_emp + (size_t)i*192*64,  wt_emp + (size_t)i*192*64,  192, 64);
    k_wt<<<(320*128 + 255)/256, 256, 0, stream>>>(W_nmp + (size_t)i*320*128, wt_nmp + (size_t)i*320*128, 320, 128);
  }
  hipMemsetAsync(stats, 0, 5 * NG * 4, stream);
  k_count<<<512, 256, 0, stream>>>(node_batch, N, cnt_n);
  k_count<<<512, 256, 0, stream>>>(edge_batch, E, cnt_e);
  k_count<<<512, 256, 0, stream>>>(angle_batch, A, cnt_a);
  k_idaff<<<4, 256, 0, stream>>>(afE_idA, afE_idB, 1024);
  k_idaff<<<4, 256, 0, stream>>>(afA_idA, afA_idB, 1024);

  // CSR over nodes (dst of edge_index) and edges (dst of threebody)
  hipMemsetAsync(cur_n, 0, (size_t)N * 4, stream);
  hipMemsetAsync(cur_e, 0, (size_t)E * 4, stream);
  k_hist<<<1024, 256, 0, stream>>>(edge_index + E, E, cur_n);
  k_hist<<<1024, 256, 0, stream>>>(tb_index + A, A, cur_e);
  int nbN = (N + 1023) / 1024, nbE = (E + 1023) / 1024;
  k_scan1<<<nbN, 256, 0, stream>>>(cur_n, ptr_n, bsum, N);
  k_scan2<<<1, 256, 0, stream>>>(bsum, nbN, ptr_n + N);
  k_scan3<<<1024, 256, 0, stream>>>(ptr_n, cur_n, bsum, N);
  k_scatter<<<1024, 256, 0, stream>>>(edge_index + E, cur_n, perm_n, E);
  k_scan1<<<nbE, 256, 0, stream>>>(cur_e, ptr_e, bsum, E);
  k_scan2<<<1, 256, 0, stream>>>(bsum, nbE, ptr_e + E);
  k_scan3<<<1024, 256, 0, stream>>>(ptr_e, cur_e, bsum, E);
  k_scatter<<<1024, 256, 0, stream>>>(tb_index + A, cur_e, perm_e, A);

  const float* x_cur = x0;
  int blkE = (E / 16 + 3) / 4;
  int blkA = (A / 16 + 3) / 4;
  int blkN = (N / 16 + 3) / 4;

  for (int i = 0; i < 2; ++i) {
    const float* fEinA = (i == 0) ? afE_idA : afE2A;
    const float* fEinB = (i == 0) ? afE_idB : afE2B;
    const float* fAinA = (i == 0) ? afA_idA : afA1A;
    const float* fAinB = (i == 0) ? afA_idB : afA1B;

    // 0. dense x-partials (P persists through stage 4)
    k_dense_x<<<blkN, 256, 0, stream>>>(x_cur, wt_ne + (size_t)i*320*64,
                                        wt_nmp + (size_t)i*320*128, P, N);

    // 1. edge stage (T1/T2 gathers only; LDS-tiled epilogue) -> affE1
    hipMemsetAsync(s1, 0, 2 * NG * 4, stream);
    if (i == 0)
      k_edge<true><<<blkE, 256, 0, stream>>>(P, (const void*)e0, eAB, edge_index, edge_batch,
                                             wt_ne + (size_t)i*320*64, b_ne + i*64,
                                             fEinA, fEinB, s1, s2, E);
    else
      k_edge<false><<<blkE, 256, 0, stream>>>(P, (const void*)eAB, eAB, edge_index, edge_batch,
                                              wt_ne + (size_t)i*320*64, b_ne + i*64,
                                              fEinA, fEinB, s1, s2, E);
    k_mkaff<<<4, 256, 0, stream>>>(s1, s2, cnt_e, 64, g_e + i*64, be_e + i*64, afE1A, afE1B);

    // 1.5 dense angle+emp partials over edges -> PAE
    k_prep_e<<<blkE, 256, 0, stream>>>(eAB, edge_batch, afE1A, afE1B,
                                       wt_ea + (size_t)i*192*64, wt_emp + (size_t)i*192*64,
                                       PAE, E);

    // 2. angle stage (adds-only gathers; LDS-tiled epilogue) -> affA1, pe -> msg
    hipMemsetAsync(s1, 0, 2 * NG * 4, stream);
    if (i == 0)
      k_angle<true><<<blkA, 256, 0, stream>>>(PAE, (const void*)a0, aAB, tb_index, angle_batch,
                                              wt_ea + (size_t)i*192*64, b_ea + i*64,
                                              fAinA, fAinB, s1, s2, msg, A);
    else
      k_angle<false><<<blkA, 256, 0, stream>>>(PAE, (const void*)aAB, aAB, tb_index, angle_batch,
                                               wt_ea + (size_t)i*192*64, b_ea + i*64,
                                               fAinA, fAinB, s1, s2, msg, A);
    k_mkaff<<<4, 256, 0, stream>>>(s1, s2, cnt_a, 64, g_a + i*64, be_a + i*64, afA1A, afA1B);

    // 3. emp finish (stream) -> msg; CSR reduce -> affE2
    k_fin_emp<<<blkA, 256, 0, stream>>>(aAB, angle_batch, wt_emp + (size_t)i*192*64,
                                        b_emp + i*64, afA1A, afA1B, msg, A);
    hipMemsetAsync(s1, 0, 2 * NG * 4, stream);
    k_red_e<<<2048, 256, 0, stream>>>(msg, eAB, eAB, ptr_e, perm_e, edge_batch,
                                      afE1A, afE1B, s1, s2, E);
    k_mkaff<<<4, 256, 0, stream>>>(s1, s2, cnt_e, 64, g_emp + i*64, be_emp + i*64, afE2A, afE2B);

    // 4. nmp finish (gathers P T3/T4 directly) -> msg; CSR reduce; apply
    k_fin_nmp<<<blkE, 256, 0, stream>>>(P, eAB, edge_index, edge_batch,
                                        wt_nmp + (size_t)i*320*128, b_nmp + i*128,
                                        afE2A, afE2B, msg, E);
    hipMemsetAsync(s1, 0, 2 * NG * 4, stream);
    k_red_n<<<2048, 256, 0, stream>>>(msg, x_cur, x_out, ptr_n, perm_n, node_batch,
                                      s1, s2, N);
    k_mkaff<<<8, 256, 0, stream>>>(s1, s2, cnt_n, 128, g_nmp + i*128, be_nmp + i*128, afXA, afXB);
    k_apply<<<2048, 256, 0, stream>>>(x_out, node_batch, afXA, afXB, N);

    x_cur = x_out;
  }
}